// Round 2
// baseline (896.339 us; speedup 1.0000x reference)
//
#include <hip/hip_runtime.h>
#include <math.h>

constexpr int IN_DIM = 256;
constexpr int HID    = 64;
constexpr int OUTD   = 32;
#define NEG_SLOPE 0.2f
#define EPSV 1e-16f

__device__ __forceinline__ float eluf(float x) {
    return x > 0.f ? x : expm1f(x);
}

// ---------------- init: zero deg + cursor ----------------
__global__ void k_init(int* __restrict__ deg, int* __restrict__ cur, int n) {
    int i = blockIdx.x * blockDim.x + threadIdx.x;
    int stride = gridDim.x * blockDim.x;
    for (; i < n; i += stride) { deg[i] = 0; cur[i] = 0; }
}

// ---------------- h = feat @ w1 ; alpha_s = h.att_src ; alpha_d = h.att_dst ----
__global__ __launch_bounds__(256) void k_feat(
    const float* __restrict__ feat, const float* __restrict__ w1,
    const float* __restrict__ att_src, const float* __restrict__ att_dst,
    float* __restrict__ h, float* __restrict__ as_, float* __restrict__ ad_, int n)
{
    __shared__ float  w1s[IN_DIM * HID];   // 64 KB, [k][j]
    __shared__ float4 fsT[4][64][4];       // 16 KB, [wave][k4][node] -> feats 4k4..4k4+3
    int t = threadIdx.x;
    int lane = t & 63, wv = t >> 6;
    for (int i = t; i < IN_DIM * HID / 4; i += 256)
        ((float4*)w1s)[i] = ((const float4*)w1)[i];
    float asl = att_src[lane], adl = att_dst[lane];
    __syncthreads();

    for (int base = blockIdx.x * 16; base < n; base += gridDim.x * 16) {
        // stage 16 nodes' features (transposed into per-wave slabs)
        #pragma unroll
        for (int i = 0; i < 4; ++i) {
            int flat = t + 256 * i;        // 0..1023
            int nl = flat >> 6;            // 0..15 local node
            int k4 = flat & 63;
            int node = base + nl;
            float4 v = (node < n) ? ((const float4*)feat)[(size_t)node * 64 + k4]
                                  : make_float4(0.f, 0.f, 0.f, 0.f);
            fsT[nl >> 2][k4][nl & 3] = v;
        }
        __syncthreads();

        float acc0 = 0.f, acc1 = 0.f, acc2 = 0.f, acc3 = 0.f;
        #pragma unroll 2
        for (int k4 = 0; k4 < 64; ++k4) {
            float4 f0 = fsT[wv][k4][0];
            float4 f1 = fsT[wv][k4][1];
            float4 f2 = fsT[wv][k4][2];
            float4 f3 = fsT[wv][k4][3];
            float w_0 = w1s[(k4 * 4 + 0) * 64 + lane];
            float w_1 = w1s[(k4 * 4 + 1) * 64 + lane];
            float w_2 = w1s[(k4 * 4 + 2) * 64 + lane];
            float w_3 = w1s[(k4 * 4 + 3) * 64 + lane];
            acc0 += f0.x * w_0 + f0.y * w_1 + f0.z * w_2 + f0.w * w_3;
            acc1 += f1.x * w_0 + f1.y * w_1 + f1.z * w_2 + f1.w * w_3;
            acc2 += f2.x * w_0 + f2.y * w_1 + f2.z * w_2 + f2.w * w_3;
            acc3 += f3.x * w_0 + f3.y * w_1 + f3.z * w_2 + f3.w * w_3;
        }

        int node0 = base + wv * 4;
        float accs[4] = {acc0, acc1, acc2, acc3};
        #pragma unroll
        for (int nd = 0; nd < 4; ++nd) {
            int node = node0 + nd;
            if (node < n) {                      // wave-uniform
                float a = accs[nd];
                h[(size_t)node * 64 + lane] = a;
                float s1 = a * asl, s2 = a * adl;
                #pragma unroll
                for (int i = 32; i > 0; i >>= 1) {
                    s1 += __shfl_xor(s1, i);
                    s2 += __shfl_xor(s2, i);
                }
                if (lane == 0) { as_[node] = s1; ad_[node] = s2; }
            }
        }
        __syncthreads();
    }
}

// ---------------- degree count ----------------
__global__ void k_deg(const int* __restrict__ ei, int* __restrict__ deg, int e) {
    int i = blockIdx.x * blockDim.x + threadIdx.x;
    int stride = gridDim.x * blockDim.x;
    for (; i < e; i += stride) {
        int d = ei[(size_t)e + i];
        atomicAdd(&deg[d], 1);
    }
}

// ---------------- exclusive scan (single block, 1024 threads) ----------------
__global__ __launch_bounds__(1024) void k_scan(const int* __restrict__ deg,
                                               int* __restrict__ off, int n) {
    __shared__ int wsum[16];
    __shared__ int carry_s;
    int t = threadIdx.x, lane = t & 63, wv = t >> 6;
    if (t == 0) carry_s = 0;
    __syncthreads();
    for (int base = 0; base < n; base += 1024) {
        int idx = base + t;
        int v = (idx < n) ? deg[idx] : 0;
        int x = v;
        #pragma unroll
        for (int i = 1; i < 64; i <<= 1) {
            int u = __shfl_up(x, i);
            if (lane >= i) x += u;
        }
        if (lane == 63) wsum[wv] = x;
        __syncthreads();
        int add = 0;
        for (int w = 0; w < wv; ++w) add += wsum[w];
        int carry = carry_s;
        __syncthreads();
        int incl = x + add;
        if (idx < n) off[idx] = carry + incl - v;
        if (t == 1023) carry_s = carry + incl;
        __syncthreads();
    }
    if (t == 0) off[n] = carry_s;
}

// ---------------- fill CSR: per-edge e value + src, sorted by dst ----------------
__global__ void k_fill(const int* __restrict__ ei, const float* __restrict__ as_,
                       const float* __restrict__ ad_, const int* __restrict__ off,
                       int* __restrict__ cur, int* __restrict__ srcs,
                       float* __restrict__ es, int e) {
    int i = blockIdx.x * blockDim.x + threadIdx.x;
    int stride = gridDim.x * blockDim.x;
    for (; i < e; i += stride) {
        int s = ei[i];
        int d = ei[(size_t)e + i];
        float v = as_[s] + ad_[d];
        v = v > 0.f ? v : NEG_SLOPE * v;
        int pos = off[d] + atomicAdd(&cur[d], 1);
        srcs[pos] = s;
        es[pos] = v;
    }
}

// ---------------- per-dst segment softmax + aggregate + elu -> h1 ----------------
__global__ __launch_bounds__(256) void k_gat(const int* __restrict__ off,
                                             const int* __restrict__ srcs,
                                             const float* __restrict__ es,
                                             const float* __restrict__ h,
                                             float* __restrict__ h1, int n) {
    int lane = threadIdx.x & 63;
    int d = blockIdx.x * 4 + (threadIdx.x >> 6);
    if (d >= n) return;
    int beg = off[d], end = off[d + 1];
    float m = -3.0e38f;
    for (int i = beg + lane; i < end; i += 64) m = fmaxf(m, es[i]);
    #pragma unroll
    for (int i = 32; i > 0; i >>= 1) m = fmaxf(m, __shfl_xor(m, i));
    float z = 0.f, acc = 0.f;
    for (int i = beg; i < end; ++i) {
        float w = __expf(es[i] - m);   // uniform across wave; each lane recomputes
        z += w;
        acc += w * h[(size_t)srcs[i] * 64 + lane];
    }
    h1[(size_t)d * 64 + lane] = eluf(acc / (z + EPSV));
}

// ---------------- fused node MLP: h2 (out0), h3, h4 (out1) ----------------
__global__ __launch_bounds__(256) void k_mlp(
    const float* __restrict__ h1g,
    const float* __restrict__ w2, const float* __restrict__ l1w, const float* __restrict__ l1b,
    const float* __restrict__ l2w, const float* __restrict__ l2b,
    float* __restrict__ oh2, float* __restrict__ oh4, int n)
{
    __shared__ float w2s[HID * OUTD];          // [j][o] 8 KB
    __shared__ float l1wt[OUTD * HID];         // [o][j] 8 KB (transposed)
    __shared__ float l2wt[HID][IN_DIM + 2];    // [k][o] padded, 66 KB (transposed)
    __shared__ float l1bs[HID];
    __shared__ float l2bs[IN_DIM];
    __shared__ float h1s[4][HID];
    __shared__ float h2s[4][OUTD];
    __shared__ float h3s[4][HID];
    int t = threadIdx.x, lane = t & 63, wv = t >> 6;

    for (int i = t; i < HID * OUTD; i += 256) {
        w2s[i] = w2[i];
        l1wt[(i & 31) * 64 + (i >> 5)] = l1w[i];
    }
    for (int i = t; i < IN_DIM * HID; i += 256) l2wt[i & 63][i >> 6] = l2w[i];
    if (t < HID) l1bs[t] = l1b[t];
    if (t < IN_DIM) l2bs[t] = l2b[t];
    __syncthreads();

    for (int base = blockIdx.x * 4; base < n; base += gridDim.x * 4) {
        int node = base + wv;
        bool valid = node < n;
        float h1 = valid ? h1g[(size_t)node * 64 + lane] : 0.f;
        h1s[wv][lane] = h1;
        __syncthreads();

        // h2 = h1 @ w2 : lanes 0..31 & 32..63 split the j-reduction
        int o = lane & 31, half = lane >> 5;
        float a2 = 0.f;
        #pragma unroll
        for (int jj = 0; jj < 32; ++jj) {
            int j = half * 32 + jj;
            a2 += h1s[wv][j] * w2s[j * 32 + o];
        }
        a2 += __shfl_xor(a2, 32);
        if (lane < 32) {
            h2s[wv][o] = a2;
            if (valid) oh2[(size_t)node * 32 + o] = a2;
        }
        __syncthreads();

        // h3 = elu(h2 @ l1w^T + l1b)
        float a3 = l1bs[lane];
        #pragma unroll
        for (int oo = 0; oo < 32; ++oo) a3 += h2s[wv][oo] * l1wt[oo * 64 + lane];
        a3 = eluf(a3);
        h3s[wv][lane] = a3;
        __syncthreads();

        // h4 = h3 @ l2w^T + l2b : 4 outputs per lane
        float b0 = 0.f, b1 = 0.f, b2 = 0.f, b3 = 0.f;
        #pragma unroll 8
        for (int k = 0; k < 64; ++k) {
            float hv = h3s[wv][k];
            b0 += hv * l2wt[k][lane];
            b1 += hv * l2wt[k][lane + 64];
            b2 += hv * l2wt[k][lane + 128];
            b3 += hv * l2wt[k][lane + 192];
        }
        if (valid) {
            size_t o4 = (size_t)node * 256;
            oh4[o4 + lane]       = b0 + l2bs[lane];
            oh4[o4 + lane + 64]  = b1 + l2bs[lane + 64];
            oh4[o4 + lane + 128] = b2 + l2bs[lane + 128];
            oh4[o4 + lane + 192] = b3 + l2bs[lane + 192];
        }
        __syncthreads();
    }
}

extern "C" void kernel_launch(void* const* d_in, const int* in_sizes, int n_in,
                              void* d_out, int out_size, void* d_ws, size_t ws_size,
                              hipStream_t stream) {
    const float* feat    = (const float*)d_in[0];
    const int*   ei      = (const int*)d_in[1];     // int64 in ref -> int32 on device
    const float* w1      = (const float*)d_in[2];
    const float* att_src = (const float*)d_in[3];
    const float* att_dst = (const float*)d_in[4];
    const float* w2      = (const float*)d_in[5];
    const float* l1w     = (const float*)d_in[6];
    const float* l1b     = (const float*)d_in[7];
    const float* l2w     = (const float*)d_in[8];
    const float* l2b     = (const float*)d_in[9];

    const int N = in_sizes[0] / IN_DIM;
    const int E = in_sizes[1] / 2;

    char* p = (char*)d_ws;
    auto alloc = [&](size_t bytes) {
        char* r = p;
        p += (bytes + 255) & ~(size_t)255;
        return r;
    };
    float* h    = (float*)alloc((size_t)N * HID * 4);
    float* h1g  = (float*)alloc((size_t)N * HID * 4);
    float* as_  = (float*)alloc((size_t)N * 4);
    float* ad_  = (float*)alloc((size_t)N * 4);
    int*   deg  = (int*)alloc((size_t)N * 4);
    int*   cur  = (int*)alloc((size_t)N * 4);
    int*   off  = (int*)alloc((size_t)(N + 1) * 4);
    int*   srcs = (int*)alloc((size_t)E * 4);
    float* es   = (float*)alloc((size_t)E * 4);

    float* oh2 = (float*)d_out;
    float* oh4 = oh2 + (size_t)N * OUTD;

    hipLaunchKernelGGL(k_init, dim3(256), dim3(256), 0, stream, deg, cur, N);
    hipLaunchKernelGGL(k_feat, dim3(512), dim3(256), 0, stream,
                       feat, w1, att_src, att_dst, h, as_, ad_, N);
    hipLaunchKernelGGL(k_deg, dim3(2048), dim3(256), 0, stream, ei, deg, E);
    hipLaunchKernelGGL(k_scan, dim3(1), dim3(1024), 0, stream, deg, off, N);
    hipLaunchKernelGGL(k_fill, dim3(2048), dim3(256), 0, stream,
                       ei, as_, ad_, off, cur, srcs, es, E);
    hipLaunchKernelGGL(k_gat, dim3((N + 3) / 4), dim3(256), 0, stream,
                       off, srcs, es, h, h1g, N);
    hipLaunchKernelGGL(k_mlp, dim3(256), dim3(256), 0, stream,
                       h1g, w2, l1w, l1b, l2w, l2b, oh2, oh4, N);
}

// Round 3
// 765.290 us; speedup vs baseline: 1.1712x; 1.1712x over previous
//
#include <hip/hip_runtime.h>
#include <math.h>

constexpr int IN_DIM = 256;
constexpr int HID    = 64;
constexpr int OUTD   = 32;
#define NEG_SLOPE 0.2f
#define EPSV 1e-16f

__device__ __forceinline__ float eluf(float x) {
    return x > 0.f ? x : expm1f(x);
}

// ---------------- init: zero deg + cursor ----------------
__global__ void k_init(int* __restrict__ deg, int* __restrict__ cur, int n) {
    int i = blockIdx.x * blockDim.x + threadIdx.x;
    int stride = gridDim.x * blockDim.x;
    for (; i < n; i += stride) { deg[i] = 0; cur[i] = 0; }
}

// ---------------- h = feat @ w1 ; alpha_s = h.att_src ; alpha_d = h.att_dst ----
__global__ __launch_bounds__(256) void k_feat(
    const float* __restrict__ feat, const float* __restrict__ w1,
    const float* __restrict__ att_src, const float* __restrict__ att_dst,
    float* __restrict__ h, float* __restrict__ as_, float* __restrict__ ad_, int n)
{
    __shared__ float  w1s[IN_DIM * HID];   // 64 KB, [k][j]
    __shared__ float4 fsT[4][64][4];       // 16 KB, [wave][k4][node] -> feats 4k4..4k4+3
    int t = threadIdx.x;
    int lane = t & 63, wv = t >> 6;
    for (int i = t; i < IN_DIM * HID / 4; i += 256)
        ((float4*)w1s)[i] = ((const float4*)w1)[i];
    float asl = att_src[lane], adl = att_dst[lane];
    __syncthreads();

    for (int base = blockIdx.x * 16; base < n; base += gridDim.x * 16) {
        // stage 16 nodes' features (transposed into per-wave slabs)
        #pragma unroll
        for (int i = 0; i < 4; ++i) {
            int flat = t + 256 * i;        // 0..1023
            int nl = flat >> 6;            // 0..15 local node
            int k4 = flat & 63;
            int node = base + nl;
            float4 v = (node < n) ? ((const float4*)feat)[(size_t)node * 64 + k4]
                                  : make_float4(0.f, 0.f, 0.f, 0.f);
            fsT[nl >> 2][k4][nl & 3] = v;
        }
        __syncthreads();

        float acc0 = 0.f, acc1 = 0.f, acc2 = 0.f, acc3 = 0.f;
        #pragma unroll 2
        for (int k4 = 0; k4 < 64; ++k4) {
            float4 f0 = fsT[wv][k4][0];
            float4 f1 = fsT[wv][k4][1];
            float4 f2 = fsT[wv][k4][2];
            float4 f3 = fsT[wv][k4][3];
            float w_0 = w1s[(k4 * 4 + 0) * 64 + lane];
            float w_1 = w1s[(k4 * 4 + 1) * 64 + lane];
            float w_2 = w1s[(k4 * 4 + 2) * 64 + lane];
            float w_3 = w1s[(k4 * 4 + 3) * 64 + lane];
            acc0 += f0.x * w_0 + f0.y * w_1 + f0.z * w_2 + f0.w * w_3;
            acc1 += f1.x * w_0 + f1.y * w_1 + f1.z * w_2 + f1.w * w_3;
            acc2 += f2.x * w_0 + f2.y * w_1 + f2.z * w_2 + f2.w * w_3;
            acc3 += f3.x * w_0 + f3.y * w_1 + f3.z * w_2 + f3.w * w_3;
        }

        int node0 = base + wv * 4;
        float accs[4] = {acc0, acc1, acc2, acc3};
        #pragma unroll
        for (int nd = 0; nd < 4; ++nd) {
            int node = node0 + nd;
            if (node < n) {                      // wave-uniform
                float a = accs[nd];
                h[(size_t)node * 64 + lane] = a;
                float s1 = a * asl, s2 = a * adl;
                #pragma unroll
                for (int i = 32; i > 0; i >>= 1) {
                    s1 += __shfl_xor(s1, i);
                    s2 += __shfl_xor(s2, i);
                }
                if (lane == 0) { as_[node] = s1; ad_[node] = s2; }
            }
        }
        __syncthreads();
    }
}

// ---------------- degree count ----------------
__global__ void k_deg(const int* __restrict__ ei, int* __restrict__ deg, int e) {
    int i = blockIdx.x * blockDim.x + threadIdx.x;
    int stride = gridDim.x * blockDim.x;
    for (; i < e; i += stride) {
        int d = ei[(size_t)e + i];
        atomicAdd(&deg[d], 1);
    }
}

// ---------------- exclusive scan (single block, 1024 threads) ----------------
__global__ __launch_bounds__(1024) void k_scan(const int* __restrict__ deg,
                                               int* __restrict__ off, int n) {
    __shared__ int wsum[16];
    __shared__ int carry_s;
    int t = threadIdx.x, lane = t & 63, wv = t >> 6;
    if (t == 0) carry_s = 0;
    __syncthreads();
    for (int base = 0; base < n; base += 1024) {
        int idx = base + t;
        int v = (idx < n) ? deg[idx] : 0;
        int x = v;
        #pragma unroll
        for (int i = 1; i < 64; i <<= 1) {
            int u = __shfl_up(x, i);
            if (lane >= i) x += u;
        }
        if (lane == 63) wsum[wv] = x;
        __syncthreads();
        int add = 0;
        for (int w = 0; w < wv; ++w) add += wsum[w];
        int carry = carry_s;
        __syncthreads();
        int incl = x + add;
        if (idx < n) off[idx] = carry + incl - v;
        if (t == 1023) carry_s = carry + incl;
        __syncthreads();
    }
    if (t == 0) off[n] = carry_s;
}

// ---------------- fill CSR: per-edge e value + src, sorted by dst ----------------
__global__ void k_fill(const int* __restrict__ ei, const float* __restrict__ as_,
                       const float* __restrict__ ad_, const int* __restrict__ off,
                       int* __restrict__ cur, int* __restrict__ srcs,
                       float* __restrict__ es, int e) {
    int i = blockIdx.x * blockDim.x + threadIdx.x;
    int stride = gridDim.x * blockDim.x;
    for (; i < e; i += stride) {
        int s = ei[i];
        int d = ei[(size_t)e + i];
        float v = as_[s] + ad_[d];
        v = v > 0.f ? v : NEG_SLOPE * v;
        int pos = off[d] + atomicAdd(&cur[d], 1);
        srcs[pos] = s;
        es[pos] = v;
    }
}

// ---------------- per-dst segment softmax + aggregate + elu -> h1 ----------------
__global__ __launch_bounds__(256) void k_gat(const int* __restrict__ off,
                                             const int* __restrict__ srcs,
                                             const float* __restrict__ es,
                                             const float* __restrict__ h,
                                             float* __restrict__ h1, int n) {
    int lane = threadIdx.x & 63;
    int d = blockIdx.x * 4 + (threadIdx.x >> 6);
    if (d >= n) return;
    int beg = off[d], end = off[d + 1];
    float m = -3.0e38f;
    for (int i = beg + lane; i < end; i += 64) m = fmaxf(m, es[i]);
    #pragma unroll
    for (int i = 32; i > 0; i >>= 1) m = fmaxf(m, __shfl_xor(m, i));
    float z = 0.f, acc = 0.f;
    for (int i = beg; i < end; ++i) {
        float w = __expf(es[i] - m);   // uniform across wave; each lane recomputes
        z += w;
        acc += w * h[(size_t)srcs[i] * 64 + lane];
    }
    h1[(size_t)d * 64 + lane] = eluf(acc / (z + EPSV));
}

// ---------------- MLP stage A: h2 = h1 @ w2 (out0), h3 = elu(h2 @ l1w^T + b) ----
// Thread-per-node; weights via wave-uniform (scalar) loads; h1 staged in LDS.
__global__ __launch_bounds__(256) void k_mlp_a(
    const float* __restrict__ h1g, const float* __restrict__ w2,
    const float* __restrict__ l1w, const float* __restrict__ l1b,
    float* __restrict__ oh2, float* __restrict__ h3, int n)
{
    __shared__ float h1s[256 * 68];   // 68 KB, pad-68 (aligned for float4, cheap banks)
    int t = threadIdx.x;

    for (int base = blockIdx.x * 256; base < n; base += gridDim.x * 256) {
        __syncthreads();
        #pragma unroll
        for (int i = 0; i < 16; ++i) {
            int flat = t + 256 * i;        // 0..4095
            int row = flat >> 4, c4 = flat & 15;
            int node = base + row;
            float4 v = (node < n) ? ((const float4*)h1g)[(size_t)node * 16 + c4]
                                  : make_float4(0.f, 0.f, 0.f, 0.f);
            *(float4*)&h1s[row * 68 + c4 * 4] = v;
        }
        __syncthreads();

        int node = base + t;
        const float* hrow = &h1s[t * 68];

        float acc2[32];
        #pragma unroll
        for (int o = 0; o < 32; ++o) acc2[o] = 0.f;
        #pragma unroll 4
        for (int j = 0; j < 64; ++j) {
            float hj = hrow[j];
            #pragma unroll
            for (int o = 0; o < 32; ++o) acc2[o] += hj * w2[j * 32 + o];
        }
        if (node < n) {
            #pragma unroll
            for (int o4 = 0; o4 < 8; ++o4) {
                float4 v = make_float4(acc2[o4 * 4], acc2[o4 * 4 + 1],
                                       acc2[o4 * 4 + 2], acc2[o4 * 4 + 3]);
                ((float4*)oh2)[(size_t)node * 8 + o4] = v;
            }
        }

        // h3 = elu(h2 @ l1w^T + l1b)
        #pragma unroll 2
        for (int j4 = 0; j4 < 16; ++j4) {
            float hv[4];
            #pragma unroll
            for (int jj = 0; jj < 4; ++jj) {
                int j = j4 * 4 + jj;
                float a = l1b[j];
                #pragma unroll
                for (int o = 0; o < 32; ++o) a += acc2[o] * l1w[j * 32 + o];
                hv[jj] = eluf(a);
            }
            if (node < n) {
                float4 v = make_float4(hv[0], hv[1], hv[2], hv[3]);
                ((float4*)h3)[(size_t)node * 16 + j4] = v;
            }
        }
    }
}

// ---------------- MLP stage B: h4 = h3 @ l2w^T + l2b (out1) ----
// Wave owns a 64-col quarter; weights resident in VGPRs; h3 row via scalar loads.
__global__ __launch_bounds__(256) void k_mlp_b(
    const float* __restrict__ h3, const float* __restrict__ l2w,
    const float* __restrict__ l2b, float* __restrict__ oh4, int n)
{
    int lane = threadIdx.x & 63;
    int wvu = __builtin_amdgcn_readfirstlane((int)(threadIdx.x >> 6));
    int col = wvu * 64 + lane;

    float wr[64];
    const float4* wp = (const float4*)(l2w + (size_t)col * 64);
    #pragma unroll
    for (int k4 = 0; k4 < 16; ++k4) {
        float4 v = wp[k4];
        wr[k4 * 4 + 0] = v.x; wr[k4 * 4 + 1] = v.y;
        wr[k4 * 4 + 2] = v.z; wr[k4 * 4 + 3] = v.w;
    }
    float bias = l2b[col];

    for (int nd = blockIdx.x; nd < n; nd += gridDim.x) {
        const float* hp = h3 + (size_t)nd * 64;   // wave-uniform address -> scalar loads
        float a0 = 0.f, a1 = 0.f, a2 = 0.f, a3 = 0.f;
        #pragma unroll
        for (int k = 0; k < 64; k += 4) {
            a0 += hp[k + 0] * wr[k + 0];
            a1 += hp[k + 1] * wr[k + 1];
            a2 += hp[k + 2] * wr[k + 2];
            a3 += hp[k + 3] * wr[k + 3];
        }
        oh4[(size_t)nd * 256 + col] = ((a0 + a1) + (a2 + a3)) + bias;
    }
}

extern "C" void kernel_launch(void* const* d_in, const int* in_sizes, int n_in,
                              void* d_out, int out_size, void* d_ws, size_t ws_size,
                              hipStream_t stream) {
    const float* feat    = (const float*)d_in[0];
    const int*   ei      = (const int*)d_in[1];     // int64 in ref -> int32 on device
    const float* w1      = (const float*)d_in[2];
    const float* att_src = (const float*)d_in[3];
    const float* att_dst = (const float*)d_in[4];
    const float* w2      = (const float*)d_in[5];
    const float* l1w     = (const float*)d_in[6];
    const float* l1b     = (const float*)d_in[7];
    const float* l2w     = (const float*)d_in[8];
    const float* l2b     = (const float*)d_in[9];

    const int N = in_sizes[0] / IN_DIM;
    const int E = in_sizes[1] / 2;

    char* p = (char*)d_ws;
    auto alloc = [&](size_t bytes) {
        char* r = p;
        p += (bytes + 255) & ~(size_t)255;
        return r;
    };
    float* h    = (float*)alloc((size_t)N * HID * 4);   // reused as h3 after k_gat
    float* h1g  = (float*)alloc((size_t)N * HID * 4);
    float* as_  = (float*)alloc((size_t)N * 4);
    float* ad_  = (float*)alloc((size_t)N * 4);
    int*   deg  = (int*)alloc((size_t)N * 4);
    int*   cur  = (int*)alloc((size_t)N * 4);
    int*   off  = (int*)alloc((size_t)(N + 1) * 4);
    int*   srcs = (int*)alloc((size_t)E * 4);
    float* es   = (float*)alloc((size_t)E * 4);

    float* oh2 = (float*)d_out;
    float* oh4 = oh2 + (size_t)N * OUTD;
    float* h3  = h;   // h is dead after k_gat

    hipLaunchKernelGGL(k_init, dim3(256), dim3(256), 0, stream, deg, cur, N);
    hipLaunchKernelGGL(k_feat, dim3(512), dim3(256), 0, stream,
                       feat, w1, att_src, att_dst, h, as_, ad_, N);
    hipLaunchKernelGGL(k_deg, dim3(2048), dim3(256), 0, stream, ei, deg, E);
    hipLaunchKernelGGL(k_scan, dim3(1), dim3(1024), 0, stream, deg, off, N);
    hipLaunchKernelGGL(k_fill, dim3(2048), dim3(256), 0, stream,
                       ei, as_, ad_, off, cur, srcs, es, E);
    hipLaunchKernelGGL(k_gat, dim3((N + 3) / 4), dim3(256), 0, stream,
                       off, srcs, es, h, h1g, N);
    hipLaunchKernelGGL(k_mlp_a, dim3((N + 255) / 256), dim3(256), 0, stream,
                       h1g, w2, l1w, l1b, oh2, h3, N);
    hipLaunchKernelGGL(k_mlp_b, dim3(1024), dim3(256), 0, stream,
                       h3, l2w, l2b, oh4, N);
}

// Round 4
// 704.195 us; speedup vs baseline: 1.2729x; 1.0868x over previous
//
#include <hip/hip_runtime.h>
#include <math.h>

constexpr int IN_DIM = 256;
constexpr int HID    = 64;
constexpr int OUTD   = 32;
#define NEG_SLOPE 0.2f
#define EPSV 1e-16f

__device__ __forceinline__ float eluf(float x) {
    return x > 0.f ? x : expm1f(x);
}

// ---------------- init: zero deg + cursor ----------------
__global__ void k_init(int* __restrict__ deg, int* __restrict__ cur, int n) {
    int i = blockIdx.x * blockDim.x + threadIdx.x;
    int stride = gridDim.x * blockDim.x;
    for (; i < n; i += stride) { deg[i] = 0; cur[i] = 0; }
}

// ---------------- h = feat @ w1 ; alpha_s = h.att_src ; alpha_d = h.att_dst ----
__global__ __launch_bounds__(256) void k_feat(
    const float* __restrict__ feat, const float* __restrict__ w1,
    const float* __restrict__ att_src, const float* __restrict__ att_dst,
    float* __restrict__ h, float* __restrict__ as_, float* __restrict__ ad_, int n)
{
    __shared__ float  w1s[IN_DIM * HID];   // 64 KB, [k][j]
    __shared__ float4 fsT[4][64][4];       // 16 KB, [wave][k4][node] -> feats 4k4..4k4+3
    int t = threadIdx.x;
    int lane = t & 63, wv = t >> 6;
    for (int i = t; i < IN_DIM * HID / 4; i += 256)
        ((float4*)w1s)[i] = ((const float4*)w1)[i];
    float asl = att_src[lane], adl = att_dst[lane];
    __syncthreads();

    for (int base = blockIdx.x * 16; base < n; base += gridDim.x * 16) {
        // stage 16 nodes' features (transposed into per-wave slabs)
        #pragma unroll
        for (int i = 0; i < 4; ++i) {
            int flat = t + 256 * i;        // 0..1023
            int nl = flat >> 6;            // 0..15 local node
            int k4 = flat & 63;
            int node = base + nl;
            float4 v = (node < n) ? ((const float4*)feat)[(size_t)node * 64 + k4]
                                  : make_float4(0.f, 0.f, 0.f, 0.f);
            fsT[nl >> 2][k4][nl & 3] = v;
        }
        __syncthreads();

        float acc0 = 0.f, acc1 = 0.f, acc2 = 0.f, acc3 = 0.f;
        #pragma unroll 2
        for (int k4 = 0; k4 < 64; ++k4) {
            float4 f0 = fsT[wv][k4][0];
            float4 f1 = fsT[wv][k4][1];
            float4 f2 = fsT[wv][k4][2];
            float4 f3 = fsT[wv][k4][3];
            float w_0 = w1s[(k4 * 4 + 0) * 64 + lane];
            float w_1 = w1s[(k4 * 4 + 1) * 64 + lane];
            float w_2 = w1s[(k4 * 4 + 2) * 64 + lane];
            float w_3 = w1s[(k4 * 4 + 3) * 64 + lane];
            acc0 += f0.x * w_0 + f0.y * w_1 + f0.z * w_2 + f0.w * w_3;
            acc1 += f1.x * w_0 + f1.y * w_1 + f1.z * w_2 + f1.w * w_3;
            acc2 += f2.x * w_0 + f2.y * w_1 + f2.z * w_2 + f2.w * w_3;
            acc3 += f3.x * w_0 + f3.y * w_1 + f3.z * w_2 + f3.w * w_3;
        }

        int node0 = base + wv * 4;
        float accs[4] = {acc0, acc1, acc2, acc3};
        #pragma unroll
        for (int nd = 0; nd < 4; ++nd) {
            int node = node0 + nd;
            if (node < n) {                      // wave-uniform
                float a = accs[nd];
                h[(size_t)node * 64 + lane] = a;
                float s1 = a * asl, s2 = a * adl;
                #pragma unroll
                for (int i = 32; i > 0; i >>= 1) {
                    s1 += __shfl_xor(s1, i);
                    s2 += __shfl_xor(s2, i);
                }
                if (lane == 0) { as_[node] = s1; ad_[node] = s2; }
            }
        }
        __syncthreads();
    }
}

// ---------------- degree count ----------------
__global__ void k_deg(const int* __restrict__ ei, int* __restrict__ deg, int e) {
    int i = blockIdx.x * blockDim.x + threadIdx.x;
    int stride = gridDim.x * blockDim.x;
    for (; i < e; i += stride) {
        int d = ei[(size_t)e + i];
        atomicAdd(&deg[d], 1);
    }
}

// ---------------- exclusive scan (single block, 1024 threads) ----------------
__global__ __launch_bounds__(1024) void k_scan(const int* __restrict__ deg,
                                               int* __restrict__ off, int n) {
    __shared__ int wsum[16];
    __shared__ int carry_s;
    int t = threadIdx.x, lane = t & 63, wv = t >> 6;
    if (t == 0) carry_s = 0;
    __syncthreads();
    for (int base = 0; base < n; base += 1024) {
        int idx = base + t;
        int v = (idx < n) ? deg[idx] : 0;
        int x = v;
        #pragma unroll
        for (int i = 1; i < 64; i <<= 1) {
            int u = __shfl_up(x, i);
            if (lane >= i) x += u;
        }
        if (lane == 63) wsum[wv] = x;
        __syncthreads();
        int add = 0;
        for (int w = 0; w < wv; ++w) add += wsum[w];
        int carry = carry_s;
        __syncthreads();
        int incl = x + add;
        if (idx < n) off[idx] = carry + incl - v;
        if (t == 1023) carry_s = carry + incl;
        __syncthreads();
    }
    if (t == 0) off[n] = carry_s;
}

// ---------------- fill CSR: per-edge e value + src, sorted by dst ----------------
__global__ void k_fill(const int* __restrict__ ei, const float* __restrict__ as_,
                       const float* __restrict__ ad_, const int* __restrict__ off,
                       int* __restrict__ cur, int* __restrict__ srcs,
                       float* __restrict__ es, int e) {
    int i = blockIdx.x * blockDim.x + threadIdx.x;
    int stride = gridDim.x * blockDim.x;
    for (; i < e; i += stride) {
        int s = ei[i];
        int d = ei[(size_t)e + i];
        float v = as_[s] + ad_[d];
        v = v > 0.f ? v : NEG_SLOPE * v;
        int pos = off[d] + atomicAdd(&cur[d], 1);
        srcs[pos] = s;
        es[pos] = v;
    }
}

// ---------------- softmax weights in-place: es[i] <- exp(es[i]-m)/ (z+eps) ----
// One wave per dst; edges striped across lanes (fully lane-parallel).
__global__ __launch_bounds__(256) void k_gatw(const int* __restrict__ off,
                                              float* __restrict__ es, int n) {
    int lane = threadIdx.x & 63;
    int d = blockIdx.x * 4 + (threadIdx.x >> 6);
    if (d >= n) return;
    int beg = off[d], end = off[d + 1];
    float m = -3.0e38f;
    for (int i = beg + lane; i < end; i += 64) m = fmaxf(m, es[i]);
    #pragma unroll
    for (int s = 32; s > 0; s >>= 1) m = fmaxf(m, __shfl_xor(m, s));

    int i0 = beg + lane;
    float e0 = 0.f, z = 0.f;
    if (i0 < end) { e0 = __expf(es[i0] - m); z = e0; }
    for (int i = i0 + 64; i < end; i += 64) {
        float e = __expf(es[i] - m);
        es[i] = e;                       // store unnormalized for rare deg>64 tail
        z += e;
    }
    #pragma unroll
    for (int s = 32; s > 0; s >>= 1) z += __shfl_xor(z, s);
    float rz = 1.f / (z + EPSV);
    if (i0 < end) es[i0] = e0 * rz;      // common case: normalized from register
    for (int i = i0 + 64; i < end; i += 64) es[i] *= rz;
}

// ---------------- weighted aggregate + elu -> h1 ----------------
// One wave per dst; unroll x4 with independent accumulators for 4x MLP.
__global__ __launch_bounds__(256) void k_gata(const int* __restrict__ off,
                                              const int* __restrict__ srcs,
                                              const float* __restrict__ es,
                                              const float* __restrict__ h,
                                              float* __restrict__ h1, int n) {
    int lane = threadIdx.x & 63;
    int d = blockIdx.x * 4 + (threadIdx.x >> 6);
    if (d >= n) return;
    int beg = off[d], end = off[d + 1];
    float a0 = 0.f, a1 = 0.f, a2 = 0.f, a3 = 0.f;
    int i = beg;
    for (; i + 4 <= end; i += 4) {
        int   s0 = srcs[i],   s1 = srcs[i + 1], s2 = srcs[i + 2], s3 = srcs[i + 3];
        float w0 = es[i],     w1 = es[i + 1],   w2 = es[i + 2],   w3 = es[i + 3];
        float v0 = h[(size_t)s0 * 64 + lane];
        float v1 = h[(size_t)s1 * 64 + lane];
        float v2 = h[(size_t)s2 * 64 + lane];
        float v3 = h[(size_t)s3 * 64 + lane];
        a0 += w0 * v0; a1 += w1 * v1; a2 += w2 * v2; a3 += w3 * v3;
    }
    for (; i < end; ++i) a0 += es[i] * h[(size_t)srcs[i] * 64 + lane];
    h1[(size_t)d * 64 + lane] = eluf((a0 + a1) + (a2 + a3));
}

// ---------------- MLP stage A: h2 = h1 @ w2 (out0), h3 = elu(h2 @ l1w^T + b) ----
// Thread-per-node; weights via wave-uniform (scalar) loads; h1 staged in LDS.
__global__ __launch_bounds__(256) void k_mlp_a(
    const float* __restrict__ h1g, const float* __restrict__ w2,
    const float* __restrict__ l1w, const float* __restrict__ l1b,
    float* __restrict__ oh2, float* __restrict__ h3, int n)
{
    __shared__ float h1s[256 * 68];   // 68 KB, pad-68 (aligned for float4, cheap banks)
    int t = threadIdx.x;

    for (int base = blockIdx.x * 256; base < n; base += gridDim.x * 256) {
        __syncthreads();
        #pragma unroll
        for (int i = 0; i < 16; ++i) {
            int flat = t + 256 * i;        // 0..4095
            int row = flat >> 4, c4 = flat & 15;
            int node = base + row;
            float4 v = (node < n) ? ((const float4*)h1g)[(size_t)node * 16 + c4]
                                  : make_float4(0.f, 0.f, 0.f, 0.f);
            *(float4*)&h1s[row * 68 + c4 * 4] = v;
        }
        __syncthreads();

        int node = base + t;
        const float* hrow = &h1s[t * 68];

        float acc2[32];
        #pragma unroll
        for (int o = 0; o < 32; ++o) acc2[o] = 0.f;
        #pragma unroll 4
        for (int j = 0; j < 64; ++j) {
            float hj = hrow[j];
            #pragma unroll
            for (int o = 0; o < 32; ++o) acc2[o] += hj * w2[j * 32 + o];
        }
        if (node < n) {
            #pragma unroll
            for (int o4 = 0; o4 < 8; ++o4) {
                float4 v = make_float4(acc2[o4 * 4], acc2[o4 * 4 + 1],
                                       acc2[o4 * 4 + 2], acc2[o4 * 4 + 3]);
                ((float4*)oh2)[(size_t)node * 8 + o4] = v;
            }
        }

        // h3 = elu(h2 @ l1w^T + l1b)
        #pragma unroll 2
        for (int j4 = 0; j4 < 16; ++j4) {
            float hv[4];
            #pragma unroll
            for (int jj = 0; jj < 4; ++jj) {
                int j = j4 * 4 + jj;
                float a = l1b[j];
                #pragma unroll
                for (int o = 0; o < 32; ++o) a += acc2[o] * l1w[j * 32 + o];
                hv[jj] = eluf(a);
            }
            if (node < n) {
                float4 v = make_float4(hv[0], hv[1], hv[2], hv[3]);
                ((float4*)h3)[(size_t)node * 16 + j4] = v;
            }
        }
    }
}

// ---------------- MLP stage B: h4 = h3 @ l2w^T + l2b (out1) ----
// Wave owns a 64-col quarter; weights resident in VGPRs; h3 row via scalar loads.
__global__ __launch_bounds__(256) void k_mlp_b(
    const float* __restrict__ h3, const float* __restrict__ l2w,
    const float* __restrict__ l2b, float* __restrict__ oh4, int n)
{
    int lane = threadIdx.x & 63;
    int wvu = __builtin_amdgcn_readfirstlane((int)(threadIdx.x >> 6));
    int col = wvu * 64 + lane;

    float wr[64];
    const float4* wp = (const float4*)(l2w + (size_t)col * 64);
    #pragma unroll
    for (int k4 = 0; k4 < 16; ++k4) {
        float4 v = wp[k4];
        wr[k4 * 4 + 0] = v.x; wr[k4 * 4 + 1] = v.y;
        wr[k4 * 4 + 2] = v.z; wr[k4 * 4 + 3] = v.w;
    }
    float bias = l2b[col];

    for (int nd = blockIdx.x; nd < n; nd += gridDim.x) {
        const float* hp = h3 + (size_t)nd * 64;   // wave-uniform address -> scalar loads
        float a0 = 0.f, a1 = 0.f, a2 = 0.f, a3 = 0.f;
        #pragma unroll
        for (int k = 0; k < 64; k += 4) {
            a0 += hp[k + 0] * wr[k + 0];
            a1 += hp[k + 1] * wr[k + 1];
            a2 += hp[k + 2] * wr[k + 2];
            a3 += hp[k + 3] * wr[k + 3];
        }
        oh4[(size_t)nd * 256 + col] = ((a0 + a1) + (a2 + a3)) + bias;
    }
}

extern "C" void kernel_launch(void* const* d_in, const int* in_sizes, int n_in,
                              void* d_out, int out_size, void* d_ws, size_t ws_size,
                              hipStream_t stream) {
    const float* feat    = (const float*)d_in[0];
    const int*   ei      = (const int*)d_in[1];     // int64 in ref -> int32 on device
    const float* w1      = (const float*)d_in[2];
    const float* att_src = (const float*)d_in[3];
    const float* att_dst = (const float*)d_in[4];
    const float* w2      = (const float*)d_in[5];
    const float* l1w     = (const float*)d_in[6];
    const float* l1b     = (const float*)d_in[7];
    const float* l2w     = (const float*)d_in[8];
    const float* l2b     = (const float*)d_in[9];

    const int N = in_sizes[0] / IN_DIM;
    const int E = in_sizes[1] / 2;

    char* p = (char*)d_ws;
    auto alloc = [&](size_t bytes) {
        char* r = p;
        p += (bytes + 255) & ~(size_t)255;
        return r;
    };
    float* h    = (float*)alloc((size_t)N * HID * 4);   // reused as h3 after k_gata
    float* h1g  = (float*)alloc((size_t)N * HID * 4);
    float* as_  = (float*)alloc((size_t)N * 4);
    float* ad_  = (float*)alloc((size_t)N * 4);
    int*   deg  = (int*)alloc((size_t)N * 4);
    int*   cur  = (int*)alloc((size_t)N * 4);
    int*   off  = (int*)alloc((size_t)(N + 1) * 4);
    int*   srcs = (int*)alloc((size_t)E * 4);
    float* es   = (float*)alloc((size_t)E * 4);

    float* oh2 = (float*)d_out;
    float* oh4 = oh2 + (size_t)N * OUTD;
    float* h3  = h;   // h is dead after k_gata

    hipLaunchKernelGGL(k_init, dim3(256), dim3(256), 0, stream, deg, cur, N);
    hipLaunchKernelGGL(k_feat, dim3(512), dim3(256), 0, stream,
                       feat, w1, att_src, att_dst, h, as_, ad_, N);
    hipLaunchKernelGGL(k_deg, dim3(2048), dim3(256), 0, stream, ei, deg, E);
    hipLaunchKernelGGL(k_scan, dim3(1), dim3(1024), 0, stream, deg, off, N);
    hipLaunchKernelGGL(k_fill, dim3(2048), dim3(256), 0, stream,
                       ei, as_, ad_, off, cur, srcs, es, E);
    hipLaunchKernelGGL(k_gatw, dim3((N + 3) / 4), dim3(256), 0, stream, off, es, N);
    hipLaunchKernelGGL(k_gata, dim3((N + 3) / 4), dim3(256), 0, stream,
                       off, srcs, es, h, h1g, N);
    hipLaunchKernelGGL(k_mlp_a, dim3((N + 255) / 256), dim3(256), 0, stream,
                       h1g, w2, l1w, l1b, oh2, h3, N);
    hipLaunchKernelGGL(k_mlp_b, dim3(1024), dim3(256), 0, stream,
                       h3, l2w, l2b, oh4, N);
}

// Round 5
// 617.077 us; speedup vs baseline: 1.4526x; 1.1412x over previous
//
#include <hip/hip_runtime.h>
#include <math.h>

constexpr int IN_DIM = 256;
constexpr int HID    = 64;
constexpr int OUTD   = 32;
#define NEG_SLOPE 0.2f
#define EPSV 1e-16f

__device__ __forceinline__ float eluf(float x) {
    return x > 0.f ? x : expm1f(x);
}

__device__ __forceinline__ unsigned short f32_to_bf16_rne(float f) {
    unsigned u = __float_as_uint(f);
    unsigned r = u + 0x7fffu + ((u >> 16) & 1u);
    return (unsigned short)(r >> 16);
}
__device__ __forceinline__ float bf16_bits_to_f32(unsigned short s) {
    return __uint_as_float(((unsigned)s) << 16);
}

// ---------------- init: zero deg + cursor ----------------
__global__ void k_init(int* __restrict__ deg, int* __restrict__ cur, int n) {
    int i = blockIdx.x * blockDim.x + threadIdx.x;
    int stride = gridDim.x * blockDim.x;
    for (; i < n; i += stride) { deg[i] = 0; cur[i] = 0; }
}

// ---------------- h = feat @ w1 via bf16-split MFMA; alphas fused ----------------
// Block: 256 thr = 4 waves; 64-node tile; wave w owns j-tile [w*16, w*16+16).
// feat tile staged as bf16 hi/lo in fragment-linear LDS layout (XOR-ks swizzle).
// w1 fragments resident in VGPRs (converted once per block).
// 3 MFMAs per (mt,ks): hi*hi + hi*lo + lo*hi  => ~2^-15 relative error.
__global__ __launch_bounds__(256) void k_feat_mfma(
    const float* __restrict__ feat, const float* __restrict__ w1,
    const float* __restrict__ att_src, const float* __restrict__ att_dst,
    float* __restrict__ h, float* __restrict__ as_, float* __restrict__ ad_, int n)
{
    typedef __attribute__((ext_vector_type(8))) short bx8;
    typedef __attribute__((ext_vector_type(4))) float fx4;

    __shared__ short a_hi[4 * 8 * 64 * 8];   // [mt*8+ks][lane'][8] = 32 KB
    __shared__ short a_lo[4 * 8 * 64 * 8];   // 32 KB
    __shared__ float al_part[2][4][64];      // alpha partials per j-tile

    int t = threadIdx.x, lane = t & 63, wv = t >> 6;
    int base = blockIdx.x * 64;

    // ---- B (w1) fragments -> registers, hi/lo split ----
    // B[k][n]: lane holds n = wv*16 + (lane&15), k = ks*32 + (lane>>4)*8 + i
    bx8 bhi[8], blo[8];
    {
        int nj = wv * 16 + (lane & 15);
        int kg = (lane >> 4) * 8;
        #pragma unroll
        for (int ks = 0; ks < 8; ++ks) {
            #pragma unroll
            for (int i = 0; i < 8; ++i) {
                float f = w1[(size_t)(ks * 32 + kg + i) * 64 + nj];
                unsigned short hb = f32_to_bf16_rne(f);
                float rem = f - bf16_bits_to_f32(hb);
                bhi[ks][i] = (short)hb;
                blo[ks][i] = (short)f32_to_bf16_rne(rem);
            }
        }
    }

    // ---- stage A (feat) tile: 64 nodes x 256 k, f32 -> bf16 hi/lo ----
    // chunk c: node = (t>>5)+c*8, oct = t&31 covers k = oct*8..oct*8+7
    float4 v[16];
    #pragma unroll
    for (int c = 0; c < 8; ++c) {
        int node = (t >> 5) + c * 8;
        int oct = t & 31;
        int gn = base + node;
        if (gn < n) {
            const float4* fp = (const float4*)(feat + (size_t)gn * 256);
            v[2 * c]     = fp[oct * 2];
            v[2 * c + 1] = fp[oct * 2 + 1];
        } else {
            v[2 * c]     = make_float4(0.f, 0.f, 0.f, 0.f);
            v[2 * c + 1] = make_float4(0.f, 0.f, 0.f, 0.f);
        }
    }
    #pragma unroll
    for (int c = 0; c < 8; ++c) {
        int node = (t >> 5) + c * 8;
        int oct = t & 31;
        int mt = node >> 4, lm = node & 15;
        int ks = oct >> 2, lg = oct & 3;
        int flane = lg * 16 + lm;
        int idx = (((mt * 8 + ks) * 64) + (flane ^ ks)) * 8;  // shorts; 16B aligned
        float ff[8] = { v[2*c].x, v[2*c].y, v[2*c].z, v[2*c].w,
                        v[2*c+1].x, v[2*c+1].y, v[2*c+1].z, v[2*c+1].w };
        bx8 hv, lv;
        #pragma unroll
        for (int i = 0; i < 8; ++i) {
            unsigned short hb = f32_to_bf16_rne(ff[i]);
            float rem = ff[i] - bf16_bits_to_f32(hb);
            hv[i] = (short)hb;
            lv[i] = (short)f32_to_bf16_rne(rem);
        }
        *(bx8*)&a_hi[idx] = hv;
        *(bx8*)&a_lo[idx] = lv;
    }
    __syncthreads();

    // ---- MFMA K-loop ----
    fx4 acc[4];
    #pragma unroll
    for (int mt = 0; mt < 4; ++mt) acc[mt] = (fx4){0.f, 0.f, 0.f, 0.f};
    #pragma unroll
    for (int mt = 0; mt < 4; ++mt) {
        #pragma unroll
        for (int ks = 0; ks < 8; ++ks) {
            int idx = (((mt * 8 + ks) * 64) + (lane ^ ks)) * 8;
            bx8 ah = *(bx8*)&a_hi[idx];
            bx8 al = *(bx8*)&a_lo[idx];
            acc[mt] = __builtin_amdgcn_mfma_f32_16x16x32_bf16(ah, bhi[ks], acc[mt], 0, 0, 0);
            acc[mt] = __builtin_amdgcn_mfma_f32_16x16x32_bf16(ah, blo[ks], acc[mt], 0, 0, 0);
            acc[mt] = __builtin_amdgcn_mfma_f32_16x16x32_bf16(al, bhi[ks], acc[mt], 0, 0, 0);
        }
    }

    // ---- epilogue: h stores + alpha partial reductions ----
    // C/D layout: col = lane&15 (j within tile), row = (lane>>4)*4 + reg (node)
    float asj = att_src[wv * 16 + (lane & 15)];
    float adj = att_dst[wv * 16 + (lane & 15)];
    #pragma unroll
    for (int mt = 0; mt < 4; ++mt) {
        #pragma unroll
        for (int r = 0; r < 4; ++r) {
            int lrow = mt * 16 + (lane >> 4) * 4 + r;
            int node = base + lrow;
            float hv = acc[mt][r];
            if (node < n) h[(size_t)node * 64 + wv * 16 + (lane & 15)] = hv;
            float p1 = hv * asj, p2 = hv * adj;
            p1 += __shfl_xor(p1, 1);  p2 += __shfl_xor(p2, 1);
            p1 += __shfl_xor(p1, 2);  p2 += __shfl_xor(p2, 2);
            p1 += __shfl_xor(p1, 4);  p2 += __shfl_xor(p2, 4);
            p1 += __shfl_xor(p1, 8);  p2 += __shfl_xor(p2, 8);
            if ((lane & 15) == 0) {
                al_part[0][wv][lrow] = p1;
                al_part[1][wv][lrow] = p2;
            }
        }
    }
    __syncthreads();
    if (t < 64) {
        int node = base + t;
        if (node < n) {
            as_[node] = al_part[0][0][t] + al_part[0][1][t] + al_part[0][2][t] + al_part[0][3][t];
            ad_[node] = al_part[1][0][t] + al_part[1][1][t] + al_part[1][2][t] + al_part[1][3][t];
        }
    }
}

// ---------------- degree count ----------------
__global__ void k_deg(const int* __restrict__ ei, int* __restrict__ deg, int e) {
    int i = blockIdx.x * blockDim.x + threadIdx.x;
    int stride = gridDim.x * blockDim.x;
    for (; i < e; i += stride) {
        int d = ei[(size_t)e + i];
        atomicAdd(&deg[d], 1);
    }
}

// ---------------- exclusive scan (single block, 1024 threads) ----------------
__global__ __launch_bounds__(1024) void k_scan(const int* __restrict__ deg,
                                               int* __restrict__ off, int n) {
    __shared__ int wsum[16];
    __shared__ int carry_s;
    int t = threadIdx.x, lane = t & 63, wv = t >> 6;
    if (t == 0) carry_s = 0;
    __syncthreads();
    for (int base = 0; base < n; base += 1024) {
        int idx = base + t;
        int v = (idx < n) ? deg[idx] : 0;
        int x = v;
        #pragma unroll
        for (int i = 1; i < 64; i <<= 1) {
            int u = __shfl_up(x, i);
            if (lane >= i) x += u;
        }
        if (lane == 63) wsum[wv] = x;
        __syncthreads();
        int add = 0;
        for (int w = 0; w < wv; ++w) add += wsum[w];
        int carry = carry_s;
        __syncthreads();
        int incl = x + add;
        if (idx < n) off[idx] = carry + incl - v;
        if (t == 1023) carry_s = carry + incl;
        __syncthreads();
    }
    if (t == 0) off[n] = carry_s;
}

// ---------------- fill CSR: per-edge e value + src, sorted by dst ----------------
__global__ void k_fill(const int* __restrict__ ei, const float* __restrict__ as_,
                       const float* __restrict__ ad_, const int* __restrict__ off,
                       int* __restrict__ cur, int* __restrict__ srcs,
                       float* __restrict__ es, int e) {
    int i = blockIdx.x * blockDim.x + threadIdx.x;
    int stride = gridDim.x * blockDim.x;
    for (; i < e; i += stride) {
        int s = ei[i];
        int d = ei[(size_t)e + i];
        float v = as_[s] + ad_[d];
        v = v > 0.f ? v : NEG_SLOPE * v;
        int pos = off[d] + atomicAdd(&cur[d], 1);
        srcs[pos] = s;
        es[pos] = v;
    }
}

// ---------------- softmax weights in-place: es[i] <- exp(es[i]-m)/ (z+eps) ----
__global__ __launch_bounds__(256) void k_gatw(const int* __restrict__ off,
                                              float* __restrict__ es, int n) {
    int lane = threadIdx.x & 63;
    int d = blockIdx.x * 4 + (threadIdx.x >> 6);
    if (d >= n) return;
    int beg = off[d], end = off[d + 1];
    float m = -3.0e38f;
    for (int i = beg + lane; i < end; i += 64) m = fmaxf(m, es[i]);
    #pragma unroll
    for (int s = 32; s > 0; s >>= 1) m = fmaxf(m, __shfl_xor(m, s));

    int i0 = beg + lane;
    float e0 = 0.f, z = 0.f;
    if (i0 < end) { e0 = __expf(es[i0] - m); z = e0; }
    for (int i = i0 + 64; i < end; i += 64) {
        float e = __expf(es[i] - m);
        es[i] = e;
        z += e;
    }
    #pragma unroll
    for (int s = 32; s > 0; s >>= 1) z += __shfl_xor(z, s);
    float rz = 1.f / (z + EPSV);
    if (i0 < end) es[i0] = e0 * rz;
    for (int i = i0 + 64; i < end; i += 64) es[i] *= rz;
}

// ---------------- weighted aggregate + elu -> h1 ----------------
__global__ __launch_bounds__(256) void k_gata(const int* __restrict__ off,
                                              const int* __restrict__ srcs,
                                              const float* __restrict__ es,
                                              const float* __restrict__ h,
                                              float* __restrict__ h1, int n) {
    int lane = threadIdx.x & 63;
    int d = blockIdx.x * 4 + (threadIdx.x >> 6);
    if (d >= n) return;
    int beg = off[d], end = off[d + 1];
    float a0 = 0.f, a1 = 0.f, a2 = 0.f, a3 = 0.f;
    int i = beg;
    for (; i + 4 <= end; i += 4) {
        int   s0 = srcs[i],   s1 = srcs[i + 1], s2 = srcs[i + 2], s3 = srcs[i + 3];
        float w0 = es[i],     w1 = es[i + 1],   w2 = es[i + 2],   w3 = es[i + 3];
        float v0 = h[(size_t)s0 * 64 + lane];
        float v1 = h[(size_t)s1 * 64 + lane];
        float v2 = h[(size_t)s2 * 64 + lane];
        float v3 = h[(size_t)s3 * 64 + lane];
        a0 += w0 * v0; a1 += w1 * v1; a2 += w2 * v2; a3 += w3 * v3;
    }
    for (; i < end; ++i) a0 += es[i] * h[(size_t)srcs[i] * 64 + lane];
    h1[(size_t)d * 64 + lane] = eluf((a0 + a1) + (a2 + a3));
}

// ---------------- MLP stage A: h2 = h1 @ w2 (out0), h3 = elu(h2 @ l1w^T + b) ----
__global__ __launch_bounds__(256) void k_mlp_a(
    const float* __restrict__ h1g, const float* __restrict__ w2,
    const float* __restrict__ l1w, const float* __restrict__ l1b,
    float* __restrict__ oh2, float* __restrict__ h3, int n)
{
    __shared__ float h1s[256 * 68];
    int t = threadIdx.x;

    for (int base = blockIdx.x * 256; base < n; base += gridDim.x * 256) {
        __syncthreads();
        #pragma unroll
        for (int i = 0; i < 16; ++i) {
            int flat = t + 256 * i;
            int row = flat >> 4, c4 = flat & 15;
            int node = base + row;
            float4 v = (node < n) ? ((const float4*)h1g)[(size_t)node * 16 + c4]
                                  : make_float4(0.f, 0.f, 0.f, 0.f);
            *(float4*)&h1s[row * 68 + c4 * 4] = v;
        }
        __syncthreads();

        int node = base + t;
        const float* hrow = &h1s[t * 68];

        float acc2[32];
        #pragma unroll
        for (int o = 0; o < 32; ++o) acc2[o] = 0.f;
        #pragma unroll 4
        for (int j = 0; j < 64; ++j) {
            float hj = hrow[j];
            #pragma unroll
            for (int o = 0; o < 32; ++o) acc2[o] += hj * w2[j * 32 + o];
        }
        if (node < n) {
            #pragma unroll
            for (int o4 = 0; o4 < 8; ++o4) {
                float4 v = make_float4(acc2[o4 * 4], acc2[o4 * 4 + 1],
                                       acc2[o4 * 4 + 2], acc2[o4 * 4 + 3]);
                ((float4*)oh2)[(size_t)node * 8 + o4] = v;
            }
        }

        #pragma unroll 2
        for (int j4 = 0; j4 < 16; ++j4) {
            float hv[4];
            #pragma unroll
            for (int jj = 0; jj < 4; ++jj) {
                int j = j4 * 4 + jj;
                float a = l1b[j];
                #pragma unroll
                for (int o = 0; o < 32; ++o) a += acc2[o] * l1w[j * 32 + o];
                hv[jj] = eluf(a);
            }
            if (node < n) {
                float4 v = make_float4(hv[0], hv[1], hv[2], hv[3]);
                ((float4*)h3)[(size_t)node * 16 + j4] = v;
            }
        }
    }
}

// ---------------- MLP stage B: h4 = h3 @ l2w^T + l2b (out1) ----
__global__ __launch_bounds__(256) void k_mlp_b(
    const float* __restrict__ h3, const float* __restrict__ l2w,
    const float* __restrict__ l2b, float* __restrict__ oh4, int n)
{
    int lane = threadIdx.x & 63;
    int wvu = __builtin_amdgcn_readfirstlane((int)(threadIdx.x >> 6));
    int col = wvu * 64 + lane;

    float wr[64];
    const float4* wp = (const float4*)(l2w + (size_t)col * 64);
    #pragma unroll
    for (int k4 = 0; k4 < 16; ++k4) {
        float4 v = wp[k4];
        wr[k4 * 4 + 0] = v.x; wr[k4 * 4 + 1] = v.y;
        wr[k4 * 4 + 2] = v.z; wr[k4 * 4 + 3] = v.w;
    }
    float bias = l2b[col];

    for (int nd = blockIdx.x; nd < n; nd += gridDim.x) {
        const float* hp = h3 + (size_t)nd * 64;
        float a0 = 0.f, a1 = 0.f, a2 = 0.f, a3 = 0.f;
        #pragma unroll
        for (int k = 0; k < 64; k += 4) {
            a0 += hp[k + 0] * wr[k + 0];
            a1 += hp[k + 1] * wr[k + 1];
            a2 += hp[k + 2] * wr[k + 2];
            a3 += hp[k + 3] * wr[k + 3];
        }
        oh4[(size_t)nd * 256 + col] = ((a0 + a1) + (a2 + a3)) + bias;
    }
}

extern "C" void kernel_launch(void* const* d_in, const int* in_sizes, int n_in,
                              void* d_out, int out_size, void* d_ws, size_t ws_size,
                              hipStream_t stream) {
    const float* feat    = (const float*)d_in[0];
    const int*   ei      = (const int*)d_in[1];     // int64 in ref -> int32 on device
    const float* w1      = (const float*)d_in[2];
    const float* att_src = (const float*)d_in[3];
    const float* att_dst = (const float*)d_in[4];
    const float* w2      = (const float*)d_in[5];
    const float* l1w     = (const float*)d_in[6];
    const float* l1b     = (const float*)d_in[7];
    const float* l2w     = (const float*)d_in[8];
    const float* l2b     = (const float*)d_in[9];

    const int N = in_sizes[0] / IN_DIM;
    const int E = in_sizes[1] / 2;

    char* p = (char*)d_ws;
    auto alloc = [&](size_t bytes) {
        char* r = p;
        p += (bytes + 255) & ~(size_t)255;
        return r;
    };
    float* h    = (float*)alloc((size_t)N * HID * 4);   // reused as h3 after k_gata
    float* h1g  = (float*)alloc((size_t)N * HID * 4);
    float* as_  = (float*)alloc((size_t)N * 4);
    float* ad_  = (float*)alloc((size_t)N * 4);
    int*   deg  = (int*)alloc((size_t)N * 4);
    int*   cur  = (int*)alloc((size_t)N * 4);
    int*   off  = (int*)alloc((size_t)(N + 1) * 4);
    int*   srcs = (int*)alloc((size_t)E * 4);
    float* es   = (float*)alloc((size_t)E * 4);

    float* oh2 = (float*)d_out;
    float* oh4 = oh2 + (size_t)N * OUTD;
    float* h3  = h;   // h is dead after k_gata

    hipLaunchKernelGGL(k_init, dim3(256), dim3(256), 0, stream, deg, cur, N);
    hipLaunchKernelGGL(k_feat_mfma, dim3((N + 63) / 64), dim3(256), 0, stream,
                       feat, w1, att_src, att_dst, h, as_, ad_, N);
    hipLaunchKernelGGL(k_deg, dim3(2048), dim3(256), 0, stream, ei, deg, E);
    hipLaunchKernelGGL(k_scan, dim3(1), dim3(1024), 0, stream, deg, off, N);
    hipLaunchKernelGGL(k_fill, dim3(2048), dim3(256), 0, stream,
                       ei, as_, ad_, off, cur, srcs, es, E);
    hipLaunchKernelGGL(k_gatw, dim3((N + 3) / 4), dim3(256), 0, stream, off, es, N);
    hipLaunchKernelGGL(k_gata, dim3((N + 3) / 4), dim3(256), 0, stream,
                       off, srcs, es, h, h1g, N);
    hipLaunchKernelGGL(k_mlp_a, dim3((N + 255) / 256), dim3(256), 0, stream,
                       h1g, w2, l1w, l1b, oh2, h3, N);
    hipLaunchKernelGGL(k_mlp_b, dim3(1024), dim3(256), 0, stream,
                       h3, l2w, l2b, oh4, N);
}

// Round 6
// 548.157 us; speedup vs baseline: 1.6352x; 1.1257x over previous
//
#include <hip/hip_runtime.h>
#include <math.h>

constexpr int IN_DIM = 256;
constexpr int HID    = 64;
constexpr int OUTD   = 32;
#define NEG_SLOPE 0.2f
#define EPSV 1e-16f

__device__ __forceinline__ float eluf(float x) {
    return x > 0.f ? x : expm1f(x);
}

__device__ __forceinline__ unsigned short f32_to_bf16_rne(float f) {
    unsigned u = __float_as_uint(f);
    unsigned r = u + 0x7fffu + ((u >> 16) & 1u);
    return (unsigned short)(r >> 16);
}
__device__ __forceinline__ float bf16_bits_to_f32(unsigned short s) {
    return __uint_as_float(((unsigned)s) << 16);
}

// ---------------- init: zero deg ----------------
__global__ void k_init(int* __restrict__ deg, int n) {
    int i = blockIdx.x * blockDim.x + threadIdx.x;
    int stride = gridDim.x * blockDim.x;
    for (; i < n; i += stride) deg[i] = 0;
}

// ---------------- h = feat @ w1 via bf16-split MFMA; alphas fused ----------------
__global__ __launch_bounds__(256) void k_feat_mfma(
    const float* __restrict__ feat, const float* __restrict__ w1,
    const float* __restrict__ att_src, const float* __restrict__ att_dst,
    float* __restrict__ h, float* __restrict__ as_, float* __restrict__ ad_, int n)
{
    typedef __attribute__((ext_vector_type(8))) short bx8;
    typedef __attribute__((ext_vector_type(4))) float fx4;

    __shared__ short a_hi[4 * 8 * 64 * 8];   // 32 KB
    __shared__ short a_lo[4 * 8 * 64 * 8];   // 32 KB
    __shared__ float al_part[2][4][64];

    int t = threadIdx.x, lane = t & 63, wv = t >> 6;
    int base = blockIdx.x * 64;

    // ---- B (w1) fragments -> registers, hi/lo split ----
    bx8 bhi[8], blo[8];
    {
        int nj = wv * 16 + (lane & 15);
        int kg = (lane >> 4) * 8;
        #pragma unroll
        for (int ks = 0; ks < 8; ++ks) {
            #pragma unroll
            for (int i = 0; i < 8; ++i) {
                float f = w1[(size_t)(ks * 32 + kg + i) * 64 + nj];
                unsigned short hb = f32_to_bf16_rne(f);
                float rem = f - bf16_bits_to_f32(hb);
                bhi[ks][i] = (short)hb;
                blo[ks][i] = (short)f32_to_bf16_rne(rem);
            }
        }
    }

    // ---- stage A (feat) tile ----
    float4 v[16];
    #pragma unroll
    for (int c = 0; c < 8; ++c) {
        int node = (t >> 5) + c * 8;
        int oct = t & 31;
        int gn = base + node;
        if (gn < n) {
            const float4* fp = (const float4*)(feat + (size_t)gn * 256);
            v[2 * c]     = fp[oct * 2];
            v[2 * c + 1] = fp[oct * 2 + 1];
        } else {
            v[2 * c]     = make_float4(0.f, 0.f, 0.f, 0.f);
            v[2 * c + 1] = make_float4(0.f, 0.f, 0.f, 0.f);
        }
    }
    #pragma unroll
    for (int c = 0; c < 8; ++c) {
        int node = (t >> 5) + c * 8;
        int oct = t & 31;
        int mt = node >> 4, lm = node & 15;
        int ks = oct >> 2, lg = oct & 3;
        int flane = lg * 16 + lm;
        int idx = (((mt * 8 + ks) * 64) + (flane ^ ks)) * 8;
        float ff[8] = { v[2*c].x, v[2*c].y, v[2*c].z, v[2*c].w,
                        v[2*c+1].x, v[2*c+1].y, v[2*c+1].z, v[2*c+1].w };
        bx8 hv, lv;
        #pragma unroll
        for (int i = 0; i < 8; ++i) {
            unsigned short hb = f32_to_bf16_rne(ff[i]);
            float rem = ff[i] - bf16_bits_to_f32(hb);
            hv[i] = (short)hb;
            lv[i] = (short)f32_to_bf16_rne(rem);
        }
        *(bx8*)&a_hi[idx] = hv;
        *(bx8*)&a_lo[idx] = lv;
    }
    __syncthreads();

    // ---- MFMA K-loop ----
    fx4 acc[4];
    #pragma unroll
    for (int mt = 0; mt < 4; ++mt) acc[mt] = (fx4){0.f, 0.f, 0.f, 0.f};
    #pragma unroll
    for (int mt = 0; mt < 4; ++mt) {
        #pragma unroll
        for (int ks = 0; ks < 8; ++ks) {
            int idx = (((mt * 8 + ks) * 64) + (lane ^ ks)) * 8;
            bx8 ah = *(bx8*)&a_hi[idx];
            bx8 al = *(bx8*)&a_lo[idx];
            acc[mt] = __builtin_amdgcn_mfma_f32_16x16x32_bf16(ah, bhi[ks], acc[mt], 0, 0, 0);
            acc[mt] = __builtin_amdgcn_mfma_f32_16x16x32_bf16(ah, blo[ks], acc[mt], 0, 0, 0);
            acc[mt] = __builtin_amdgcn_mfma_f32_16x16x32_bf16(al, bhi[ks], acc[mt], 0, 0, 0);
        }
    }

    // ---- epilogue ----
    float asj = att_src[wv * 16 + (lane & 15)];
    float adj = att_dst[wv * 16 + (lane & 15)];
    #pragma unroll
    for (int mt = 0; mt < 4; ++mt) {
        #pragma unroll
        for (int r = 0; r < 4; ++r) {
            int lrow = mt * 16 + (lane >> 4) * 4 + r;
            int node = base + lrow;
            float hv = acc[mt][r];
            if (node < n) h[(size_t)node * 64 + wv * 16 + (lane & 15)] = hv;
            float p1 = hv * asj, p2 = hv * adj;
            p1 += __shfl_xor(p1, 1);  p2 += __shfl_xor(p2, 1);
            p1 += __shfl_xor(p1, 2);  p2 += __shfl_xor(p2, 2);
            p1 += __shfl_xor(p1, 4);  p2 += __shfl_xor(p2, 4);
            p1 += __shfl_xor(p1, 8);  p2 += __shfl_xor(p2, 8);
            if ((lane & 15) == 0) {
                al_part[0][wv][lrow] = p1;
                al_part[1][wv][lrow] = p2;
            }
        }
    }
    __syncthreads();
    if (t < 64) {
        int node = base + t;
        if (node < n) {
            as_[node] = al_part[0][0][t] + al_part[0][1][t] + al_part[0][2][t] + al_part[0][3][t];
            ad_[node] = al_part[1][0][t] + al_part[1][1][t] + al_part[1][2][t] + al_part[1][3][t];
        }
    }
}

// ---------------- degree count + per-edge rank (coalesced write) ----------------
__global__ void k_deg(const int* __restrict__ ei, int* __restrict__ deg,
                      int* __restrict__ rank, int e) {
    int i = blockIdx.x * blockDim.x + threadIdx.x;
    int stride = gridDim.x * blockDim.x;
    for (; i < e; i += stride) {
        int d = ei[(size_t)e + i];
        rank[i] = atomicAdd(&deg[d], 1);
    }
}

// ---------------- exclusive scan (single block, 1024 threads) ----------------
__global__ __launch_bounds__(1024) void k_scan(const int* __restrict__ deg,
                                               int* __restrict__ off, int n) {
    __shared__ int wsum[16];
    __shared__ int carry_s;
    int t = threadIdx.x, lane = t & 63, wv = t >> 6;
    if (t == 0) carry_s = 0;
    __syncthreads();
    for (int base = 0; base < n; base += 1024) {
        int idx = base + t;
        int v = (idx < n) ? deg[idx] : 0;
        int x = v;
        #pragma unroll
        for (int i = 1; i < 64; i <<= 1) {
            int u = __shfl_up(x, i);
            if (lane >= i) x += u;
        }
        if (lane == 63) wsum[wv] = x;
        __syncthreads();
        int add = 0;
        for (int w = 0; w < wv; ++w) add += wsum[w];
        int carry = carry_s;
        __syncthreads();
        int incl = x + add;
        if (idx < n) off[idx] = carry + incl - v;
        if (t == 1023) carry_s = carry + incl;
        __syncthreads();
    }
    if (t == 0) off[n] = carry_s;
}

// ---------------- fill CSR (no atomics): edata[pos] = {src, leakyrelu(e)} ----
// dst-partitioned pass [lo,hi): scatter target ~3.2 MB stays L2-resident.
__global__ void k_fill(const int* __restrict__ ei, const float* __restrict__ as_,
                       const float* __restrict__ ad_, const int* __restrict__ off,
                       const int* __restrict__ rank, int2* __restrict__ edata,
                       int e, int lo, int hi) {
    int i = blockIdx.x * blockDim.x + threadIdx.x;
    int stride = gridDim.x * blockDim.x;
    for (; i < e; i += stride) {
        int d = ei[(size_t)e + i];
        if (d < lo || d >= hi) continue;
        int s = ei[i];
        float v = as_[s] + ad_[d];
        v = v > 0.f ? v : NEG_SLOPE * v;
        edata[off[d] + rank[i]] = make_int2(s, __float_as_int(v));
    }
}

// ---------------- softmax weights in-place on edata.y ----------------
__global__ __launch_bounds__(256) void k_gatw(const int* __restrict__ off,
                                              int2* __restrict__ edata, int n) {
    int lane = threadIdx.x & 63;
    int d = blockIdx.x * 4 + (threadIdx.x >> 6);
    if (d >= n) return;
    int beg = off[d], end = off[d + 1];
    float m = -3.0e38f;
    for (int i = beg + lane; i < end; i += 64)
        m = fmaxf(m, __int_as_float(edata[i].y));
    #pragma unroll
    for (int s = 32; s > 0; s >>= 1) m = fmaxf(m, __shfl_xor(m, s));

    int i0 = beg + lane;
    float e0 = 0.f, z = 0.f;
    if (i0 < end) { e0 = __expf(__int_as_float(edata[i0].y) - m); z = e0; }
    for (int i = i0 + 64; i < end; i += 64) {
        float e = __expf(__int_as_float(edata[i].y) - m);
        edata[i].y = __float_as_int(e);     // unnormalized, rare deg>64 tail
        z += e;
    }
    #pragma unroll
    for (int s = 32; s > 0; s >>= 1) z += __shfl_xor(z, s);
    float rz = 1.f / (z + EPSV);
    if (i0 < end) edata[i0].y = __float_as_int(e0 * rz);
    for (int i = i0 + 64; i < end; i += 64)
        edata[i].y = __float_as_int(__int_as_float(edata[i].y) * rz);
}

// ---------------- weighted aggregate + elu -> h1 ----------------
__global__ __launch_bounds__(256) void k_gata(const int* __restrict__ off,
                                              const int2* __restrict__ edata,
                                              const float* __restrict__ h,
                                              float* __restrict__ h1, int n) {
    int lane = threadIdx.x & 63;
    int d = blockIdx.x * 4 + (threadIdx.x >> 6);
    if (d >= n) return;
    int beg = off[d], end = off[d + 1];
    float a0 = 0.f, a1 = 0.f, a2 = 0.f, a3 = 0.f;
    int i = beg;
    for (; i + 4 <= end; i += 4) {
        int2 e0 = edata[i],     e1 = edata[i + 1];
        int2 e2 = edata[i + 2], e3 = edata[i + 3];
        float v0 = h[(size_t)e0.x * 64 + lane];
        float v1 = h[(size_t)e1.x * 64 + lane];
        float v2 = h[(size_t)e2.x * 64 + lane];
        float v3 = h[(size_t)e3.x * 64 + lane];
        a0 += __int_as_float(e0.y) * v0;
        a1 += __int_as_float(e1.y) * v1;
        a2 += __int_as_float(e2.y) * v2;
        a3 += __int_as_float(e3.y) * v3;
    }
    for (; i < end; ++i) {
        int2 ed = edata[i];
        a0 += __int_as_float(ed.y) * h[(size_t)ed.x * 64 + lane];
    }
    h1[(size_t)d * 64 + lane] = eluf((a0 + a1) + (a2 + a3));
}

// ---------------- MLP stage A: h2 = h1 @ w2 (out0), h3 = elu(h2 @ l1w^T + b) ----
__global__ __launch_bounds__(256) void k_mlp_a(
    const float* __restrict__ h1g, const float* __restrict__ w2,
    const float* __restrict__ l1w, const float* __restrict__ l1b,
    float* __restrict__ oh2, float* __restrict__ h3, int n)
{
    __shared__ float h1s[256 * 68];
    int t = threadIdx.x;

    for (int base = blockIdx.x * 256; base < n; base += gridDim.x * 256) {
        __syncthreads();
        #pragma unroll
        for (int i = 0; i < 16; ++i) {
            int flat = t + 256 * i;
            int row = flat >> 4, c4 = flat & 15;
            int node = base + row;
            float4 v = (node < n) ? ((const float4*)h1g)[(size_t)node * 16 + c4]
                                  : make_float4(0.f, 0.f, 0.f, 0.f);
            *(float4*)&h1s[row * 68 + c4 * 4] = v;
        }
        __syncthreads();

        int node = base + t;
        const float* hrow = &h1s[t * 68];

        float acc2[32];
        #pragma unroll
        for (int o = 0; o < 32; ++o) acc2[o] = 0.f;
        #pragma unroll 4
        for (int j = 0; j < 64; ++j) {
            float hj = hrow[j];
            #pragma unroll
            for (int o = 0; o < 32; ++o) acc2[o] += hj * w2[j * 32 + o];
        }
        if (node < n) {
            #pragma unroll
            for (int o4 = 0; o4 < 8; ++o4) {
                float4 v = make_float4(acc2[o4 * 4], acc2[o4 * 4 + 1],
                                       acc2[o4 * 4 + 2], acc2[o4 * 4 + 3]);
                ((float4*)oh2)[(size_t)node * 8 + o4] = v;
            }
        }

        #pragma unroll 2
        for (int j4 = 0; j4 < 16; ++j4) {
            float hv[4];
            #pragma unroll
            for (int jj = 0; jj < 4; ++jj) {
                int j = j4 * 4 + jj;
                float a = l1b[j];
                #pragma unroll
                for (int o = 0; o < 32; ++o) a += acc2[o] * l1w[j * 32 + o];
                hv[jj] = eluf(a);
            }
            if (node < n) {
                float4 v = make_float4(hv[0], hv[1], hv[2], hv[3]);
                ((float4*)h3)[(size_t)node * 16 + j4] = v;
            }
        }
    }
}

// ---------------- MLP stage B: h4 = h3 @ l2w^T + l2b (out1) ----
__global__ __launch_bounds__(256) void k_mlp_b(
    const float* __restrict__ h3, const float* __restrict__ l2w,
    const float* __restrict__ l2b, float* __restrict__ oh4, int n)
{
    int lane = threadIdx.x & 63;
    int wvu = __builtin_amdgcn_readfirstlane((int)(threadIdx.x >> 6));
    int col = wvu * 64 + lane;

    float wr[64];
    const float4* wp = (const float4*)(l2w + (size_t)col * 64);
    #pragma unroll
    for (int k4 = 0; k4 < 16; ++k4) {
        float4 v = wp[k4];
        wr[k4 * 4 + 0] = v.x; wr[k4 * 4 + 1] = v.y;
        wr[k4 * 4 + 2] = v.z; wr[k4 * 4 + 3] = v.w;
    }
    float bias = l2b[col];

    for (int nd = blockIdx.x; nd < n; nd += gridDim.x) {
        const float* hp = h3 + (size_t)nd * 64;
        float a0 = 0.f, a1 = 0.f, a2 = 0.f, a3 = 0.f;
        #pragma unroll
        for (int k = 0; k < 64; k += 4) {
            a0 += hp[k + 0] * wr[k + 0];
            a1 += hp[k + 1] * wr[k + 1];
            a2 += hp[k + 2] * wr[k + 2];
            a3 += hp[k + 3] * wr[k + 3];
        }
        oh4[(size_t)nd * 256 + col] = ((a0 + a1) + (a2 + a3)) + bias;
    }
}

extern "C" void kernel_launch(void* const* d_in, const int* in_sizes, int n_in,
                              void* d_out, int out_size, void* d_ws, size_t ws_size,
                              hipStream_t stream) {
    const float* feat    = (const float*)d_in[0];
    const int*   ei      = (const int*)d_in[1];     // int64 in ref -> int32 on device
    const float* w1      = (const float*)d_in[2];
    const float* att_src = (const float*)d_in[3];
    const float* att_dst = (const float*)d_in[4];
    const float* w2      = (const float*)d_in[5];
    const float* l1w     = (const float*)d_in[6];
    const float* l1b     = (const float*)d_in[7];
    const float* l2w     = (const float*)d_in[8];
    const float* l2b     = (const float*)d_in[9];

    const int N = in_sizes[0] / IN_DIM;
    const int E = in_sizes[1] / 2;

    char* p = (char*)d_ws;
    auto alloc = [&](size_t bytes) {
        char* r = p;
        p += (bytes + 255) & ~(size_t)255;
        return r;
    };
    float* h     = (float*)alloc((size_t)N * HID * 4);   // reused as h3 after k_gata
    float* h1g   = (float*)alloc((size_t)N * HID * 4);
    float* as_   = (float*)alloc((size_t)N * 4);
    float* ad_   = (float*)alloc((size_t)N * 4);
    int*   deg   = (int*)alloc((size_t)N * 4);
    int*   off   = (int*)alloc((size_t)(N + 1) * 4);
    int*   rank  = (int*)alloc((size_t)E * 4);
    int2*  edata = (int2*)alloc((size_t)E * 8);

    float* oh2 = (float*)d_out;
    float* oh4 = oh2 + (size_t)N * OUTD;
    float* h3  = h;   // h is dead after k_gata

    hipLaunchKernelGGL(k_init, dim3(256), dim3(256), 0, stream, deg, N);
    hipLaunchKernelGGL(k_feat_mfma, dim3((N + 63) / 64), dim3(256), 0, stream,
                       feat, w1, att_src, att_dst, h, as_, ad_, N);
    hipLaunchKernelGGL(k_deg, dim3(2048), dim3(256), 0, stream, ei, deg, rank, E);
    hipLaunchKernelGGL(k_scan, dim3(1), dim3(1024), 0, stream, deg, off, N);
    for (int pass = 0; pass < 4; ++pass) {
        int lo = (int)((size_t)N * pass / 4);
        int hi = (int)((size_t)N * (pass + 1) / 4);
        hipLaunchKernelGGL(k_fill, dim3(2048), dim3(256), 0, stream,
                           ei, as_, ad_, off, rank, edata, E, lo, hi);
    }
    hipLaunchKernelGGL(k_gatw, dim3((N + 3) / 4), dim3(256), 0, stream, off, edata, N);
    hipLaunchKernelGGL(k_gata, dim3((N + 3) / 4), dim3(256), 0, stream,
                       off, edata, h, h1g, N);
    hipLaunchKernelGGL(k_mlp_a, dim3((N + 255) / 256), dim3(256), 0, stream,
                       h1g, w2, l1w, l1b, oh2, h3, N);
    hipLaunchKernelGGL(k_mlp_b, dim3(1024), dim3(256), 0, stream,
                       h3, l2w, l2b, oh4, N);
}

// Round 7
// 469.724 us; speedup vs baseline: 1.9082x; 1.1670x over previous
//
#include <hip/hip_runtime.h>
#include <math.h>

constexpr int IN_DIM = 256;
constexpr int HID    = 64;
constexpr int OUTD   = 32;
#define NEG_SLOPE 0.2f
#define EPSV 1e-16f

__device__ __forceinline__ float eluf(float x) {
    return x > 0.f ? x : expm1f(x);
}

__device__ __forceinline__ unsigned short f32_to_bf16_rne(float f) {
    unsigned u = __float_as_uint(f);
    unsigned r = u + 0x7fffu + ((u >> 16) & 1u);
    return (unsigned short)(r >> 16);
}
__device__ __forceinline__ float bf16_bits_to_f32(unsigned short s) {
    return __uint_as_float(((unsigned)s) << 16);
}

// ---------------- init: zero deg ----------------
__global__ void k_init(int* __restrict__ deg, int n) {
    int i = blockIdx.x * blockDim.x + threadIdx.x;
    int stride = gridDim.x * blockDim.x;
    for (; i < n; i += stride) deg[i] = 0;
}

// ---------------- h = feat @ w1 via bf16-split MFMA; alphas fused ----------------
__global__ __launch_bounds__(256) void k_feat_mfma(
    const float* __restrict__ feat, const float* __restrict__ w1,
    const float* __restrict__ att_src, const float* __restrict__ att_dst,
    float* __restrict__ h, float* __restrict__ as_, float* __restrict__ ad_, int n)
{
    typedef __attribute__((ext_vector_type(8))) short bx8;
    typedef __attribute__((ext_vector_type(4))) float fx4;

    __shared__ short a_hi[4 * 8 * 64 * 8];   // 32 KB
    __shared__ short a_lo[4 * 8 * 64 * 8];   // 32 KB
    __shared__ float al_part[2][4][64];

    int t = threadIdx.x, lane = t & 63, wv = t >> 6;
    int base = blockIdx.x * 64;

    // ---- B (w1) fragments -> registers, hi/lo split ----
    bx8 bhi[8], blo[8];
    {
        int nj = wv * 16 + (lane & 15);
        int kg = (lane >> 4) * 8;
        #pragma unroll
        for (int ks = 0; ks < 8; ++ks) {
            #pragma unroll
            for (int i = 0; i < 8; ++i) {
                float f = w1[(size_t)(ks * 32 + kg + i) * 64 + nj];
                unsigned short hb = f32_to_bf16_rne(f);
                float rem = f - bf16_bits_to_f32(hb);
                bhi[ks][i] = (short)hb;
                blo[ks][i] = (short)f32_to_bf16_rne(rem);
            }
        }
    }

    // ---- stage A (feat) tile ----
    float4 v[16];
    #pragma unroll
    for (int c = 0; c < 8; ++c) {
        int node = (t >> 5) + c * 8;
        int oct = t & 31;
        int gn = base + node;
        if (gn < n) {
            const float4* fp = (const float4*)(feat + (size_t)gn * 256);
            v[2 * c]     = fp[oct * 2];
            v[2 * c + 1] = fp[oct * 2 + 1];
        } else {
            v[2 * c]     = make_float4(0.f, 0.f, 0.f, 0.f);
            v[2 * c + 1] = make_float4(0.f, 0.f, 0.f, 0.f);
        }
    }
    #pragma unroll
    for (int c = 0; c < 8; ++c) {
        int node = (t >> 5) + c * 8;
        int oct = t & 31;
        int mt = node >> 4, lm = node & 15;
        int ks = oct >> 2, lg = oct & 3;
        int flane = lg * 16 + lm;
        int idx = (((mt * 8 + ks) * 64) + (flane ^ ks)) * 8;
        float ff[8] = { v[2*c].x, v[2*c].y, v[2*c].z, v[2*c].w,
                        v[2*c+1].x, v[2*c+1].y, v[2*c+1].z, v[2*c+1].w };
        bx8 hv, lv;
        #pragma unroll
        for (int i = 0; i < 8; ++i) {
            unsigned short hb = f32_to_bf16_rne(ff[i]);
            float rem = ff[i] - bf16_bits_to_f32(hb);
            hv[i] = (short)hb;
            lv[i] = (short)f32_to_bf16_rne(rem);
        }
        *(bx8*)&a_hi[idx] = hv;
        *(bx8*)&a_lo[idx] = lv;
    }
    __syncthreads();

    // ---- MFMA K-loop ----
    fx4 acc[4];
    #pragma unroll
    for (int mt = 0; mt < 4; ++mt) acc[mt] = (fx4){0.f, 0.f, 0.f, 0.f};
    #pragma unroll
    for (int mt = 0; mt < 4; ++mt) {
        #pragma unroll
        for (int ks = 0; ks < 8; ++ks) {
            int idx = (((mt * 8 + ks) * 64) + (lane ^ ks)) * 8;
            bx8 ah = *(bx8*)&a_hi[idx];
            bx8 al = *(bx8*)&a_lo[idx];
            acc[mt] = __builtin_amdgcn_mfma_f32_16x16x32_bf16(ah, bhi[ks], acc[mt], 0, 0, 0);
            acc[mt] = __builtin_amdgcn_mfma_f32_16x16x32_bf16(ah, blo[ks], acc[mt], 0, 0, 0);
            acc[mt] = __builtin_amdgcn_mfma_f32_16x16x32_bf16(al, bhi[ks], acc[mt], 0, 0, 0);
        }
    }

    // ---- epilogue ----
    float asj = att_src[wv * 16 + (lane & 15)];
    float adj = att_dst[wv * 16 + (lane & 15)];
    #pragma unroll
    for (int mt = 0; mt < 4; ++mt) {
        #pragma unroll
        for (int r = 0; r < 4; ++r) {
            int lrow = mt * 16 + (lane >> 4) * 4 + r;
            int node = base + lrow;
            float hv = acc[mt][r];
            if (node < n) h[(size_t)node * 64 + wv * 16 + (lane & 15)] = hv;
            float p1 = hv * asj, p2 = hv * adj;
            p1 += __shfl_xor(p1, 1);  p2 += __shfl_xor(p2, 1);
            p1 += __shfl_xor(p1, 2);  p2 += __shfl_xor(p2, 2);
            p1 += __shfl_xor(p1, 4);  p2 += __shfl_xor(p2, 4);
            p1 += __shfl_xor(p1, 8);  p2 += __shfl_xor(p2, 8);
            if ((lane & 15) == 0) {
                al_part[0][wv][lrow] = p1;
                al_part[1][wv][lrow] = p2;
            }
        }
    }
    __syncthreads();
    if (t < 64) {
        int node = base + t;
        if (node < n) {
            as_[node] = al_part[0][0][t] + al_part[0][1][t] + al_part[0][2][t] + al_part[0][3][t];
            ad_[node] = al_part[1][0][t] + al_part[1][1][t] + al_part[1][2][t] + al_part[1][3][t];
        }
    }
}

// ---------------- degree count + per-edge rank (coalesced write) ----------------
__global__ void k_deg(const int* __restrict__ ei, int* __restrict__ deg,
                      int* __restrict__ rank, int e) {
    int i = blockIdx.x * blockDim.x + threadIdx.x;
    int stride = gridDim.x * blockDim.x;
    for (; i < e; i += stride) {
        int d = ei[(size_t)e + i];
        rank[i] = atomicAdd(&deg[d], 1);
    }
}

// ---------------- exclusive scan (single block, 1024 threads) ----------------
__global__ __launch_bounds__(1024) void k_scan(const int* __restrict__ deg,
                                               int* __restrict__ off, int n) {
    __shared__ int wsum[16];
    __shared__ int carry_s;
    int t = threadIdx.x, lane = t & 63, wv = t >> 6;
    if (t == 0) carry_s = 0;
    __syncthreads();
    for (int base = 0; base < n; base += 1024) {
        int idx = base + t;
        int v = (idx < n) ? deg[idx] : 0;
        int x = v;
        #pragma unroll
        for (int i = 1; i < 64; i <<= 1) {
            int u = __shfl_up(x, i);
            if (lane >= i) x += u;
        }
        if (lane == 63) wsum[wv] = x;
        __syncthreads();
        int add = 0;
        for (int w = 0; w < wv; ++w) add += wsum[w];
        int carry = carry_s;
        __syncthreads();
        int incl = x + add;
        if (idx < n) off[idx] = carry + incl - v;
        if (t == 1023) carry_s = carry + incl;
        __syncthreads();
    }
    if (t == 0) off[n] = carry_s;
}

// ---------------- fill CSR (no atomics): edata[pos] = {src, leakyrelu(e)} ----
__global__ void k_fill(const int* __restrict__ ei, const float* __restrict__ as_,
                       const float* __restrict__ ad_, const int* __restrict__ off,
                       const int* __restrict__ rank, int2* __restrict__ edata,
                       int e, int lo, int hi) {
    int i = blockIdx.x * blockDim.x + threadIdx.x;
    int stride = gridDim.x * blockDim.x;
    for (; i < e; i += stride) {
        int d = ei[(size_t)e + i];
        if (d < lo || d >= hi) continue;
        int s = ei[i];
        float v = as_[s] + ad_[d];
        v = v > 0.f ? v : NEG_SLOPE * v;
        edata[off[d] + rank[i]] = make_int2(s, __float_as_int(v));
    }
}

// ---------------- softmax weights in-place on edata.y ----------------
__global__ __launch_bounds__(256) void k_gatw(const int* __restrict__ off,
                                              int2* __restrict__ edata, int n) {
    int lane = threadIdx.x & 63;
    int d = blockIdx.x * 4 + (threadIdx.x >> 6);
    if (d >= n) return;
    int beg = off[d], end = off[d + 1];
    float m = -3.0e38f;
    for (int i = beg + lane; i < end; i += 64)
        m = fmaxf(m, __int_as_float(edata[i].y));
    #pragma unroll
    for (int s = 32; s > 0; s >>= 1) m = fmaxf(m, __shfl_xor(m, s));

    int i0 = beg + lane;
    float e0 = 0.f, z = 0.f;
    if (i0 < end) { e0 = __expf(__int_as_float(edata[i0].y) - m); z = e0; }
    for (int i = i0 + 64; i < end; i += 64) {
        float e = __expf(__int_as_float(edata[i].y) - m);
        edata[i].y = __float_as_int(e);
        z += e;
    }
    #pragma unroll
    for (int s = 32; s > 0; s >>= 1) z += __shfl_xor(z, s);
    float rz = 1.f / (z + EPSV);
    if (i0 < end) edata[i0].y = __float_as_int(e0 * rz);
    for (int i = i0 + 64; i < end; i += 64)
        edata[i].y = __float_as_int(__int_as_float(edata[i].y) * rz);
}

// ---------------- weighted aggregate + elu -> h1 ----------------
__global__ __launch_bounds__(256) void k_gata(const int* __restrict__ off,
                                              const int2* __restrict__ edata,
                                              const float* __restrict__ h,
                                              float* __restrict__ h1, int n) {
    int lane = threadIdx.x & 63;
    int d = blockIdx.x * 4 + (threadIdx.x >> 6);
    if (d >= n) return;
    int beg = off[d], end = off[d + 1];
    float a0 = 0.f, a1 = 0.f, a2 = 0.f, a3 = 0.f;
    int i = beg;
    for (; i + 4 <= end; i += 4) {
        int2 e0 = edata[i],     e1 = edata[i + 1];
        int2 e2 = edata[i + 2], e3 = edata[i + 3];
        float v0 = h[(size_t)e0.x * 64 + lane];
        float v1 = h[(size_t)e1.x * 64 + lane];
        float v2 = h[(size_t)e2.x * 64 + lane];
        float v3 = h[(size_t)e3.x * 64 + lane];
        a0 += __int_as_float(e0.y) * v0;
        a1 += __int_as_float(e1.y) * v1;
        a2 += __int_as_float(e2.y) * v2;
        a3 += __int_as_float(e3.y) * v3;
    }
    for (; i < end; ++i) {
        int2 ed = edata[i];
        a0 += __int_as_float(ed.y) * h[(size_t)ed.x * 64 + lane];
    }
    h1[(size_t)d * 64 + lane] = eluf((a0 + a1) + (a2 + a3));
}

// ---------------- MLP stage A: h2 = h1 @ w2 (out0), h3 = elu(h2 @ l1w^T + b) ----
__global__ __launch_bounds__(256) void k_mlp_a(
    const float* __restrict__ h1g, const float* __restrict__ w2,
    const float* __restrict__ l1w, const float* __restrict__ l1b,
    float* __restrict__ oh2, float* __restrict__ h3, int n)
{
    __shared__ float h1s[256 * 68];
    int t = threadIdx.x;

    for (int base = blockIdx.x * 256; base < n; base += gridDim.x * 256) {
        __syncthreads();
        #pragma unroll
        for (int i = 0; i < 16; ++i) {
            int flat = t + 256 * i;
            int row = flat >> 4, c4 = flat & 15;
            int node = base + row;
            float4 v = (node < n) ? ((const float4*)h1g)[(size_t)node * 16 + c4]
                                  : make_float4(0.f, 0.f, 0.f, 0.f);
            *(float4*)&h1s[row * 68 + c4 * 4] = v;
        }
        __syncthreads();

        int node = base + t;
        const float* hrow = &h1s[t * 68];

        float acc2[32];
        #pragma unroll
        for (int o = 0; o < 32; ++o) acc2[o] = 0.f;
        #pragma unroll 4
        for (int j = 0; j < 64; ++j) {
            float hj = hrow[j];
            #pragma unroll
            for (int o = 0; o < 32; ++o) acc2[o] += hj * w2[j * 32 + o];
        }
        if (node < n) {
            #pragma unroll
            for (int o4 = 0; o4 < 8; ++o4) {
                float4 v = make_float4(acc2[o4 * 4], acc2[o4 * 4 + 1],
                                       acc2[o4 * 4 + 2], acc2[o4 * 4 + 3]);
                ((float4*)oh2)[(size_t)node * 8 + o4] = v;
            }
        }

        #pragma unroll 2
        for (int j4 = 0; j4 < 16; ++j4) {
            float hv[4];
            #pragma unroll
            for (int jj = 0; jj < 4; ++jj) {
                int j = j4 * 4 + jj;
                float a = l1b[j];
                #pragma unroll
                for (int o = 0; o < 32; ++o) a += acc2[o] * l1w[j * 32 + o];
                hv[jj] = eluf(a);
            }
            if (node < n) {
                float4 v = make_float4(hv[0], hv[1], hv[2], hv[3]);
                ((float4*)h3)[(size_t)node * 16 + j4] = v;
            }
        }
    }
}

// ---------------- MLP stage B: h4 = h3 @ l2w^T + l2b via bf16-split MFMA ----
// 64-node tile/block; wave wv owns cols [wv*64, wv*64+64) as 4x16-col tiles.
// l2w^T fragments resident in VGPRs; h3 fragments straight from global.
__global__ __launch_bounds__(256) void k_mlp_b_mfma(
    const float* __restrict__ h3, const float* __restrict__ l2w,
    const float* __restrict__ l2b, float* __restrict__ oh4, int n)
{
    typedef __attribute__((ext_vector_type(8))) short bx8;
    typedef __attribute__((ext_vector_type(4))) float fx4;

    int t = threadIdx.x, lane = t & 63, wv = t >> 6;
    int base = blockIdx.x * 64;

    // B fragments: B[k][col] = l2w[col*64 + k]; k contiguous -> float4 loads
    bx8 bhi[4][2], blo[4][2];
    float bias[4];
    #pragma unroll
    for (int ct = 0; ct < 4; ++ct) {
        int col = wv * 64 + ct * 16 + (lane & 15);
        bias[ct] = l2b[col];
        const float* wp = l2w + (size_t)col * 64 + (lane >> 4) * 8;
        #pragma unroll
        for (int ks = 0; ks < 2; ++ks) {
            float4 w0 = *(const float4*)(wp + ks * 32);
            float4 w1 = *(const float4*)(wp + ks * 32 + 4);
            float ff[8] = { w0.x, w0.y, w0.z, w0.w, w1.x, w1.y, w1.z, w1.w };
            #pragma unroll
            for (int i = 0; i < 8; ++i) {
                unsigned short hb = f32_to_bf16_rne(ff[i]);
                float rem = ff[i] - bf16_bits_to_f32(hb);
                bhi[ct][ks][i] = (short)hb;
                blo[ct][ks][i] = (short)f32_to_bf16_rne(rem);
            }
        }
    }

    #pragma unroll
    for (int mt = 0; mt < 4; ++mt) {
        // A fragment for this 16-row tile, straight from global
        int row = base + mt * 16 + (lane & 15);
        const float* hp = h3 + (size_t)row * 64 + (lane >> 4) * 8;
        bx8 ahi[2], alo[2];
        #pragma unroll
        for (int ks = 0; ks < 2; ++ks) {
            float4 a0, a1;
            if (row < n) {
                a0 = *(const float4*)(hp + ks * 32);
                a1 = *(const float4*)(hp + ks * 32 + 4);
            } else {
                a0 = make_float4(0.f, 0.f, 0.f, 0.f);
                a1 = make_float4(0.f, 0.f, 0.f, 0.f);
            }
            float ff[8] = { a0.x, a0.y, a0.z, a0.w, a1.x, a1.y, a1.z, a1.w };
            #pragma unroll
            for (int i = 0; i < 8; ++i) {
                unsigned short hb = f32_to_bf16_rne(ff[i]);
                float rem = ff[i] - bf16_bits_to_f32(hb);
                ahi[ks][i] = (short)hb;
                alo[ks][i] = (short)f32_to_bf16_rne(rem);
            }
        }

        fx4 acc[4];
        #pragma unroll
        for (int ct = 0; ct < 4; ++ct) acc[ct] = (fx4){0.f, 0.f, 0.f, 0.f};
        #pragma unroll
        for (int ct = 0; ct < 4; ++ct) {
            #pragma unroll
            for (int ks = 0; ks < 2; ++ks) {
                acc[ct] = __builtin_amdgcn_mfma_f32_16x16x32_bf16(ahi[ks], bhi[ct][ks], acc[ct], 0, 0, 0);
                acc[ct] = __builtin_amdgcn_mfma_f32_16x16x32_bf16(ahi[ks], blo[ct][ks], acc[ct], 0, 0, 0);
                acc[ct] = __builtin_amdgcn_mfma_f32_16x16x32_bf16(alo[ks], bhi[ct][ks], acc[ct], 0, 0, 0);
            }
        }

        // store: row = (lane>>4)*4 + r within tile, col = ct*16 + (lane&15)
        #pragma unroll
        for (int ct = 0; ct < 4; ++ct) {
            #pragma unroll
            for (int r = 0; r < 4; ++r) {
                int orow = base + mt * 16 + (lane >> 4) * 4 + r;
                if (orow < n) {
                    int ocol = wv * 64 + ct * 16 + (lane & 15);
                    oh4[(size_t)orow * 256 + ocol] = acc[ct][r] + bias[ct];
                }
            }
        }
    }
}

extern "C" void kernel_launch(void* const* d_in, const int* in_sizes, int n_in,
                              void* d_out, int out_size, void* d_ws, size_t ws_size,
                              hipStream_t stream) {
    const float* feat    = (const float*)d_in[0];
    const int*   ei      = (const int*)d_in[1];     // int64 in ref -> int32 on device
    const float* w1      = (const float*)d_in[2];
    const float* att_src = (const float*)d_in[3];
    const float* att_dst = (const float*)d_in[4];
    const float* w2      = (const float*)d_in[5];
    const float* l1w     = (const float*)d_in[6];
    const float* l1b     = (const float*)d_in[7];
    const float* l2w     = (const float*)d_in[8];
    const float* l2b     = (const float*)d_in[9];

    const int N = in_sizes[0] / IN_DIM;
    const int E = in_sizes[1] / 2;

    char* p = (char*)d_ws;
    auto alloc = [&](size_t bytes) {
        char* r = p;
        p += (bytes + 255) & ~(size_t)255;
        return r;
    };
    float* h     = (float*)alloc((size_t)N * HID * 4);   // reused as h3 after k_gata
    float* h1g   = (float*)alloc((size_t)N * HID * 4);
    float* as_   = (float*)alloc((size_t)N * 4);
    float* ad_   = (float*)alloc((size_t)N * 4);
    int*   deg   = (int*)alloc((size_t)N * 4);
    int*   off   = (int*)alloc((size_t)(N + 1) * 4);
    int*   rank  = (int*)alloc((size_t)E * 4);
    int2*  edata = (int2*)alloc((size_t)E * 8);

    float* oh2 = (float*)d_out;
    float* oh4 = oh2 + (size_t)N * OUTD;
    float* h3  = h;   // h is dead after k_gata

    hipLaunchKernelGGL(k_init, dim3(256), dim3(256), 0, stream, deg, N);
    hipLaunchKernelGGL(k_feat_mfma, dim3((N + 63) / 64), dim3(256), 0, stream,
                       feat, w1, att_src, att_dst, h, as_, ad_, N);
    hipLaunchKernelGGL(k_deg, dim3(2048), dim3(256), 0, stream, ei, deg, rank, E);
    hipLaunchKernelGGL(k_scan, dim3(1), dim3(1024), 0, stream, deg, off, N);
    for (int pass = 0; pass < 4; ++pass) {
        int lo = (int)((size_t)N * pass / 4);
        int hi = (int)((size_t)N * (pass + 1) / 4);
        hipLaunchKernelGGL(k_fill, dim3(2048), dim3(256), 0, stream,
                           ei, as_, ad_, off, rank, edata, E, lo, hi);
    }
    hipLaunchKernelGGL(k_gatw, dim3((N + 3) / 4), dim3(256), 0, stream, off, edata, N);
    hipLaunchKernelGGL(k_gata, dim3((N + 3) / 4), dim3(256), 0, stream,
                       off, edata, h, h1g, N);
    hipLaunchKernelGGL(k_mlp_a, dim3((N + 255) / 256), dim3(256), 0, stream,
                       h1g, w2, l1w, l1b, oh2, h3, N);
    hipLaunchKernelGGL(k_mlp_b_mfma, dim3((N + 63) / 64), dim3(256), 0, stream,
                       h3, l2w, l2b, oh4, N);
}

// Round 9
// 379.026 us; speedup vs baseline: 2.3648x; 1.2393x over previous
//
#include <hip/hip_runtime.h>
#include <math.h>

constexpr int IN_DIM = 256;
constexpr int HID    = 64;
constexpr int OUTD   = 32;
#define NEG_SLOPE 0.2f
#define EPSV 1e-16f

__device__ __forceinline__ float eluf(float x) {
    return x > 0.f ? x : expm1f(x);
}

__device__ __forceinline__ unsigned short f32_to_bf16_rne(float f) {
    unsigned u = __float_as_uint(f);
    unsigned r = u + 0x7fffu + ((u >> 16) & 1u);
    return (unsigned short)(r >> 16);
}
__device__ __forceinline__ float bf16_bits_to_f32(unsigned short s) {
    return __uint_as_float(((unsigned)s) << 16);
}

// ---------------- init: zero deg ----------------
__global__ void k_init(int* __restrict__ deg, int n) {
    int i = blockIdx.x * blockDim.x + threadIdx.x;
    int stride = gridDim.x * blockDim.x;
    for (; i < n; i += stride) deg[i] = 0;
}

// ---------------- h = feat @ w1 via bf16-split MFMA; alphas fused ----------------
__global__ __launch_bounds__(256) void k_feat_mfma(
    const float* __restrict__ feat, const float* __restrict__ w1,
    const float* __restrict__ att_src, const float* __restrict__ att_dst,
    float* __restrict__ h, float* __restrict__ as_, float* __restrict__ ad_, int n)
{
    typedef __attribute__((ext_vector_type(8))) short bx8;
    typedef __attribute__((ext_vector_type(4))) float fx4;

    __shared__ short a_hi[4 * 8 * 64 * 8];   // 32 KB
    __shared__ short a_lo[4 * 8 * 64 * 8];   // 32 KB
    __shared__ float al_part[2][4][64];

    int t = threadIdx.x, lane = t & 63, wv = t >> 6;
    int base = blockIdx.x * 64;

    // ---- B (w1) fragments -> registers, hi/lo split ----
    bx8 bhi[8], blo[8];
    {
        int nj = wv * 16 + (lane & 15);
        int kg = (lane >> 4) * 8;
        #pragma unroll
        for (int ks = 0; ks < 8; ++ks) {
            #pragma unroll
            for (int i = 0; i < 8; ++i) {
                float f = w1[(size_t)(ks * 32 + kg + i) * 64 + nj];
                unsigned short hb = f32_to_bf16_rne(f);
                float rem = f - bf16_bits_to_f32(hb);
                bhi[ks][i] = (short)hb;
                blo[ks][i] = (short)f32_to_bf16_rne(rem);
            }
        }
    }

    // ---- stage A (feat) tile ----
    float4 v[16];
    #pragma unroll
    for (int c = 0; c < 8; ++c) {
        int node = (t >> 5) + c * 8;
        int oct = t & 31;
        int gn = base + node;
        if (gn < n) {
            const float4* fp = (const float4*)(feat + (size_t)gn * 256);
            v[2 * c]     = fp[oct * 2];
            v[2 * c + 1] = fp[oct * 2 + 1];
        } else {
            v[2 * c]     = make_float4(0.f, 0.f, 0.f, 0.f);
            v[2 * c + 1] = make_float4(0.f, 0.f, 0.f, 0.f);
        }
    }
    #pragma unroll
    for (int c = 0; c < 8; ++c) {
        int node = (t >> 5) + c * 8;
        int oct = t & 31;
        int mt = node >> 4, lm = node & 15;
        int ks = oct >> 2, lg = oct & 3;
        int flane = lg * 16 + lm;
        int idx = (((mt * 8 + ks) * 64) + (flane ^ ks)) * 8;
        float ff[8] = { v[2*c].x, v[2*c].y, v[2*c].z, v[2*c].w,
                        v[2*c+1].x, v[2*c+1].y, v[2*c+1].z, v[2*c+1].w };
        bx8 hv, lv;
        #pragma unroll
        for (int i = 0; i < 8; ++i) {
            unsigned short hb = f32_to_bf16_rne(ff[i]);
            float rem = ff[i] - bf16_bits_to_f32(hb);
            hv[i] = (short)hb;
            lv[i] = (short)f32_to_bf16_rne(rem);
        }
        *(bx8*)&a_hi[idx] = hv;
        *(bx8*)&a_lo[idx] = lv;
    }
    __syncthreads();

    // ---- MFMA K-loop ----
    fx4 acc[4];
    #pragma unroll
    for (int mt = 0; mt < 4; ++mt) acc[mt] = (fx4){0.f, 0.f, 0.f, 0.f};
    #pragma unroll
    for (int mt = 0; mt < 4; ++mt) {
        #pragma unroll
        for (int ks = 0; ks < 8; ++ks) {
            int idx = (((mt * 8 + ks) * 64) + (lane ^ ks)) * 8;
            bx8 ah = *(bx8*)&a_hi[idx];
            bx8 al = *(bx8*)&a_lo[idx];
            acc[mt] = __builtin_amdgcn_mfma_f32_16x16x32_bf16(ah, bhi[ks], acc[mt], 0, 0, 0);
            acc[mt] = __builtin_amdgcn_mfma_f32_16x16x32_bf16(ah, blo[ks], acc[mt], 0, 0, 0);
            acc[mt] = __builtin_amdgcn_mfma_f32_16x16x32_bf16(al, bhi[ks], acc[mt], 0, 0, 0);
        }
    }

    // ---- epilogue ----
    float asj = att_src[wv * 16 + (lane & 15)];
    float adj = att_dst[wv * 16 + (lane & 15)];
    #pragma unroll
    for (int mt = 0; mt < 4; ++mt) {
        #pragma unroll
        for (int r = 0; r < 4; ++r) {
            int lrow = mt * 16 + (lane >> 4) * 4 + r;
            int node = base + lrow;
            float hv = acc[mt][r];
            if (node < n) h[(size_t)node * 64 + wv * 16 + (lane & 15)] = hv;
            float p1 = hv * asj, p2 = hv * adj;
            p1 += __shfl_xor(p1, 1);  p2 += __shfl_xor(p2, 1);
            p1 += __shfl_xor(p1, 2);  p2 += __shfl_xor(p2, 2);
            p1 += __shfl_xor(p1, 4);  p2 += __shfl_xor(p2, 4);
            p1 += __shfl_xor(p1, 8);  p2 += __shfl_xor(p2, 8);
            if ((lane & 15) == 0) {
                al_part[0][wv][lrow] = p1;
                al_part[1][wv][lrow] = p2;
            }
        }
    }
    __syncthreads();
    if (t < 64) {
        int node = base + t;
        if (node < n) {
            as_[node] = al_part[0][0][t] + al_part[0][1][t] + al_part[0][2][t] + al_part[0][3][t];
            ad_[node] = al_part[1][0][t] + al_part[1][1][t] + al_part[1][2][t] + al_part[1][3][t];
        }
    }
}

// ---------------- degree count + per-edge rank (coalesced write) ----------------
__global__ void k_deg(const int* __restrict__ ei, int* __restrict__ deg,
                      int* __restrict__ rank, int e) {
    int i = blockIdx.x * blockDim.x + threadIdx.x;
    int stride = gridDim.x * blockDim.x;
    for (; i < e; i += stride) {
        int d = ei[(size_t)e + i];
        rank[i] = atomicAdd(&deg[d], 1);
    }
}

// ---------------- multi-block exclusive scan, 3 phases ----------------
// Phase 1: block-local sums -> part[b]
__global__ __launch_bounds__(1024) void k_scan_part(const int* __restrict__ deg,
                                                    int* __restrict__ part, int n) {
    __shared__ int wlds[16];
    int t = threadIdx.x, lane = t & 63, wv = t >> 6;
    int idx = blockIdx.x * 1024 + t;
    int v = (idx < n) ? deg[idx] : 0;
    #pragma unroll
    for (int s = 32; s > 0; s >>= 1) v += __shfl_xor(v, s);
    if (lane == 0) wlds[wv] = v;
    __syncthreads();
    if (t == 0) {
        int s = 0;
        #pragma unroll
        for (int w = 0; w < 16; ++w) s += wlds[w];
        part[blockIdx.x] = s;
    }
}

// Phase 2: single block exclusive-scans part[0..nb) in place; writes off[n]=total
__global__ __launch_bounds__(1024) void k_scan_top(int* __restrict__ part,
                                                   int* __restrict__ off,
                                                   int nb, int n) {
    __shared__ int wsum[16];
    int t = threadIdx.x, lane = t & 63, wv = t >> 6;
    int v = (t < nb) ? part[t] : 0;
    int x = v;
    #pragma unroll
    for (int i = 1; i < 64; i <<= 1) {
        int u = __shfl_up(x, i);
        if (lane >= i) x += u;
    }
    if (lane == 63) wsum[wv] = x;
    __syncthreads();
    int add = 0;
    for (int w = 0; w < wv; ++w) add += wsum[w];
    if (t < nb) part[t] = x - v + add;
    if (t == nb - 1) off[n] = x + add;
}

// Phase 3: block-local exclusive scan + part offset -> off[idx]
__global__ __launch_bounds__(1024) void k_scan_down(const int* __restrict__ deg,
                                                    const int* __restrict__ part,
                                                    int* __restrict__ off, int n) {
    __shared__ int wsum[16];
    int t = threadIdx.x, lane = t & 63, wv = t >> 6;
    int idx = blockIdx.x * 1024 + t;
    int v = (idx < n) ? deg[idx] : 0;
    int x = v;
    #pragma unroll
    for (int i = 1; i < 64; i <<= 1) {
        int u = __shfl_up(x, i);
        if (lane >= i) x += u;
    }
    if (lane == 63) wsum[wv] = x;
    __syncthreads();
    int add = 0;
    for (int w = 0; w < wv; ++w) add += wsum[w];
    if (idx < n) off[idx] = x - v + add + part[blockIdx.x];
}

// ---------------- fill CSR (no atomics): edata[pos] = {src, leakyrelu(e)} ----
__global__ void k_fill(const int* __restrict__ ei, const float* __restrict__ as_,
                       const float* __restrict__ ad_, const int* __restrict__ off,
                       const int* __restrict__ rank, int2* __restrict__ edata,
                       int e, int lo, int hi) {
    int i = blockIdx.x * blockDim.x + threadIdx.x;
    int stride = gridDim.x * blockDim.x;
    for (; i < e; i += stride) {
        int d = ei[(size_t)e + i];
        if (d < lo || d >= hi) continue;
        int s = ei[i];
        float v = as_[s] + ad_[d];
        v = v > 0.f ? v : NEG_SLOPE * v;
        edata[off[d] + rank[i]] = make_int2(s, __float_as_int(v));
    }
}

// ---------------- softmax weights in-place on edata.y ----------------
__global__ __launch_bounds__(256) void k_gatw(const int* __restrict__ off,
                                              int2* __restrict__ edata, int n) {
    int lane = threadIdx.x & 63;
    int d = blockIdx.x * 4 + (threadIdx.x >> 6);
    if (d >= n) return;
    int beg = off[d], end = off[d + 1];
    float m = -3.0e38f;
    for (int i = beg + lane; i < end; i += 64)
        m = fmaxf(m, __int_as_float(edata[i].y));
    #pragma unroll
    for (int s = 32; s > 0; s >>= 1) m = fmaxf(m, __shfl_xor(m, s));

    int i0 = beg + lane;
    float e0 = 0.f, z = 0.f;
    if (i0 < end) { e0 = __expf(__int_as_float(edata[i0].y) - m); z = e0; }
    for (int i = i0 + 64; i < end; i += 64) {
        float e = __expf(__int_as_float(edata[i].y) - m);
        edata[i].y = __float_as_int(e);
        z += e;
    }
    #pragma unroll
    for (int s = 32; s > 0; s >>= 1) z += __shfl_xor(z, s);
    float rz = 1.f / (z + EPSV);
    if (i0 < end) edata[i0].y = __float_as_int(e0 * rz);
    for (int i = i0 + 64; i < end; i += 64)
        edata[i].y = __float_as_int(__int_as_float(edata[i].y) * rz);
}

// ---------------- weighted aggregate + elu -> h1 ----------------
__global__ __launch_bounds__(256) void k_gata(const int* __restrict__ off,
                                              const int2* __restrict__ edata,
                                              const float* __restrict__ h,
                                              float* __restrict__ h1, int n) {
    int lane = threadIdx.x & 63;
    int d = blockIdx.x * 4 + (threadIdx.x >> 6);
    if (d >= n) return;
    int beg = off[d], end = off[d + 1];
    float a0 = 0.f, a1 = 0.f, a2 = 0.f, a3 = 0.f;
    int i = beg;
    for (; i + 4 <= end; i += 4) {
        int2 e0 = edata[i],     e1 = edata[i + 1];
        int2 e2 = edata[i + 2], e3 = edata[i + 3];
        float v0 = h[(size_t)e0.x * 64 + lane];
        float v1 = h[(size_t)e1.x * 64 + lane];
        float v2 = h[(size_t)e2.x * 64 + lane];
        float v3 = h[(size_t)e3.x * 64 + lane];
        a0 += __int_as_float(e0.y) * v0;
        a1 += __int_as_float(e1.y) * v1;
        a2 += __int_as_float(e2.y) * v2;
        a3 += __int_as_float(e3.y) * v3;
    }
    for (; i < end; ++i) {
        int2 ed = edata[i];
        a0 += __int_as_float(ed.y) * h[(size_t)ed.x * 64 + lane];
    }
    h1[(size_t)d * 64 + lane] = eluf((a0 + a1) + (a2 + a3));
}

// ---------------- MLP stage A: h2 = h1 @ w2 (out0), h3 = elu(h2 @ l1w^T + b) ----
__global__ __launch_bounds__(256) void k_mlp_a(
    const float* __restrict__ h1g, const float* __restrict__ w2,
    const float* __restrict__ l1w, const float* __restrict__ l1b,
    float* __restrict__ oh2, float* __restrict__ h3, int n)
{
    __shared__ float h1s[256 * 68];
    int t = threadIdx.x;

    for (int base = blockIdx.x * 256; base < n; base += gridDim.x * 256) {
        __syncthreads();
        #pragma unroll
        for (int i = 0; i < 16; ++i) {
            int flat = t + 256 * i;
            int row = flat >> 4, c4 = flat & 15;
            int node = base + row;
            float4 v = (node < n) ? ((const float4*)h1g)[(size_t)node * 16 + c4]
                                  : make_float4(0.f, 0.f, 0.f, 0.f);
            *(float4*)&h1s[row * 68 + c4 * 4] = v;
        }
        __syncthreads();

        int node = base + t;
        const float* hrow = &h1s[t * 68];

        float acc2[32];
        #pragma unroll
        for (int o = 0; o < 32; ++o) acc2[o] = 0.f;
        #pragma unroll 4
        for (int j = 0; j < 64; ++j) {
            float hj = hrow[j];
            #pragma unroll
            for (int o = 0; o < 32; ++o) acc2[o] += hj * w2[j * 32 + o];
        }
        if (node < n) {
            #pragma unroll
            for (int o4 = 0; o4 < 8; ++o4) {
                float4 v = make_float4(acc2[o4 * 4], acc2[o4 * 4 + 1],
                                       acc2[o4 * 4 + 2], acc2[o4 * 4 + 3]);
                ((float4*)oh2)[(size_t)node * 8 + o4] = v;
            }
        }

        #pragma unroll 2
        for (int j4 = 0; j4 < 16; ++j4) {
            float hv[4];
            #pragma unroll
            for (int jj = 0; jj < 4; ++jj) {
                int j = j4 * 4 + jj;
                float a = l1b[j];
                #pragma unroll
                for (int o = 0; o < 32; ++o) a += acc2[o] * l1w[j * 32 + o];
                hv[jj] = eluf(a);
            }
            if (node < n) {
                float4 v = make_float4(hv[0], hv[1], hv[2], hv[3]);
                ((float4*)h3)[(size_t)node * 16 + j4] = v;
            }
        }
    }
}

// ---------------- MLP stage B: h4 = h3 @ l2w^T + l2b via bf16-split MFMA ----
__global__ __launch_bounds__(256) void k_mlp_b_mfma(
    const float* __restrict__ h3, const float* __restrict__ l2w,
    const float* __restrict__ l2b, float* __restrict__ oh4, int n)
{
    typedef __attribute__((ext_vector_type(8))) short bx8;
    typedef __attribute__((ext_vector_type(4))) float fx4;

    int t = threadIdx.x, lane = t & 63, wv = t >> 6;
    int base = blockIdx.x * 64;

    // B fragments: B[k][col] = l2w[col*64 + k]; k contiguous -> float4 loads
    bx8 bhi[4][2], blo[4][2];
    float bias[4];
    #pragma unroll
    for (int ct = 0; ct < 4; ++ct) {
        int col = wv * 64 + ct * 16 + (lane & 15);
        bias[ct] = l2b[col];
        const float* wp = l2w + (size_t)col * 64 + (lane >> 4) * 8;
        #pragma unroll
        for (int ks = 0; ks < 2; ++ks) {
            float4 w0 = *(const float4*)(wp + ks * 32);
            float4 w1 = *(const float4*)(wp + ks * 32 + 4);
            float ff[8] = { w0.x, w0.y, w0.z, w0.w, w1.x, w1.y, w1.z, w1.w };
            #pragma unroll
            for (int i = 0; i < 8; ++i) {
                unsigned short hb = f32_to_bf16_rne(ff[i]);
                float rem = ff[i] - bf16_bits_to_f32(hb);
                bhi[ct][ks][i] = (short)hb;
                blo[ct][ks][i] = (short)f32_to_bf16_rne(rem);
            }
        }
    }

    #pragma unroll
    for (int mt = 0; mt < 4; ++mt) {
        int row = base + mt * 16 + (lane & 15);
        const float* hp = h3 + (size_t)row * 64 + (lane >> 4) * 8;
        bx8 ahi[2], alo[2];
        #pragma unroll
        for (int ks = 0; ks < 2; ++ks) {
            float4 a0, a1;
            if (row < n) {
                a0 = *(const float4*)(hp + ks * 32);
                a1 = *(const float4*)(hp + ks * 32 + 4);
            } else {
                a0 = make_float4(0.f, 0.f, 0.f, 0.f);
                a1 = make_float4(0.f, 0.f, 0.f, 0.f);
            }
            float ff[8] = { a0.x, a0.y, a0.z, a0.w, a1.x, a1.y, a1.z, a1.w };
            #pragma unroll
            for (int i = 0; i < 8; ++i) {
                unsigned short hb = f32_to_bf16_rne(ff[i]);
                float rem = ff[i] - bf16_bits_to_f32(hb);
                ahi[ks][i] = (short)hb;
                alo[ks][i] = (short)f32_to_bf16_rne(rem);
            }
        }

        fx4 acc[4];
        #pragma unroll
        for (int ct = 0; ct < 4; ++ct) acc[ct] = (fx4){0.f, 0.f, 0.f, 0.f};
        #pragma unroll
        for (int ct = 0; ct < 4; ++ct) {
            #pragma unroll
            for (int ks = 0; ks < 2; ++ks) {
                acc[ct] = __builtin_amdgcn_mfma_f32_16x16x32_bf16(ahi[ks], bhi[ct][ks], acc[ct], 0, 0, 0);
                acc[ct] = __builtin_amdgcn_mfma_f32_16x16x32_bf16(ahi[ks], blo[ct][ks], acc[ct], 0, 0, 0);
                acc[ct] = __builtin_amdgcn_mfma_f32_16x16x32_bf16(alo[ks], bhi[ct][ks], acc[ct], 0, 0, 0);
            }
        }

        #pragma unroll
        for (int ct = 0; ct < 4; ++ct) {
            #pragma unroll
            for (int r = 0; r < 4; ++r) {
                int orow = base + mt * 16 + (lane >> 4) * 4 + r;
                if (orow < n) {
                    int ocol = wv * 64 + ct * 16 + (lane & 15);
                    oh4[(size_t)orow * 256 + ocol] = acc[ct][r] + bias[ct];
                }
            }
        }
    }
}

extern "C" void kernel_launch(void* const* d_in, const int* in_sizes, int n_in,
                              void* d_out, int out_size, void* d_ws, size_t ws_size,
                              hipStream_t stream) {
    const float* feat    = (const float*)d_in[0];
    const int*   ei      = (const int*)d_in[1];     // int64 in ref -> int32 on device
    const float* w1      = (const float*)d_in[2];
    const float* att_src = (const float*)d_in[3];
    const float* att_dst = (const float*)d_in[4];
    const float* w2      = (const float*)d_in[5];
    const float* l1w     = (const float*)d_in[6];
    const float* l1b     = (const float*)d_in[7];
    const float* l2w     = (const float*)d_in[8];
    const float* l2b     = (const float*)d_in[9];

    const int N = in_sizes[0] / IN_DIM;
    const int E = in_sizes[1] / 2;

    char* p = (char*)d_ws;
    auto alloc = [&](size_t bytes) {
        char* r = p;
        p += (bytes + 255) & ~(size_t)255;
        return r;
    };
    float* h     = (float*)alloc((size_t)N * HID * 4);   // reused as h3 after k_gata
    float* h1g   = (float*)alloc((size_t)N * HID * 4);
    float* as_   = (float*)alloc((size_t)N * 4);
    float* ad_   = (float*)alloc((size_t)N * 4);
    int*   deg   = (int*)alloc((size_t)N * 4);
    int*   off   = (int*)alloc((size_t)(N + 1) * 4);
    int*   rank  = (int*)alloc((size_t)E * 4);
    int2*  edata = (int2*)alloc((size_t)E * 8);
    const int nb = (N + 1023) / 1024;
    int*   part  = (int*)alloc((size_t)nb * 4);

    float* oh2 = (float*)d_out;
    float* oh4 = oh2 + (size_t)N * OUTD;
    float* h3  = h;   // h is dead after k_gata

    hipLaunchKernelGGL(k_init, dim3(256), dim3(256), 0, stream, deg, N);
    hipLaunchKernelGGL(k_feat_mfma, dim3((N + 63) / 64), dim3(256), 0, stream,
                       feat, w1, att_src, att_dst, h, as_, ad_, N);
    hipLaunchKernelGGL(k_deg, dim3(2048), dim3(256), 0, stream, ei, deg, rank, E);
    hipLaunchKernelGGL(k_scan_part, dim3(nb), dim3(1024), 0, stream, deg, part, N);
    hipLaunchKernelGGL(k_scan_top, dim3(1), dim3(1024), 0, stream, part, off, nb, N);
    hipLaunchKernelGGL(k_scan_down, dim3(nb), dim3(1024), 0, stream, deg, part, off, N);
    for (int pass = 0; pass < 4; ++pass) {
        int lo = (int)((size_t)N * pass / 4);
        int hi = (int)((size_t)N * (pass + 1) / 4);
        hipLaunchKernelGGL(k_fill, dim3(2048), dim3(256), 0, stream,
                           ei, as_, ad_, off, rank, edata, E, lo, hi);
    }
    hipLaunchKernelGGL(k_gatw, dim3((N + 3) / 4), dim3(256), 0, stream, off, edata, N);
    hipLaunchKernelGGL(k_gata, dim3((N + 3) / 4), dim3(256), 0, stream,
                       off, edata, h, h1g, N);
    hipLaunchKernelGGL(k_mlp_a, dim3((N + 255) / 256), dim3(256), 0, stream,
                       h1g, w2, l1w, l1b, oh2, h3, N);
    hipLaunchKernelGGL(k_mlp_b_mfma, dim3((N + 63) / 64), dim3(256), 0, stream,
                       h3, l2w, l2b, oh4, N);
}

// Round 11
// 334.038 us; speedup vs baseline: 2.6833x; 1.1347x over previous
//
#include <hip/hip_runtime.h>
#include <math.h>

constexpr int IN_DIM = 256;
constexpr int HID    = 64;
constexpr int OUTD   = 32;
#define NEG_SLOPE 0.2f
#define EPSV 1e-16f

__device__ __forceinline__ float eluf(float x) {
    return x > 0.f ? x : expm1f(x);
}

__device__ __forceinline__ unsigned short f32_to_bf16_rne(float f) {
    unsigned u = __float_as_uint(f);
    unsigned r = u + 0x7fffu + ((u >> 16) & 1u);
    return (unsigned short)(r >> 16);
}
__device__ __forceinline__ float bf16_bits_to_f32(unsigned short s) {
    return __uint_as_float(((unsigned)s) << 16);
}

// ---------------- init: zero deg ----------------
__global__ void k_init(int* __restrict__ deg, int n) {
    int i = blockIdx.x * blockDim.x + threadIdx.x;
    int stride = gridDim.x * blockDim.x;
    for (; i < n; i += stride) deg[i] = 0;
}

// ---------------- h = feat @ w1 via bf16-split MFMA; alphas fused ----------------
__global__ __launch_bounds__(256) void k_feat_mfma(
    const float* __restrict__ feat, const float* __restrict__ w1,
    const float* __restrict__ att_src, const float* __restrict__ att_dst,
    float* __restrict__ h, float* __restrict__ as_, float* __restrict__ ad_, int n)
{
    typedef __attribute__((ext_vector_type(8))) short bx8;
    typedef __attribute__((ext_vector_type(4))) float fx4;

    __shared__ short a_hi[4 * 8 * 64 * 8];   // 32 KB
    __shared__ short a_lo[4 * 8 * 64 * 8];   // 32 KB
    __shared__ float al_part[2][4][64];

    int t = threadIdx.x, lane = t & 63, wv = t >> 6;
    int base = blockIdx.x * 64;

    // ---- B (w1) fragments -> registers, hi/lo split ----
    bx8 bhi[8], blo[8];
    {
        int nj = wv * 16 + (lane & 15);
        int kg = (lane >> 4) * 8;
        #pragma unroll
        for (int ks = 0; ks < 8; ++ks) {
            #pragma unroll
            for (int i = 0; i < 8; ++i) {
                float f = w1[(size_t)(ks * 32 + kg + i) * 64 + nj];
                unsigned short hb = f32_to_bf16_rne(f);
                float rem = f - bf16_bits_to_f32(hb);
                bhi[ks][i] = (short)hb;
                blo[ks][i] = (short)f32_to_bf16_rne(rem);
            }
        }
    }

    // ---- stage A (feat) tile ----
    float4 v[16];
    #pragma unroll
    for (int c = 0; c < 8; ++c) {
        int node = (t >> 5) + c * 8;
        int oct = t & 31;
        int gn = base + node;
        if (gn < n) {
            const float4* fp = (const float4*)(feat + (size_t)gn * 256);
            v[2 * c]     = fp[oct * 2];
            v[2 * c + 1] = fp[oct * 2 + 1];
        } else {
            v[2 * c]     = make_float4(0.f, 0.f, 0.f, 0.f);
            v[2 * c + 1] = make_float4(0.f, 0.f, 0.f, 0.f);
        }
    }
    #pragma unroll
    for (int c = 0; c < 8; ++c) {
        int node = (t >> 5) + c * 8;
        int oct = t & 31;
        int mt = node >> 4, lm = node & 15;
        int ks = oct >> 2, lg = oct & 3;
        int flane = lg * 16 + lm;
        int idx = (((mt * 8 + ks) * 64) + (flane ^ ks)) * 8;
        float ff[8] = { v[2*c].x, v[2*c].y, v[2*c].z, v[2*c].w,
                        v[2*c+1].x, v[2*c+1].y, v[2*c+1].z, v[2*c+1].w };
        bx8 hv, lv;
        #pragma unroll
        for (int i = 0; i < 8; ++i) {
            unsigned short hb = f32_to_bf16_rne(ff[i]);
            float rem = ff[i] - bf16_bits_to_f32(hb);
            hv[i] = (short)hb;
            lv[i] = (short)f32_to_bf16_rne(rem);
        }
        *(bx8*)&a_hi[idx] = hv;
        *(bx8*)&a_lo[idx] = lv;
    }
    __syncthreads();

    // ---- MFMA K-loop ----
    fx4 acc[4];
    #pragma unroll
    for (int mt = 0; mt < 4; ++mt) acc[mt] = (fx4){0.f, 0.f, 0.f, 0.f};
    #pragma unroll
    for (int mt = 0; mt < 4; ++mt) {
        #pragma unroll
        for (int ks = 0; ks < 8; ++ks) {
            int idx = (((mt * 8 + ks) * 64) + (lane ^ ks)) * 8;
            bx8 ah = *(bx8*)&a_hi[idx];
            bx8 al = *(bx8*)&a_lo[idx];
            acc[mt] = __builtin_amdgcn_mfma_f32_16x16x32_bf16(ah, bhi[ks], acc[mt], 0, 0, 0);
            acc[mt] = __builtin_amdgcn_mfma_f32_16x16x32_bf16(ah, blo[ks], acc[mt], 0, 0, 0);
            acc[mt] = __builtin_amdgcn_mfma_f32_16x16x32_bf16(al, bhi[ks], acc[mt], 0, 0, 0);
        }
    }

    // ---- epilogue ----
    float asj = att_src[wv * 16 + (lane & 15)];
    float adj = att_dst[wv * 16 + (lane & 15)];
    #pragma unroll
    for (int mt = 0; mt < 4; ++mt) {
        #pragma unroll
        for (int r = 0; r < 4; ++r) {
            int lrow = mt * 16 + (lane >> 4) * 4 + r;
            int node = base + lrow;
            float hv = acc[mt][r];
            if (node < n) h[(size_t)node * 64 + wv * 16 + (lane & 15)] = hv;
            float p1 = hv * asj, p2 = hv * adj;
            p1 += __shfl_xor(p1, 1);  p2 += __shfl_xor(p2, 1);
            p1 += __shfl_xor(p1, 2);  p2 += __shfl_xor(p2, 2);
            p1 += __shfl_xor(p1, 4);  p2 += __shfl_xor(p2, 4);
            p1 += __shfl_xor(p1, 8);  p2 += __shfl_xor(p2, 8);
            if ((lane & 15) == 0) {
                al_part[0][wv][lrow] = p1;
                al_part[1][wv][lrow] = p2;
            }
        }
    }
    __syncthreads();
    if (t < 64) {
        int node = base + t;
        if (node < n) {
            as_[node] = al_part[0][0][t] + al_part[0][1][t] + al_part[0][2][t] + al_part[0][3][t];
            ad_[node] = al_part[1][0][t] + al_part[1][1][t] + al_part[1][2][t] + al_part[1][3][t];
        }
    }
}

// ---------------- degree count + per-edge rank (coalesced write) ----------------
__global__ void k_deg(const int* __restrict__ ei, int* __restrict__ deg,
                      int* __restrict__ rank, int e) {
    int i = blockIdx.x * blockDim.x + threadIdx.x;
    int stride = gridDim.x * blockDim.x;
    for (; i < e; i += stride) {
        int d = ei[(size_t)e + i];
        rank[i] = atomicAdd(&deg[d], 1);
    }
}

// ---------------- multi-block exclusive scan, 3 phases ----------------
__global__ __launch_bounds__(1024) void k_scan_part(const int* __restrict__ deg,
                                                    int* __restrict__ part, int n) {
    __shared__ int wlds[16];
    int t = threadIdx.x, lane = t & 63, wv = t >> 6;
    int idx = blockIdx.x * 1024 + t;
    int v = (idx < n) ? deg[idx] : 0;
    #pragma unroll
    for (int s = 32; s > 0; s >>= 1) v += __shfl_xor(v, s);
    if (lane == 0) wlds[wv] = v;
    __syncthreads();
    if (t == 0) {
        int s = 0;
        #pragma unroll
        for (int w = 0; w < 16; ++w) s += wlds[w];
        part[blockIdx.x] = s;
    }
}

__global__ __launch_bounds__(1024) void k_scan_top(int* __restrict__ part,
                                                   int* __restrict__ off,
                                                   int nb, int n) {
    __shared__ int wsum[16];
    int t = threadIdx.x, lane = t & 63, wv = t >> 6;
    int v = (t < nb) ? part[t] : 0;
    int x = v;
    #pragma unroll
    for (int i = 1; i < 64; i <<= 1) {
        int u = __shfl_up(x, i);
        if (lane >= i) x += u;
    }
    if (lane == 63) wsum[wv] = x;
    __syncthreads();
    int add = 0;
    for (int w = 0; w < wv; ++w) add += wsum[w];
    if (t < nb) part[t] = x - v + add;
    if (t == nb - 1) off[n] = x + add;
}

__global__ __launch_bounds__(1024) void k_scan_down(const int* __restrict__ deg,
                                                    const int* __restrict__ part,
                                                    int* __restrict__ off, int n) {
    __shared__ int wsum[16];
    int t = threadIdx.x, lane = t & 63, wv = t >> 6;
    int idx = blockIdx.x * 1024 + t;
    int v = (idx < n) ? deg[idx] : 0;
    int x = v;
    #pragma unroll
    for (int i = 1; i < 64; i <<= 1) {
        int u = __shfl_up(x, i);
        if (lane >= i) x += u;
    }
    if (lane == 63) wsum[wv] = x;
    __syncthreads();
    int add = 0;
    for (int w = 0; w < wv; ++w) add += wsum[w];
    if (idx < n) off[idx] = x - v + add + part[blockIdx.x];
}

// ---------------- fill CSR (no atomics): edata[pos] = {src, leakyrelu(e)} ----
__global__ void k_fill(const int* __restrict__ ei, const float* __restrict__ as_,
                       const float* __restrict__ ad_, const int* __restrict__ off,
                       const int* __restrict__ rank, int2* __restrict__ edata,
                       int e, int lo, int hi) {
    int i = blockIdx.x * blockDim.x + threadIdx.x;
    int stride = gridDim.x * blockDim.x;
    for (; i < e; i += stride) {
        int d = ei[(size_t)e + i];
        if (d < lo || d >= hi) continue;
        int s = ei[i];
        float v = as_[s] + ad_[d];
        v = v > 0.f ? v : NEG_SLOPE * v;
        edata[off[d] + rank[i]] = make_int2(s, __float_as_int(v));
    }
}

// ---------------- softmax weights in-place on edata.y ----------------
__global__ __launch_bounds__(256) void k_gatw(const int* __restrict__ off,
                                              int2* __restrict__ edata, int n) {
    int lane = threadIdx.x & 63;
    int d = blockIdx.x * 4 + (threadIdx.x >> 6);
    if (d >= n) return;
    int beg = off[d], end = off[d + 1];
    float m = -3.0e38f;
    for (int i = beg + lane; i < end; i += 64)
        m = fmaxf(m, __int_as_float(edata[i].y));
    #pragma unroll
    for (int s = 32; s > 0; s >>= 1) m = fmaxf(m, __shfl_xor(m, s));

    int i0 = beg + lane;
    float e0 = 0.f, z = 0.f;
    if (i0 < end) { e0 = __expf(__int_as_float(edata[i0].y) - m); z = e0; }
    for (int i = i0 + 64; i < end; i += 64) {
        float e = __expf(__int_as_float(edata[i].y) - m);
        edata[i].y = __float_as_int(e);
        z += e;
    }
    #pragma unroll
    for (int s = 32; s > 0; s >>= 1) z += __shfl_xor(z, s);
    float rz = 1.f / (z + EPSV);
    if (i0 < end) edata[i0].y = __float_as_int(e0 * rz);
    for (int i = i0 + 64; i < end; i += 64)
        edata[i].y = __float_as_int(__int_as_float(edata[i].y) * rz);
}

// ---------------- weighted aggregate + elu -> h1 ----------------
__global__ __launch_bounds__(256) void k_gata(const int* __restrict__ off,
                                              const int2* __restrict__ edata,
                                              const float* __restrict__ h,
                                              float* __restrict__ h1, int n) {
    int lane = threadIdx.x & 63;
    int d = blockIdx.x * 4 + (threadIdx.x >> 6);
    if (d >= n) return;
    int beg = off[d], end = off[d + 1];
    float a0 = 0.f, a1 = 0.f, a2 = 0.f, a3 = 0.f;
    int i = beg;
    for (; i + 4 <= end; i += 4) {
        int2 e0 = edata[i],     e1 = edata[i + 1];
        int2 e2 = edata[i + 2], e3 = edata[i + 3];
        float v0 = h[(size_t)e0.x * 64 + lane];
        float v1 = h[(size_t)e1.x * 64 + lane];
        float v2 = h[(size_t)e2.x * 64 + lane];
        float v3 = h[(size_t)e3.x * 64 + lane];
        a0 += __int_as_float(e0.y) * v0;
        a1 += __int_as_float(e1.y) * v1;
        a2 += __int_as_float(e2.y) * v2;
        a3 += __int_as_float(e3.y) * v3;
    }
    for (; i < end; ++i) {
        int2 ed = edata[i];
        a0 += __int_as_float(ed.y) * h[(size_t)ed.x * 64 + lane];
    }
    h1[(size_t)d * 64 + lane] = eluf((a0 + a1) + (a2 + a3));
}

// ---------------- fused node MLP via bf16-split MFMA ----------------
// 64-node tile, 4 waves. Step1: h2 = h1@w2 (store oh2, stage LDS).
// Step2: h3 = elu(h2@l1w^T + l1b) (stage LDS). Step3: h4 = h3@l2w^T + l2b.
__global__ __launch_bounds__(256) void k_mlp_fused(
    const float* __restrict__ h1g, const float* __restrict__ w2,
    const float* __restrict__ l1w, const float* __restrict__ l1b,
    const float* __restrict__ l2w, const float* __restrict__ l2b,
    float* __restrict__ oh2, float* __restrict__ oh4, int n)
{
    typedef __attribute__((ext_vector_type(8))) short bx8;
    typedef __attribute__((ext_vector_type(4))) float fx4;

    __shared__ float lds2[64 * 36];   // h2 tile, pad-36
    __shared__ float lds3[64 * 68];   // h3 tile, pad-68

    int t = threadIdx.x, lane = t & 63, wv = t >> 6;
    int base = blockIdx.x * 64;
    int lm = lane & 15, lg = lane >> 4;

    // ---- step 1: h2 = h1 @ w2 ; wave wv owns row-tile mt=wv, n-tiles 0..1 ----
    fx4 acc2[2];
    acc2[0] = (fx4){0.f, 0.f, 0.f, 0.f};
    acc2[1] = (fx4){0.f, 0.f, 0.f, 0.f};
    {
        // A fragments from global: row = base + wv*16 + lm, k = ks*32 + lg*8 + i
        bx8 ahi[2], alo[2];
        int row = base + wv * 16 + lm;
        const float* hp = h1g + (size_t)row * 64 + lg * 8;
        #pragma unroll
        for (int ks = 0; ks < 2; ++ks) {
            float4 a0, a1;
            if (row < n) {
                a0 = *(const float4*)(hp + ks * 32);
                a1 = *(const float4*)(hp + ks * 32 + 4);
            } else {
                a0 = make_float4(0.f, 0.f, 0.f, 0.f);
                a1 = make_float4(0.f, 0.f, 0.f, 0.f);
            }
            float ff[8] = { a0.x, a0.y, a0.z, a0.w, a1.x, a1.y, a1.z, a1.w };
            #pragma unroll
            for (int i = 0; i < 8; ++i) {
                unsigned short hb = f32_to_bf16_rne(ff[i]);
                float rem = ff[i] - bf16_bits_to_f32(hb);
                ahi[ks][i] = (short)hb;
                alo[ks][i] = (short)f32_to_bf16_rne(rem);
            }
        }
        // B fragments: B[k][o] = w2[k*32 + o]; o = nt*16 + lm, k = ks*32 + lg*8 + i
        bx8 bhi[2][2], blo[2][2];
        #pragma unroll
        for (int nt = 0; nt < 2; ++nt) {
            #pragma unroll
            for (int ks = 0; ks < 2; ++ks) {
                #pragma unroll
                for (int i = 0; i < 8; ++i) {
                    float f = w2[(size_t)(ks * 32 + lg * 8 + i) * 32 + nt * 16 + lm];
                    unsigned short hb = f32_to_bf16_rne(f);
                    float rem = f - bf16_bits_to_f32(hb);
                    bhi[nt][ks][i] = (short)hb;
                    blo[nt][ks][i] = (short)f32_to_bf16_rne(rem);
                }
            }
        }
        #pragma unroll
        for (int nt = 0; nt < 2; ++nt) {
            #pragma unroll
            for (int ks = 0; ks < 2; ++ks) {
                acc2[nt] = __builtin_amdgcn_mfma_f32_16x16x32_bf16(ahi[ks], bhi[nt][ks], acc2[nt], 0, 0, 0);
                acc2[nt] = __builtin_amdgcn_mfma_f32_16x16x32_bf16(ahi[ks], blo[nt][ks], acc2[nt], 0, 0, 0);
                acc2[nt] = __builtin_amdgcn_mfma_f32_16x16x32_bf16(alo[ks], bhi[nt][ks], acc2[nt], 0, 0, 0);
            }
        }
    }
    // store oh2 + stage h2 to LDS. C/D: col = nt*16+lm, row(local) = wv*16 + lg*4 + r
    #pragma unroll
    for (int nt = 0; nt < 2; ++nt) {
        #pragma unroll
        for (int r = 0; r < 4; ++r) {
            int lrow = wv * 16 + lg * 4 + r;
            int node = base + lrow;
            float v = acc2[nt][r];
            if (node < n) oh2[(size_t)node * 32 + nt * 16 + lm] = v;
            lds2[lrow * 36 + nt * 16 + lm] = v;
        }
    }
    __syncthreads();

    // ---- step 2: h3 = elu(h2 @ l1w^T + l1b) ; K=32, n-tiles 0..3 ----
    fx4 acc3[4];
    #pragma unroll
    for (int nt = 0; nt < 4; ++nt) acc3[nt] = (fx4){0.f, 0.f, 0.f, 0.f};
    {
        // A fragment from lds2: row = wv*16 + lm, k = lg*8 + i
        bx8 ahi, alo;
        {
            const float* ap = &lds2[(wv * 16 + lm) * 36 + lg * 8];
            float4 a0 = *(const float4*)ap;
            float4 a1 = *(const float4*)(ap + 4);
            float ff[8] = { a0.x, a0.y, a0.z, a0.w, a1.x, a1.y, a1.z, a1.w };
            #pragma unroll
            for (int i = 0; i < 8; ++i) {
                unsigned short hb = f32_to_bf16_rne(ff[i]);
                float rem = ff[i] - bf16_bits_to_f32(hb);
                ahi[i] = (short)hb;
                alo[i] = (short)f32_to_bf16_rne(rem);
            }
        }
        // B fragments: B[k][j] = l1w[j*32 + k]; j = nt*16+lm, k = lg*8 + i (contig)
        #pragma unroll
        for (int nt = 0; nt < 4; ++nt) {
            const float* lp = l1w + (size_t)(nt * 16 + lm) * 32 + lg * 8;
            float4 w0 = *(const float4*)lp;
            float4 w1 = *(const float4*)(lp + 4);
            float ff[8] = { w0.x, w0.y, w0.z, w0.w, w1.x, w1.y, w1.z, w1.w };
            bx8 bh, bl;
            #pragma unroll
            for (int i = 0; i < 8; ++i) {
                unsigned short hb = f32_to_bf16_rne(ff[i]);
                float rem = ff[i] - bf16_bits_to_f32(hb);
                bh[i] = (short)hb;
                bl[i] = (short)f32_to_bf16_rne(rem);
            }
            acc3[nt] = __builtin_amdgcn_mfma_f32_16x16x32_bf16(ahi, bh, acc3[nt], 0, 0, 0);
            acc3[nt] = __builtin_amdgcn_mfma_f32_16x16x32_bf16(ahi, bl, acc3[nt], 0, 0, 0);
            acc3[nt] = __builtin_amdgcn_mfma_f32_16x16x32_bf16(alo, bh, acc3[nt], 0, 0, 0);
        }
    }
    // elu + bias, stage h3 to LDS
    #pragma unroll
    for (int nt = 0; nt < 4; ++nt) {
        float b = l1b[nt * 16 + lm];
        #pragma unroll
        for (int r = 0; r < 4; ++r) {
            int lrow = wv * 16 + lg * 4 + r;
            lds3[lrow * 68 + nt * 16 + lm] = eluf(acc3[nt][r] + b);
        }
    }
    __syncthreads();

    // ---- step 3: h4 = h3 @ l2w^T + l2b ; wave wv owns cols wv*64..wv*64+63 ----
    // B fragments resident: B[k][col] = l2w[col*64 + k]
    bx8 bhi[4][2], blo[4][2];
    float bias[4];
    #pragma unroll
    for (int ct = 0; ct < 4; ++ct) {
        int col = wv * 64 + ct * 16 + lm;
        bias[ct] = l2b[col];
        const float* wp = l2w + (size_t)col * 64 + lg * 8;
        #pragma unroll
        for (int ks = 0; ks < 2; ++ks) {
            float4 w0 = *(const float4*)(wp + ks * 32);
            float4 w1 = *(const float4*)(wp + ks * 32 + 4);
            float ff[8] = { w0.x, w0.y, w0.z, w0.w, w1.x, w1.y, w1.z, w1.w };
            #pragma unroll
            for (int i = 0; i < 8; ++i) {
                unsigned short hb = f32_to_bf16_rne(ff[i]);
                float rem = ff[i] - bf16_bits_to_f32(hb);
                bhi[ct][ks][i] = (short)hb;
                blo[ct][ks][i] = (short)f32_to_bf16_rne(rem);
            }
        }
    }
    #pragma unroll
    for (int mt = 0; mt < 4; ++mt) {
        // A fragments from lds3: row = mt*16 + lm, k = ks*32 + lg*8 + i
        bx8 ahi[2], alo[2];
        #pragma unroll
        for (int ks = 0; ks < 2; ++ks) {
            const float* ap = &lds3[(mt * 16 + lm) * 68 + ks * 32 + lg * 8];
            float4 a0 = *(const float4*)ap;
            float4 a1 = *(const float4*)(ap + 4);
            float ff[8] = { a0.x, a0.y, a0.z, a0.w, a1.x, a1.y, a1.z, a1.w };
            #pragma unroll
            for (int i = 0; i < 8; ++i) {
                unsigned short hb = f32_to_bf16_rne(ff[i]);
                float rem = ff[i] - bf16_bits_to_f32(hb);
                ahi[ks][i] = (short)hb;
                alo[ks][i] = (short)f32_to_bf16_rne(rem);
            }
        }
        fx4 acc[4];
        #pragma unroll
        for (int ct = 0; ct < 4; ++ct) acc[ct] = (fx4){0.f, 0.f, 0.f, 0.f};
        #pragma unroll
        for (int ct = 0; ct < 4; ++ct) {
            #pragma unroll
            for (int ks = 0; ks < 2; ++ks) {
                acc[ct] = __builtin_amdgcn_mfma_f32_16x16x32_bf16(ahi[ks], bhi[ct][ks], acc[ct], 0, 0, 0);
                acc[ct] = __builtin_amdgcn_mfma_f32_16x16x32_bf16(ahi[ks], blo[ct][ks], acc[ct], 0, 0, 0);
                acc[ct] = __builtin_amdgcn_mfma_f32_16x16x32_bf16(alo[ks], bhi[ct][ks], acc[ct], 0, 0, 0);
            }
        }
        #pragma unroll
        for (int ct = 0; ct < 4; ++ct) {
            #pragma unroll
            for (int r = 0; r < 4; ++r) {
                int orow = base + mt * 16 + lg * 4 + r;
                if (orow < n) {
                    int ocol = wv * 64 + ct * 16 + lm;
                    oh4[(size_t)orow * 256 + ocol] = acc[ct][r] + bias[ct];
                }
            }
        }
    }
}

extern "C" void kernel_launch(void* const* d_in, const int* in_sizes, int n_in,
                              void* d_out, int out_size, void* d_ws, size_t ws_size,
                              hipStream_t stream) {
    const float* feat    = (const float*)d_in[0];
    const int*   ei      = (const int*)d_in[1];     // int64 in ref -> int32 on device
    const float* w1      = (const float*)d_in[2];
    const float* att_src = (const float*)d_in[3];
    const float* att_dst = (const float*)d_in[4];
    const float* w2      = (const float*)d_in[5];
    const float* l1w     = (const float*)d_in[6];
    const float* l1b     = (const float*)d_in[7];
    const float* l2w     = (const float*)d_in[8];
    const float* l2b     = (const float*)d_in[9];

    const int N = in_sizes[0] / IN_DIM;
    const int E = in_sizes[1] / 2;

    char* p = (char*)d_ws;
    auto alloc = [&](size_t bytes) {
        char* r = p;
        p += (bytes + 255) & ~(size_t)255;
        return r;
    };
    float* h     = (float*)alloc((size_t)N * HID * 4);
    float* h1g   = (float*)alloc((size_t)N * HID * 4);
    float* as_   = (float*)alloc((size_t)N * 4);
    float* ad_   = (float*)alloc((size_t)N * 4);
    int*   deg   = (int*)alloc((size_t)N * 4);
    int*   off   = (int*)alloc((size_t)(N + 1) * 4);
    int*   rank  = (int*)alloc((size_t)E * 4);
    int2*  edata = (int2*)alloc((size_t)E * 8);
    const int nb = (N + 1023) / 1024;
    int*   part  = (int*)alloc((size_t)nb * 4);

    float* oh2 = (float*)d_out;
    float* oh4 = oh2 + (size_t)N * OUTD;

    hipLaunchKernelGGL(k_init, dim3(256), dim3(256), 0, stream, deg, N);
    hipLaunchKernelGGL(k_feat_mfma, dim3((N + 63) / 64), dim3(256), 0, stream,
                       feat, w1, att_src, att_dst, h, as_, ad_, N);
    hipLaunchKernelGGL(k_deg, dim3(2048), dim3(256), 0, stream, ei, deg, rank, E);
    hipLaunchKernelGGL(k_scan_part, dim3(nb), dim3(1024), 0, stream, deg, part, N);
    hipLaunchKernelGGL(k_scan_top, dim3(1), dim3(1024), 0, stream, part, off, nb, N);
    hipLaunchKernelGGL(k_scan_down, dim3(nb), dim3(1024), 0, stream, deg, part, off, N);
    for (int pass = 0; pass < 4; ++pass) {
        int lo = (int)((size_t)N * pass / 4);
        int hi = (int)((size_t)N * (pass + 1) / 4);
        hipLaunchKernelGGL(k_fill, dim3(2048), dim3(256), 0, stream,
                           ei, as_, ad_, off, rank, edata, E, lo, hi);
    }
    hipLaunchKernelGGL(k_gatw, dim3((N + 3) / 4), dim3(256), 0, stream, off, edata, N);
    hipLaunchKernelGGL(k_gata, dim3((N + 3) / 4), dim3(256), 0, stream,
                       off, edata, h, h1g, N);
    hipLaunchKernelGGL(k_mlp_fused, dim3((N + 63) / 64), dim3(256), 0, stream,
                       h1g, w2, l1w, l1b, l2w, l2b, oh2, oh4, N);
}

// Round 12
// 319.576 us; speedup vs baseline: 2.8048x; 1.0453x over previous
//
#include <hip/hip_runtime.h>
#include <math.h>

constexpr int IN_DIM = 256;
constexpr int HID    = 64;
constexpr int OUTD   = 32;
#define NEG_SLOPE 0.2f
#define EPSV 1e-16f

__device__ __forceinline__ float eluf(float x) {
    return x > 0.f ? x : expm1f(x);
}

__device__ __forceinline__ unsigned short f32_to_bf16_rne(float f) {
    unsigned u = __float_as_uint(f);
    unsigned r = u + 0x7fffu + ((u >> 16) & 1u);
    return (unsigned short)(r >> 16);
}
__device__ __forceinline__ float bf16_bits_to_f32(unsigned short s) {
    return __uint_as_float(((unsigned)s) << 16);
}

// ---------------- init: zero deg ----------------
__global__ void k_init(int* __restrict__ deg, int n) {
    int i = blockIdx.x * blockDim.x + threadIdx.x;
    int stride = gridDim.x * blockDim.x;
    for (; i < n; i += stride) deg[i] = 0;
}

// ---------------- h = feat @ w1 via bf16-split MFMA; alphas fused ----------------
// h stored as bf16 (gather payload); alphas computed from full-f32 accumulators.
__global__ __launch_bounds__(256) void k_feat_mfma(
    const float* __restrict__ feat, const float* __restrict__ w1,
    const float* __restrict__ att_src, const float* __restrict__ att_dst,
    unsigned short* __restrict__ h_bf, float* __restrict__ as_,
    float* __restrict__ ad_, int n)
{
    typedef __attribute__((ext_vector_type(8))) short bx8;
    typedef __attribute__((ext_vector_type(4))) float fx4;

    __shared__ short a_hi[4 * 8 * 64 * 8];   // 32 KB
    __shared__ short a_lo[4 * 8 * 64 * 8];   // 32 KB
    __shared__ float al_part[2][4][64];

    int t = threadIdx.x, lane = t & 63, wv = t >> 6;
    int base = blockIdx.x * 64;

    // ---- B (w1) fragments -> registers, hi/lo split ----
    bx8 bhi[8], blo[8];
    {
        int nj = wv * 16 + (lane & 15);
        int kg = (lane >> 4) * 8;
        #pragma unroll
        for (int ks = 0; ks < 8; ++ks) {
            #pragma unroll
            for (int i = 0; i < 8; ++i) {
                float f = w1[(size_t)(ks * 32 + kg + i) * 64 + nj];
                unsigned short hb = f32_to_bf16_rne(f);
                float rem = f - bf16_bits_to_f32(hb);
                bhi[ks][i] = (short)hb;
                blo[ks][i] = (short)f32_to_bf16_rne(rem);
            }
        }
    }

    // ---- stage A (feat) tile ----
    float4 v[16];
    #pragma unroll
    for (int c = 0; c < 8; ++c) {
        int node = (t >> 5) + c * 8;
        int oct = t & 31;
        int gn = base + node;
        if (gn < n) {
            const float4* fp = (const float4*)(feat + (size_t)gn * 256);
            v[2 * c]     = fp[oct * 2];
            v[2 * c + 1] = fp[oct * 2 + 1];
        } else {
            v[2 * c]     = make_float4(0.f, 0.f, 0.f, 0.f);
            v[2 * c + 1] = make_float4(0.f, 0.f, 0.f, 0.f);
        }
    }
    #pragma unroll
    for (int c = 0; c < 8; ++c) {
        int node = (t >> 5) + c * 8;
        int oct = t & 31;
        int mt = node >> 4, lm = node & 15;
        int ks = oct >> 2, lg = oct & 3;
        int flane = lg * 16 + lm;
        int idx = (((mt * 8 + ks) * 64) + (flane ^ ks)) * 8;
        float ff[8] = { v[2*c].x, v[2*c].y, v[2*c].z, v[2*c].w,
                        v[2*c+1].x, v[2*c+1].y, v[2*c+1].z, v[2*c+1].w };
        bx8 hv, lv;
        #pragma unroll
        for (int i = 0; i < 8; ++i) {
            unsigned short hb = f32_to_bf16_rne(ff[i]);
            float rem = ff[i] - bf16_bits_to_f32(hb);
            hv[i] = (short)hb;
            lv[i] = (short)f32_to_bf16_rne(rem);
        }
        *(bx8*)&a_hi[idx] = hv;
        *(bx8*)&a_lo[idx] = lv;
    }
    __syncthreads();

    // ---- MFMA K-loop ----
    fx4 acc[4];
    #pragma unroll
    for (int mt = 0; mt < 4; ++mt) acc[mt] = (fx4){0.f, 0.f, 0.f, 0.f};
    #pragma unroll
    for (int mt = 0; mt < 4; ++mt) {
        #pragma unroll
        for (int ks = 0; ks < 8; ++ks) {
            int idx = (((mt * 8 + ks) * 64) + (lane ^ ks)) * 8;
            bx8 ah = *(bx8*)&a_hi[idx];
            bx8 al = *(bx8*)&a_lo[idx];
            acc[mt] = __builtin_amdgcn_mfma_f32_16x16x32_bf16(ah, bhi[ks], acc[mt], 0, 0, 0);
            acc[mt] = __builtin_amdgcn_mfma_f32_16x16x32_bf16(ah, blo[ks], acc[mt], 0, 0, 0);
            acc[mt] = __builtin_amdgcn_mfma_f32_16x16x32_bf16(al, bhi[ks], acc[mt], 0, 0, 0);
        }
    }

    // ---- epilogue ----
    float asj = att_src[wv * 16 + (lane & 15)];
    float adj = att_dst[wv * 16 + (lane & 15)];
    #pragma unroll
    for (int mt = 0; mt < 4; ++mt) {
        #pragma unroll
        for (int r = 0; r < 4; ++r) {
            int lrow = mt * 16 + (lane >> 4) * 4 + r;
            int node = base + lrow;
            float hv = acc[mt][r];
            if (node < n)
                h_bf[(size_t)node * 64 + wv * 16 + (lane & 15)] = f32_to_bf16_rne(hv);
            float p1 = hv * asj, p2 = hv * adj;
            p1 += __shfl_xor(p1, 1);  p2 += __shfl_xor(p2, 1);
            p1 += __shfl_xor(p1, 2);  p2 += __shfl_xor(p2, 2);
            p1 += __shfl_xor(p1, 4);  p2 += __shfl_xor(p2, 4);
            p1 += __shfl_xor(p1, 8);  p2 += __shfl_xor(p2, 8);
            if ((lane & 15) == 0) {
                al_part[0][wv][lrow] = p1;
                al_part[1][wv][lrow] = p2;
            }
        }
    }
    __syncthreads();
    if (t < 64) {
        int node = base + t;
        if (node < n) {
            as_[node] = al_part[0][0][t] + al_part[0][1][t] + al_part[0][2][t] + al_part[0][3][t];
            ad_[node] = al_part[1][0][t] + al_part[1][1][t] + al_part[1][2][t] + al_part[1][3][t];
        }
    }
}

// ---------------- degree count + per-edge rank (coalesced write) ----------------
__global__ void k_deg(const int* __restrict__ ei, int* __restrict__ deg,
                      int* __restrict__ rank, int e) {
    int i = blockIdx.x * blockDim.x + threadIdx.x;
    int stride = gridDim.x * blockDim.x;
    for (; i < e; i += stride) {
        int d = ei[(size_t)e + i];
        rank[i] = atomicAdd(&deg[d], 1);
    }
}

// ---------------- multi-block exclusive scan, 3 phases ----------------
__global__ __launch_bounds__(1024) void k_scan_part(const int* __restrict__ deg,
                                                    int* __restrict__ part, int n) {
    __shared__ int wlds[16];
    int t = threadIdx.x, lane = t & 63, wv = t >> 6;
    int idx = blockIdx.x * 1024 + t;
    int v = (idx < n) ? deg[idx] : 0;
    #pragma unroll
    for (int s = 32; s > 0; s >>= 1) v += __shfl_xor(v, s);
    if (lane == 0) wlds[wv] = v;
    __syncthreads();
    if (t == 0) {
        int s = 0;
        #pragma unroll
        for (int w = 0; w < 16; ++w) s += wlds[w];
        part[blockIdx.x] = s;
    }
}

__global__ __launch_bounds__(1024) void k_scan_top(int* __restrict__ part,
                                                   int* __restrict__ off,
                                                   int nb, int n) {
    __shared__ int wsum[16];
    int t = threadIdx.x, lane = t & 63, wv = t >> 6;
    int v = (t < nb) ? part[t] : 0;
    int x = v;
    #pragma unroll
    for (int i = 1; i < 64; i <<= 1) {
        int u = __shfl_up(x, i);
        if (lane >= i) x += u;
    }
    if (lane == 63) wsum[wv] = x;
    __syncthreads();
    int add = 0;
    for (int w = 0; w < wv; ++w) add += wsum[w];
    if (t < nb) part[t] = x - v + add;
    if (t == nb - 1) off[n] = x + add;
}

__global__ __launch_bounds__(1024) void k_scan_down(const int* __restrict__ deg,
                                                    const int* __restrict__ part,
                                                    int* __restrict__ off, int n) {
    __shared__ int wsum[16];
    int t = threadIdx.x, lane = t & 63, wv = t >> 6;
    int idx = blockIdx.x * 1024 + t;
    int v = (idx < n) ? deg[idx] : 0;
    int x = v;
    #pragma unroll
    for (int i = 1; i < 64; i <<= 1) {
        int u = __shfl_up(x, i);
        if (lane >= i) x += u;
    }
    if (lane == 63) wsum[wv] = x;
    __syncthreads();
    int add = 0;
    for (int w = 0; w < wv; ++w) add += wsum[w];
    if (idx < n) off[idx] = x - v + add + part[blockIdx.x];
}

// ---------------- fill CSR (no atomics): edata[pos] = {src, leakyrelu(e)} ----
__global__ void k_fill(const int* __restrict__ ei, const float* __restrict__ as_,
                       const float* __restrict__ ad_, const int* __restrict__ off,
                       const int* __restrict__ rank, int2* __restrict__ edata,
                       int e, int lo, int hi) {
    int i = blockIdx.x * blockDim.x + threadIdx.x;
    int stride = gridDim.x * blockDim.x;
    for (; i < e; i += stride) {
        int d = ei[(size_t)e + i];
        if (d < lo || d >= hi) continue;
        int s = ei[i];
        float v = as_[s] + ad_[d];
        v = v > 0.f ? v : NEG_SLOPE * v;
        edata[off[d] + rank[i]] = make_int2(s, __float_as_int(v));
    }
}

// ---------------- softmax weights in-place on edata.y ----------------
__global__ __launch_bounds__(256) void k_gatw(const int* __restrict__ off,
                                              int2* __restrict__ edata, int n) {
    int lane = threadIdx.x & 63;
    int d = blockIdx.x * 4 + (threadIdx.x >> 6);
    if (d >= n) return;
    int beg = off[d], end = off[d + 1];
    float m = -3.0e38f;
    for (int i = beg + lane; i < end; i += 64)
        m = fmaxf(m, __int_as_float(edata[i].y));
    #pragma unroll
    for (int s = 32; s > 0; s >>= 1) m = fmaxf(m, __shfl_xor(m, s));

    int i0 = beg + lane;
    float e0 = 0.f, z = 0.f;
    if (i0 < end) { e0 = __expf(__int_as_float(edata[i0].y) - m); z = e0; }
    for (int i = i0 + 64; i < end; i += 64) {
        float e = __expf(__int_as_float(edata[i].y) - m);
        edata[i].y = __float_as_int(e);
        z += e;
    }
    #pragma unroll
    for (int s = 32; s > 0; s >>= 1) z += __shfl_xor(z, s);
    float rz = 1.f / (z + EPSV);
    if (i0 < end) edata[i0].y = __float_as_int(e0 * rz);
    for (int i = i0 + 64; i < end; i += 64)
        edata[i].y = __float_as_int(__int_as_float(edata[i].y) * rz);
}

// ---------------- weighted aggregate + elu -> h1 (bf16 h gather) ----------------
__global__ __launch_bounds__(256) void k_gata(const int* __restrict__ off,
                                              const int2* __restrict__ edata,
                                              const unsigned short* __restrict__ h_bf,
                                              float* __restrict__ h1, int n) {
    int lane = threadIdx.x & 63;
    int d = blockIdx.x * 4 + (threadIdx.x >> 6);
    if (d >= n) return;
    int beg = off[d], end = off[d + 1];
    float a0 = 0.f, a1 = 0.f, a2 = 0.f, a3 = 0.f;
    int i = beg;
    for (; i + 4 <= end; i += 4) {
        int2 e0 = edata[i],     e1 = edata[i + 1];
        int2 e2 = edata[i + 2], e3 = edata[i + 3];
        float v0 = bf16_bits_to_f32(h_bf[(size_t)e0.x * 64 + lane]);
        float v1 = bf16_bits_to_f32(h_bf[(size_t)e1.x * 64 + lane]);
        float v2 = bf16_bits_to_f32(h_bf[(size_t)e2.x * 64 + lane]);
        float v3 = bf16_bits_to_f32(h_bf[(size_t)e3.x * 64 + lane]);
        a0 += __int_as_float(e0.y) * v0;
        a1 += __int_as_float(e1.y) * v1;
        a2 += __int_as_float(e2.y) * v2;
        a3 += __int_as_float(e3.y) * v3;
    }
    for (; i < end; ++i) {
        int2 ed = edata[i];
        a0 += __int_as_float(ed.y) * bf16_bits_to_f32(h_bf[(size_t)ed.x * 64 + lane]);
    }
    h1[(size_t)d * 64 + lane] = eluf((a0 + a1) + (a2 + a3));
}

// ---------------- fused node MLP via bf16-split MFMA ----------------
__global__ __launch_bounds__(256) void k_mlp_fused(
    const float* __restrict__ h1g, const float* __restrict__ w2,
    const float* __restrict__ l1w, const float* __restrict__ l1b,
    const float* __restrict__ l2w, const float* __restrict__ l2b,
    float* __restrict__ oh2, float* __restrict__ oh4, int n)
{
    typedef __attribute__((ext_vector_type(8))) short bx8;
    typedef __attribute__((ext_vector_type(4))) float fx4;

    __shared__ float lds2[64 * 36];   // h2 tile, pad-36
    __shared__ float lds3[64 * 68];   // h3 tile, pad-68

    int t = threadIdx.x, lane = t & 63, wv = t >> 6;
    int base = blockIdx.x * 64;
    int lm = lane & 15, lg = lane >> 4;

    // ---- step 1: h2 = h1 @ w2 ----
    fx4 acc2[2];
    acc2[0] = (fx4){0.f, 0.f, 0.f, 0.f};
    acc2[1] = (fx4){0.f, 0.f, 0.f, 0.f};
    {
        bx8 ahi[2], alo[2];
        int row = base + wv * 16 + lm;
        const float* hp = h1g + (size_t)row * 64 + lg * 8;
        #pragma unroll
        for (int ks = 0; ks < 2; ++ks) {
            float4 a0, a1;
            if (row < n) {
                a0 = *(const float4*)(hp + ks * 32);
                a1 = *(const float4*)(hp + ks * 32 + 4);
            } else {
                a0 = make_float4(0.f, 0.f, 0.f, 0.f);
                a1 = make_float4(0.f, 0.f, 0.f, 0.f);
            }
            float ff[8] = { a0.x, a0.y, a0.z, a0.w, a1.x, a1.y, a1.z, a1.w };
            #pragma unroll
            for (int i = 0; i < 8; ++i) {
                unsigned short hb = f32_to_bf16_rne(ff[i]);
                float rem = ff[i] - bf16_bits_to_f32(hb);
                ahi[ks][i] = (short)hb;
                alo[ks][i] = (short)f32_to_bf16_rne(rem);
            }
        }
        bx8 bhi[2][2], blo[2][2];
        #pragma unroll
        for (int nt = 0; nt < 2; ++nt) {
            #pragma unroll
            for (int ks = 0; ks < 2; ++ks) {
                #pragma unroll
                for (int i = 0; i < 8; ++i) {
                    float f = w2[(size_t)(ks * 32 + lg * 8 + i) * 32 + nt * 16 + lm];
                    unsigned short hb = f32_to_bf16_rne(f);
                    float rem = f - bf16_bits_to_f32(hb);
                    bhi[nt][ks][i] = (short)hb;
                    blo[nt][ks][i] = (short)f32_to_bf16_rne(rem);
                }
            }
        }
        #pragma unroll
        for (int nt = 0; nt < 2; ++nt) {
            #pragma unroll
            for (int ks = 0; ks < 2; ++ks) {
                acc2[nt] = __builtin_amdgcn_mfma_f32_16x16x32_bf16(ahi[ks], bhi[nt][ks], acc2[nt], 0, 0, 0);
                acc2[nt] = __builtin_amdgcn_mfma_f32_16x16x32_bf16(ahi[ks], blo[nt][ks], acc2[nt], 0, 0, 0);
                acc2[nt] = __builtin_amdgcn_mfma_f32_16x16x32_bf16(alo[ks], bhi[nt][ks], acc2[nt], 0, 0, 0);
            }
        }
    }
    #pragma unroll
    for (int nt = 0; nt < 2; ++nt) {
        #pragma unroll
        for (int r = 0; r < 4; ++r) {
            int lrow = wv * 16 + lg * 4 + r;
            int node = base + lrow;
            float v = acc2[nt][r];
            if (node < n) oh2[(size_t)node * 32 + nt * 16 + lm] = v;
            lds2[lrow * 36 + nt * 16 + lm] = v;
        }
    }
    __syncthreads();

    // ---- step 2: h3 = elu(h2 @ l1w^T + l1b) ----
    fx4 acc3[4];
    #pragma unroll
    for (int nt = 0; nt < 4; ++nt) acc3[nt] = (fx4){0.f, 0.f, 0.f, 0.f};
    {
        bx8 ahi, alo;
        {
            const float* ap = &lds2[(wv * 16 + lm) * 36 + lg * 8];
            float4 a0 = *(const float4*)ap;
            float4 a1 = *(const float4*)(ap + 4);
            float ff[8] = { a0.x, a0.y, a0.z, a0.w, a1.x, a1.y, a1.z, a1.w };
            #pragma unroll
            for (int i = 0; i < 8; ++i) {
                unsigned short hb = f32_to_bf16_rne(ff[i]);
                float rem = ff[i] - bf16_bits_to_f32(hb);
                ahi[i] = (short)hb;
                alo[i] = (short)f32_to_bf16_rne(rem);
            }
        }
        #pragma unroll
        for (int nt = 0; nt < 4; ++nt) {
            const float* lp = l1w + (size_t)(nt * 16 + lm) * 32 + lg * 8;
            float4 w0 = *(const float4*)lp;
            float4 w1 = *(const float4*)(lp + 4);
            float ff[8] = { w0.x, w0.y, w0.z, w0.w, w1.x, w1.y, w1.z, w1.w };
            bx8 bh, bl;
            #pragma unroll
            for (int i = 0; i < 8; ++i) {
                unsigned short hb = f32_to_bf16_rne(ff[i]);
                float rem = ff[i] - bf16_bits_to_f32(hb);
                bh[i] = (short)hb;
                bl[i] = (short)f32_to_bf16_rne(rem);
            }
            acc3[nt] = __builtin_amdgcn_mfma_f32_16x16x32_bf16(ahi, bh, acc3[nt], 0, 0, 0);
            acc3[nt] = __builtin_amdgcn_mfma_f32_16x16x32_bf16(ahi, bl, acc3[nt], 0, 0, 0);
            acc3[nt] = __builtin_amdgcn_mfma_f32_16x16x32_bf16(alo, bh, acc3[nt], 0, 0, 0);
        }
    }
    #pragma unroll
    for (int nt = 0; nt < 4; ++nt) {
        float b = l1b[nt * 16 + lm];
        #pragma unroll
        for (int r = 0; r < 4; ++r) {
            int lrow = wv * 16 + lg * 4 + r;
            lds3[lrow * 68 + nt * 16 + lm] = eluf(acc3[nt][r] + b);
        }
    }
    __syncthreads();

    // ---- step 3: h4 = h3 @ l2w^T + l2b ----
    bx8 bhi[4][2], blo[4][2];
    float bias[4];
    #pragma unroll
    for (int ct = 0; ct < 4; ++ct) {
        int col = wv * 64 + ct * 16 + lm;
        bias[ct] = l2b[col];
        const float* wp = l2w + (size_t)col * 64 + lg * 8;
        #pragma unroll
        for (int ks = 0; ks < 2; ++ks) {
            float4 w0 = *(const float4*)(wp + ks * 32);
            float4 w1 = *(const float4*)(wp + ks * 32 + 4);
            float ff[8] = { w0.x, w0.y, w0.z, w0.w, w1.x, w1.y, w1.z, w1.w };
            #pragma unroll
            for (int i = 0; i < 8; ++i) {
                unsigned short hb = f32_to_bf16_rne(ff[i]);
                float rem = ff[i] - bf16_bits_to_f32(hb);
                bhi[ct][ks][i] = (short)hb;
                blo[ct][ks][i] = (short)f32_to_bf16_rne(rem);
            }
        }
    }
    #pragma unroll
    for (int mt = 0; mt < 4; ++mt) {
        bx8 ahi[2], alo[2];
        #pragma unroll
        for (int ks = 0; ks < 2; ++ks) {
            const float* ap = &lds3[(mt * 16 + lm) * 68 + ks * 32 + lg * 8];
            float4 a0 = *(const float4*)ap;
            float4 a1 = *(const float4*)(ap + 4);
            float ff[8] = { a0.x, a0.y, a0.z, a0.w, a1.x, a1.y, a1.z, a1.w };
            #pragma unroll
            for (int i = 0; i < 8; ++i) {
                unsigned short hb = f32_to_bf16_rne(ff[i]);
                float rem = ff[i] - bf16_bits_to_f32(hb);
                ahi[ks][i] = (short)hb;
                alo[ks][i] = (short)f32_to_bf16_rne(rem);
            }
        }
        fx4 acc[4];
        #pragma unroll
        for (int ct = 0; ct < 4; ++ct) acc[ct] = (fx4){0.f, 0.f, 0.f, 0.f};
        #pragma unroll
        for (int ct = 0; ct < 4; ++ct) {
            #pragma unroll
            for (int ks = 0; ks < 2; ++ks) {
                acc[ct] = __builtin_amdgcn_mfma_f32_16x16x32_bf16(ahi[ks], bhi[ct][ks], acc[ct], 0, 0, 0);
                acc[ct] = __builtin_amdgcn_mfma_f32_16x16x32_bf16(ahi[ks], blo[ct][ks], acc[ct], 0, 0, 0);
                acc[ct] = __builtin_amdgcn_mfma_f32_16x16x32_bf16(alo[ks], bhi[ct][ks], acc[ct], 0, 0, 0);
            }
        }
        #pragma unroll
        for (int ct = 0; ct < 4; ++ct) {
            #pragma unroll
            for (int r = 0; r < 4; ++r) {
                int orow = base + mt * 16 + lg * 4 + r;
                if (orow < n) {
                    int ocol = wv * 64 + ct * 16 + lm;
                    oh4[(size_t)orow * 256 + ocol] = acc[ct][r] + bias[ct];
                }
            }
        }
    }
}

extern "C" void kernel_launch(void* const* d_in, const int* in_sizes, int n_in,
                              void* d_out, int out_size, void* d_ws, size_t ws_size,
                              hipStream_t stream) {
    const float* feat    = (const float*)d_in[0];
    const int*   ei      = (const int*)d_in[1];     // int64 in ref -> int32 on device
    const float* w1      = (const float*)d_in[2];
    const float* att_src = (const float*)d_in[3];
    const float* att_dst = (const float*)d_in[4];
    const float* w2      = (const float*)d_in[5];
    const float* l1w     = (const float*)d_in[6];
    const float* l1b     = (const float*)d_in[7];
    const float* l2w     = (const float*)d_in[8];
    const float* l2b     = (const float*)d_in[9];

    const int N = in_sizes[0] / IN_DIM;
    const int E = in_sizes[1] / 2;

    char* p = (char*)d_ws;
    auto alloc = [&](size_t bytes) {
        char* r = p;
        p += (bytes + 255) & ~(size_t)255;
        return r;
    };
    unsigned short* h_bf = (unsigned short*)alloc((size_t)N * HID * 2);
    float* h1g   = (float*)alloc((size_t)N * HID * 4);
    float* as_   = (float*)alloc((size_t)N * 4);
    float* ad_   = (float*)alloc((size_t)N * 4);
    int*   deg   = (int*)alloc((size_t)N * 4);
    int*   off   = (int*)alloc((size_t)(N + 1) * 4);
    int*   rank  = (int*)alloc((size_t)E * 4);
    int2*  edata = (int2*)alloc((size_t)E * 8);
    const int nb = (N + 1023) / 1024;
    int*   part  = (int*)alloc((size_t)nb * 4);

    float* oh2 = (float*)d_out;
    float* oh4 = oh2 + (size_t)N * OUTD;

    hipLaunchKernelGGL(k_init, dim3(256), dim3(256), 0, stream, deg, N);
    hipLaunchKernelGGL(k_feat_mfma, dim3((N + 63) / 64), dim3(256), 0, stream,
                       feat, w1, att_src, att_dst, h_bf, as_, ad_, N);
    hipLaunchKernelGGL(k_deg, dim3(2048), dim3(256), 0, stream, ei, deg, rank, E);
    hipLaunchKernelGGL(k_scan_part, dim3(nb), dim3(1024), 0, stream, deg, part, N);
    hipLaunchKernelGGL(k_scan_top, dim3(1), dim3(1024), 0, stream, part, off, nb, N);
    hipLaunchKernelGGL(k_scan_down, dim3(nb), dim3(1024), 0, stream, deg, part, off, N);
    for (int pass = 0; pass < 4; ++pass) {
        int lo = (int)((size_t)N * pass / 4);
        int hi = (int)((size_t)N * (pass + 1) / 4);
        hipLaunchKernelGGL(k_fill, dim3(2048), dim3(256), 0, stream,
                           ei, as_, ad_, off, rank, edata, E, lo, hi);
    }
    hipLaunchKernelGGL(k_gatw, dim3((N + 3) / 4), dim3(256), 0, stream, off, edata, N);
    hipLaunchKernelGGL(k_gata, dim3((N + 3) / 4), dim3(256), 0, stream,
                       off, edata, h_bf, h1g, N);
    hipLaunchKernelGGL(k_mlp_fused, dim3((N + 63) / 64), dim3(256), 0, stream,
                       h1g, w2, l1w, l1b, l2w, l2b, oh2, oh4, N);
}

// Round 13
// 317.054 us; speedup vs baseline: 2.8271x; 1.0080x over previous
//
#include <hip/hip_runtime.h>
#include <math.h>

constexpr int IN_DIM = 256;
constexpr int HID    = 64;
constexpr int OUTD   = 32;
#define NEG_SLOPE 0.2f
#define EPSV 1e-16f

__device__ __forceinline__ float eluf(float x) {
    return x > 0.f ? x : expm1f(x);
}

__device__ __forceinline__ unsigned short f32_to_bf16_rne(float f) {
    unsigned u = __float_as_uint(f);
    unsigned r = u + 0x7fffu + ((u >> 16) & 1u);
    return (unsigned short)(r >> 16);
}
__device__ __forceinline__ float bf16_bits_to_f32(unsigned short s) {
    return __uint_as_float(((unsigned)s) << 16);
}

// ---------------- init: zero deg ----------------
__global__ void k_init(int* __restrict__ deg, int n) {
    int i = blockIdx.x * blockDim.x + threadIdx.x;
    int stride = gridDim.x * blockDim.x;
    for (; i < n; i += stride) deg[i] = 0;
}

// ---------------- one-shot weight fragment conversion (1 block) ----------------
// Lays out w2 / l1w / l2w as fragment-ordered bf16 hi/lo short8, lane-indexed
// exactly as k_mlp_fused consumes them.
__global__ __launch_bounds__(256) void k_wconv(
    const float* __restrict__ w2, const float* __restrict__ l1w,
    const float* __restrict__ l2w,
    short* __restrict__ w2f_hi, short* __restrict__ w2f_lo,
    short* __restrict__ l1f_hi, short* __restrict__ l1f_lo,
    short* __restrict__ l2f_hi, short* __restrict__ l2f_lo)
{
    int t = threadIdx.x;
    int lane = t & 63, combo = t >> 6;
    int lm = lane & 15, lg = lane >> 4;

    // w2 fragments: combo = nt*2 + ks  (4 combos)
    {
        int nt = combo >> 1, ks = combo & 1;
        #pragma unroll
        for (int i = 0; i < 8; ++i) {
            float f = w2[(size_t)(ks * 32 + lg * 8 + i) * 32 + nt * 16 + lm];
            unsigned short hb = f32_to_bf16_rne(f);
            float rem = f - bf16_bits_to_f32(hb);
            w2f_hi[((size_t)combo * 64 + lane) * 8 + i] = (short)hb;
            w2f_lo[((size_t)combo * 64 + lane) * 8 + i] = (short)f32_to_bf16_rne(rem);
        }
    }
    // l1w fragments: combo = nt (4 combos)
    {
        int nt = combo;
        #pragma unroll
        for (int i = 0; i < 8; ++i) {
            float f = l1w[(size_t)(nt * 16 + lm) * 32 + lg * 8 + i];
            unsigned short hb = f32_to_bf16_rne(f);
            float rem = f - bf16_bits_to_f32(hb);
            l1f_hi[((size_t)combo * 64 + lane) * 8 + i] = (short)hb;
            l1f_lo[((size_t)combo * 64 + lane) * 8 + i] = (short)f32_to_bf16_rne(rem);
        }
    }
    // l2w fragments: c = wv*8 + ct*2 + ks (32 combos), 8 iterations
    for (int it = 0; it < 8; ++it) {
        int c = it * 4 + combo;
        int wv = c >> 3, ct = (c >> 1) & 3, ks = c & 1;
        #pragma unroll
        for (int i = 0; i < 8; ++i) {
            float f = l2w[(size_t)(wv * 64 + ct * 16 + lm) * 64 + ks * 32 + lg * 8 + i];
            unsigned short hb = f32_to_bf16_rne(f);
            float rem = f - bf16_bits_to_f32(hb);
            l2f_hi[((size_t)c * 64 + lane) * 8 + i] = (short)hb;
            l2f_lo[((size_t)c * 64 + lane) * 8 + i] = (short)f32_to_bf16_rne(rem);
        }
    }
}

// ---------------- h = feat @ w1 via bf16-split MFMA; alphas fused ----------------
__global__ __launch_bounds__(256) void k_feat_mfma(
    const float* __restrict__ feat, const float* __restrict__ w1,
    const float* __restrict__ att_src, const float* __restrict__ att_dst,
    unsigned short* __restrict__ h_bf, float* __restrict__ as_,
    float* __restrict__ ad_, int n)
{
    typedef __attribute__((ext_vector_type(8))) short bx8;
    typedef __attribute__((ext_vector_type(4))) float fx4;

    __shared__ short a_hi[4 * 8 * 64 * 8];   // 32 KB
    __shared__ short a_lo[4 * 8 * 64 * 8];   // 32 KB
    __shared__ float al_part[2][4][64];

    int t = threadIdx.x, lane = t & 63, wv = t >> 6;
    int base = blockIdx.x * 64;

    bx8 bhi[8], blo[8];
    {
        int nj = wv * 16 + (lane & 15);
        int kg = (lane >> 4) * 8;
        #pragma unroll
        for (int ks = 0; ks < 8; ++ks) {
            #pragma unroll
            for (int i = 0; i < 8; ++i) {
                float f = w1[(size_t)(ks * 32 + kg + i) * 64 + nj];
                unsigned short hb = f32_to_bf16_rne(f);
                float rem = f - bf16_bits_to_f32(hb);
                bhi[ks][i] = (short)hb;
                blo[ks][i] = (short)f32_to_bf16_rne(rem);
            }
        }
    }

    float4 v[16];
    #pragma unroll
    for (int c = 0; c < 8; ++c) {
        int node = (t >> 5) + c * 8;
        int oct = t & 31;
        int gn = base + node;
        if (gn < n) {
            const float4* fp = (const float4*)(feat + (size_t)gn * 256);
            v[2 * c]     = fp[oct * 2];
            v[2 * c + 1] = fp[oct * 2 + 1];
        } else {
            v[2 * c]     = make_float4(0.f, 0.f, 0.f, 0.f);
            v[2 * c + 1] = make_float4(0.f, 0.f, 0.f, 0.f);
        }
    }
    #pragma unroll
    for (int c = 0; c < 8; ++c) {
        int node = (t >> 5) + c * 8;
        int oct = t & 31;
        int mt = node >> 4, lm = node & 15;
        int ks = oct >> 2, lg = oct & 3;
        int flane = lg * 16 + lm;
        int idx = (((mt * 8 + ks) * 64) + (flane ^ ks)) * 8;
        float ff[8] = { v[2*c].x, v[2*c].y, v[2*c].z, v[2*c].w,
                        v[2*c+1].x, v[2*c+1].y, v[2*c+1].z, v[2*c+1].w };
        bx8 hv, lv;
        #pragma unroll
        for (int i = 0; i < 8; ++i) {
            unsigned short hb = f32_to_bf16_rne(ff[i]);
            float rem = ff[i] - bf16_bits_to_f32(hb);
            hv[i] = (short)hb;
            lv[i] = (short)f32_to_bf16_rne(rem);
        }
        *(bx8*)&a_hi[idx] = hv;
        *(bx8*)&a_lo[idx] = lv;
    }
    __syncthreads();

    fx4 acc[4];
    #pragma unroll
    for (int mt = 0; mt < 4; ++mt) acc[mt] = (fx4){0.f, 0.f, 0.f, 0.f};
    #pragma unroll
    for (int mt = 0; mt < 4; ++mt) {
        #pragma unroll
        for (int ks = 0; ks < 8; ++ks) {
            int idx = (((mt * 8 + ks) * 64) + (lane ^ ks)) * 8;
            bx8 ah = *(bx8*)&a_hi[idx];
            bx8 al = *(bx8*)&a_lo[idx];
            acc[mt] = __builtin_amdgcn_mfma_f32_16x16x32_bf16(ah, bhi[ks], acc[mt], 0, 0, 0);
            acc[mt] = __builtin_amdgcn_mfma_f32_16x16x32_bf16(ah, blo[ks], acc[mt], 0, 0, 0);
            acc[mt] = __builtin_amdgcn_mfma_f32_16x16x32_bf16(al, bhi[ks], acc[mt], 0, 0, 0);
        }
    }

    float asj = att_src[wv * 16 + (lane & 15)];
    float adj = att_dst[wv * 16 + (lane & 15)];
    #pragma unroll
    for (int mt = 0; mt < 4; ++mt) {
        #pragma unroll
        for (int r = 0; r < 4; ++r) {
            int lrow = mt * 16 + (lane >> 4) * 4 + r;
            int node = base + lrow;
            float hv = acc[mt][r];
            if (node < n)
                h_bf[(size_t)node * 64 + wv * 16 + (lane & 15)] = f32_to_bf16_rne(hv);
            float p1 = hv * asj, p2 = hv * adj;
            p1 += __shfl_xor(p1, 1);  p2 += __shfl_xor(p2, 1);
            p1 += __shfl_xor(p1, 2);  p2 += __shfl_xor(p2, 2);
            p1 += __shfl_xor(p1, 4);  p2 += __shfl_xor(p2, 4);
            p1 += __shfl_xor(p1, 8);  p2 += __shfl_xor(p2, 8);
            if ((lane & 15) == 0) {
                al_part[0][wv][lrow] = p1;
                al_part[1][wv][lrow] = p2;
            }
        }
    }
    __syncthreads();
    if (t < 64) {
        int node = base + t;
        if (node < n) {
            as_[node] = al_part[0][0][t] + al_part[0][1][t] + al_part[0][2][t] + al_part[0][3][t];
            ad_[node] = al_part[1][0][t] + al_part[1][1][t] + al_part[1][2][t] + al_part[1][3][t];
        }
    }
}

// ---------------- degree count + per-edge rank (coalesced write) ----------------
__global__ void k_deg(const int* __restrict__ ei, int* __restrict__ deg,
                      int* __restrict__ rank, int e) {
    int i = blockIdx.x * blockDim.x + threadIdx.x;
    int stride = gridDim.x * blockDim.x;
    for (; i < e; i += stride) {
        int d = ei[(size_t)e + i];
        rank[i] = atomicAdd(&deg[d], 1);
    }
}

// ---------------- multi-block exclusive scan, 3 phases ----------------
__global__ __launch_bounds__(1024) void k_scan_part(const int* __restrict__ deg,
                                                    int* __restrict__ part, int n) {
    __shared__ int wlds[16];
    int t = threadIdx.x, lane = t & 63, wv = t >> 6;
    int idx = blockIdx.x * 1024 + t;
    int v = (idx < n) ? deg[idx] : 0;
    #pragma unroll
    for (int s = 32; s > 0; s >>= 1) v += __shfl_xor(v, s);
    if (lane == 0) wlds[wv] = v;
    __syncthreads();
    if (t == 0) {
        int s = 0;
        #pragma unroll
        for (int w = 0; w < 16; ++w) s += wlds[w];
        part[blockIdx.x] = s;
    }
}

__global__ __launch_bounds__(1024) void k_scan_top(int* __restrict__ part,
                                                   int* __restrict__ off,
                                                   int nb, int n) {
    __shared__ int wsum[16];
    int t = threadIdx.x, lane = t & 63, wv = t >> 6;
    int v = (t < nb) ? part[t] : 0;
    int x = v;
    #pragma unroll
    for (int i = 1; i < 64; i <<= 1) {
        int u = __shfl_up(x, i);
        if (lane >= i) x += u;
    }
    if (lane == 63) wsum[wv] = x;
    __syncthreads();
    int add = 0;
    for (int w = 0; w < wv; ++w) add += wsum[w];
    if (t < nb) part[t] = x - v + add;
    if (t == nb - 1) off[n] = x + add;
}

__global__ __launch_bounds__(1024) void k_scan_down(const int* __restrict__ deg,
                                                    const int* __restrict__ part,
                                                    int* __restrict__ off, int n) {
    __shared__ int wsum[16];
    int t = threadIdx.x, lane = t & 63, wv = t >> 6;
    int idx = blockIdx.x * 1024 + t;
    int v = (idx < n) ? deg[idx] : 0;
    int x = v;
    #pragma unroll
    for (int i = 1; i < 64; i <<= 1) {
        int u = __shfl_up(x, i);
        if (lane >= i) x += u;
    }
    if (lane == 63) wsum[wv] = x;
    __syncthreads();
    int add = 0;
    for (int w = 0; w < wv; ++w) add += wsum[w];
    if (idx < n) off[idx] = x - v + add + part[blockIdx.x];
}

// ---------------- fill CSR (no atomics): edata[pos] = {src, leakyrelu(e)} ----
__global__ void k_fill(const int* __restrict__ ei, const float* __restrict__ as_,
                       const float* __restrict__ ad_, const int* __restrict__ off,
                       const int* __restrict__ rank, int2* __restrict__ edata,
                       int e, int lo, int hi) {
    int i = blockIdx.x * blockDim.x + threadIdx.x;
    int stride = gridDim.x * blockDim.x;
    for (; i < e; i += stride) {
        int d = ei[(size_t)e + i];
        if (d < lo || d >= hi) continue;
        int s = ei[i];
        float v = as_[s] + ad_[d];
        v = v > 0.f ? v : NEG_SLOPE * v;
        edata[off[d] + rank[i]] = make_int2(s, __float_as_int(v));
    }
}

// ---------------- softmax weights in-place on edata.y ----------------
__global__ __launch_bounds__(256) void k_gatw(const int* __restrict__ off,
                                              int2* __restrict__ edata, int n) {
    int lane = threadIdx.x & 63;
    int d = blockIdx.x * 4 + (threadIdx.x >> 6);
    if (d >= n) return;
    int beg = off[d], end = off[d + 1];
    float m = -3.0e38f;
    for (int i = beg + lane; i < end; i += 64)
        m = fmaxf(m, __int_as_float(edata[i].y));
    #pragma unroll
    for (int s = 32; s > 0; s >>= 1) m = fmaxf(m, __shfl_xor(m, s));

    int i0 = beg + lane;
    float e0 = 0.f, z = 0.f;
    if (i0 < end) { e0 = __expf(__int_as_float(edata[i0].y) - m); z = e0; }
    for (int i = i0 + 64; i < end; i += 64) {
        float e = __expf(__int_as_float(edata[i].y) - m);
        edata[i].y = __float_as_int(e);
        z += e;
    }
    #pragma unroll
    for (int s = 32; s > 0; s >>= 1) z += __shfl_xor(z, s);
    float rz = 1.f / (z + EPSV);
    if (i0 < end) edata[i0].y = __float_as_int(e0 * rz);
    for (int i = i0 + 64; i < end; i += 64)
        edata[i].y = __float_as_int(__int_as_float(edata[i].y) * rz);
}

// ---------------- weighted aggregate + elu -> h1 (bf16 h gather) ----------------
__global__ __launch_bounds__(256) void k_gata(const int* __restrict__ off,
                                              const int2* __restrict__ edata,
                                              const unsigned short* __restrict__ h_bf,
                                              float* __restrict__ h1, int n) {
    int lane = threadIdx.x & 63;
    int d = blockIdx.x * 4 + (threadIdx.x >> 6);
    if (d >= n) return;
    int beg = off[d], end = off[d + 1];
    float a0 = 0.f, a1 = 0.f, a2 = 0.f, a3 = 0.f;
    int i = beg;
    for (; i + 4 <= end; i += 4) {
        int2 e0 = edata[i],     e1 = edata[i + 1];
        int2 e2 = edata[i + 2], e3 = edata[i + 3];
        float v0 = bf16_bits_to_f32(h_bf[(size_t)e0.x * 64 + lane]);
        float v1 = bf16_bits_to_f32(h_bf[(size_t)e1.x * 64 + lane]);
        float v2 = bf16_bits_to_f32(h_bf[(size_t)e2.x * 64 + lane]);
        float v3 = bf16_bits_to_f32(h_bf[(size_t)e3.x * 64 + lane]);
        a0 += __int_as_float(e0.y) * v0;
        a1 += __int_as_float(e1.y) * v1;
        a2 += __int_as_float(e2.y) * v2;
        a3 += __int_as_float(e3.y) * v3;
    }
    for (; i < end; ++i) {
        int2 ed = edata[i];
        a0 += __int_as_float(ed.y) * bf16_bits_to_f32(h_bf[(size_t)ed.x * 64 + lane]);
    }
    h1[(size_t)d * 64 + lane] = eluf((a0 + a1) + (a2 + a3));
}

// ---------------- fused node MLP via bf16-split MFMA (pre-converted weights) ----
__global__ __launch_bounds__(256) void k_mlp_fused(
    const float* __restrict__ h1g,
    const short* __restrict__ w2f_hi, const short* __restrict__ w2f_lo,
    const short* __restrict__ l1f_hi, const short* __restrict__ l1f_lo,
    const short* __restrict__ l2f_hi, const short* __restrict__ l2f_lo,
    const float* __restrict__ l1b, const float* __restrict__ l2b,
    float* __restrict__ oh2, float* __restrict__ oh4, int n)
{
    typedef __attribute__((ext_vector_type(8))) short bx8;
    typedef __attribute__((ext_vector_type(4))) float fx4;

    __shared__ float lds2[64 * 36];   // h2 tile, pad-36
    __shared__ float lds3[64 * 68];   // h3 tile, pad-68

    int t = threadIdx.x, lane = t & 63, wv = t >> 6;
    int base = blockIdx.x * 64;
    int lm = lane & 15, lg = lane >> 4;

    // ---- step 1: h2 = h1 @ w2 ----
    fx4 acc2[2];
    acc2[0] = (fx4){0.f, 0.f, 0.f, 0.f};
    acc2[1] = (fx4){0.f, 0.f, 0.f, 0.f};
    {
        bx8 ahi[2], alo[2];
        int row = base + wv * 16 + lm;
        const float* hp = h1g + (size_t)row * 64 + lg * 8;
        #pragma unroll
        for (int ks = 0; ks < 2; ++ks) {
            float4 a0, a1;
            if (row < n) {
                a0 = *(const float4*)(hp + ks * 32);
                a1 = *(const float4*)(hp + ks * 32 + 4);
            } else {
                a0 = make_float4(0.f, 0.f, 0.f, 0.f);
                a1 = make_float4(0.f, 0.f, 0.f, 0.f);
            }
            float ff[8] = { a0.x, a0.y, a0.z, a0.w, a1.x, a1.y, a1.z, a1.w };
            #pragma unroll
            for (int i = 0; i < 8; ++i) {
                unsigned short hb = f32_to_bf16_rne(ff[i]);
                float rem = ff[i] - bf16_bits_to_f32(hb);
                ahi[ks][i] = (short)hb;
                alo[ks][i] = (short)f32_to_bf16_rne(rem);
            }
        }
        #pragma unroll
        for (int nt = 0; nt < 2; ++nt) {
            #pragma unroll
            for (int ks = 0; ks < 2; ++ks) {
                int c = nt * 2 + ks;
                bx8 bh = *(const bx8*)&w2f_hi[((size_t)c * 64 + lane) * 8];
                bx8 bl = *(const bx8*)&w2f_lo[((size_t)c * 64 + lane) * 8];
                acc2[nt] = __builtin_amdgcn_mfma_f32_16x16x32_bf16(ahi[ks], bh, acc2[nt], 0, 0, 0);
                acc2[nt] = __builtin_amdgcn_mfma_f32_16x16x32_bf16(ahi[ks], bl, acc2[nt], 0, 0, 0);
                acc2[nt] = __builtin_amdgcn_mfma_f32_16x16x32_bf16(alo[ks], bh, acc2[nt], 0, 0, 0);
            }
        }
    }
    #pragma unroll
    for (int nt = 0; nt < 2; ++nt) {
        #pragma unroll
        for (int r = 0; r < 4; ++r) {
            int lrow = wv * 16 + lg * 4 + r;
            int node = base + lrow;
            float v = acc2[nt][r];
            if (node < n) oh2[(size_t)node * 32 + nt * 16 + lm] = v;
            lds2[lrow * 36 + nt * 16 + lm] = v;
        }
    }
    __syncthreads();

    // ---- step 2: h3 = elu(h2 @ l1w^T + l1b) ----
    fx4 acc3[4];
    #pragma unroll
    for (int nt = 0; nt < 4; ++nt) acc3[nt] = (fx4){0.f, 0.f, 0.f, 0.f};
    {
        bx8 ahi, alo;
        {
            const float* ap = &lds2[(wv * 16 + lm) * 36 + lg * 8];
            float4 a0 = *(const float4*)ap;
            float4 a1 = *(const float4*)(ap + 4);
            float ff[8] = { a0.x, a0.y, a0.z, a0.w, a1.x, a1.y, a1.z, a1.w };
            #pragma unroll
            for (int i = 0; i < 8; ++i) {
                unsigned short hb = f32_to_bf16_rne(ff[i]);
                float rem = ff[i] - bf16_bits_to_f32(hb);
                ahi[i] = (short)hb;
                alo[i] = (short)f32_to_bf16_rne(rem);
            }
        }
        #pragma unroll
        for (int nt = 0; nt < 4; ++nt) {
            bx8 bh = *(const bx8*)&l1f_hi[((size_t)nt * 64 + lane) * 8];
            bx8 bl = *(const bx8*)&l1f_lo[((size_t)nt * 64 + lane) * 8];
            acc3[nt] = __builtin_amdgcn_mfma_f32_16x16x32_bf16(ahi, bh, acc3[nt], 0, 0, 0);
            acc3[nt] = __builtin_amdgcn_mfma_f32_16x16x32_bf16(ahi, bl, acc3[nt], 0, 0, 0);
            acc3[nt] = __builtin_amdgcn_mfma_f32_16x16x32_bf16(alo, bh, acc3[nt], 0, 0, 0);
        }
    }
    #pragma unroll
    for (int nt = 0; nt < 4; ++nt) {
        float b = l1b[nt * 16 + lm];
        #pragma unroll
        for (int r = 0; r < 4; ++r) {
            int lrow = wv * 16 + lg * 4 + r;
            lds3[lrow * 68 + nt * 16 + lm] = eluf(acc3[nt][r] + b);
        }
    }
    __syncthreads();

    // ---- step 3: h4 = h3 @ l2w^T + l2b ----
    float bias[4];
    #pragma unroll
    for (int ct = 0; ct < 4; ++ct) bias[ct] = l2b[wv * 64 + ct * 16 + lm];

    #pragma unroll
    for (int mt = 0; mt < 4; ++mt) {
        bx8 ahi[2], alo[2];
        #pragma unroll
        for (int ks = 0; ks < 2; ++ks) {
            const float* ap = &lds3[(mt * 16 + lm) * 68 + ks * 32 + lg * 8];
            float4 a0 = *(const float4*)ap;
            float4 a1 = *(const float4*)(ap + 4);
            float ff[8] = { a0.x, a0.y, a0.z, a0.w, a1.x, a1.y, a1.z, a1.w };
            #pragma unroll
            for (int i = 0; i < 8; ++i) {
                unsigned short hb = f32_to_bf16_rne(ff[i]);
                float rem = ff[i] - bf16_bits_to_f32(hb);
                ahi[ks][i] = (short)hb;
                alo[ks][i] = (short)f32_to_bf16_rne(rem);
            }
        }
        fx4 acc[4];
        #pragma unroll
        for (int ct = 0; ct < 4; ++ct) acc[ct] = (fx4){0.f, 0.f, 0.f, 0.f};
        #pragma unroll
        for (int ct = 0; ct < 4; ++ct) {
            #pragma unroll
            for (int ks = 0; ks < 2; ++ks) {
                int c = wv * 8 + ct * 2 + ks;
                bx8 bh = *(const bx8*)&l2f_hi[((size_t)c * 64 + lane) * 8];
                bx8 bl = *(const bx8*)&l2f_lo[((size_t)c * 64 + lane) * 8];
                acc[ct] = __builtin_amdgcn_mfma_f32_16x16x32_bf16(ahi[ks], bh, acc[ct], 0, 0, 0);
                acc[ct] = __builtin_amdgcn_mfma_f32_16x16x32_bf16(ahi[ks], bl, acc[ct], 0, 0, 0);
                acc[ct] = __builtin_amdgcn_mfma_f32_16x16x32_bf16(alo[ks], bh, acc[ct], 0, 0, 0);
            }
        }
        #pragma unroll
        for (int ct = 0; ct < 4; ++ct) {
            #pragma unroll
            for (int r = 0; r < 4; ++r) {
                int orow = base + mt * 16 + lg * 4 + r;
                if (orow < n) {
                    int ocol = wv * 64 + ct * 16 + lm;
                    oh4[(size_t)orow * 256 + ocol] = acc[ct][r] + bias[ct];
                }
            }
        }
    }
}

extern "C" void kernel_launch(void* const* d_in, const int* in_sizes, int n_in,
                              void* d_out, int out_size, void* d_ws, size_t ws_size,
                              hipStream_t stream) {
    const float* feat    = (const float*)d_in[0];
    const int*   ei      = (const int*)d_in[1];     // int64 in ref -> int32 on device
    const float* w1      = (const float*)d_in[2];
    const float* att_src = (const float*)d_in[3];
    const float* att_dst = (const float*)d_in[4];
    const float* w2      = (const float*)d_in[5];
    const float* l1w     = (const float*)d_in[6];
    const float* l1b     = (const float*)d_in[7];
    const float* l2w     = (const float*)d_in[8];
    const float* l2b     = (const float*)d_in[9];

    const int N = in_sizes[0] / IN_DIM;
    const int E = in_sizes[1] / 2;

    char* p = (char*)d_ws;
    auto alloc = [&](size_t bytes) {
        char* r = p;
        p += (bytes + 255) & ~(size_t)255;
        return r;
    };
    unsigned short* h_bf = (unsigned short*)alloc((size_t)N * HID * 2);
    float* h1g   = (float*)alloc((size_t)N * HID * 4);
    float* as_   = (float*)alloc((size_t)N * 4);
    float* ad_   = (float*)alloc((size_t)N * 4);
    int*   deg   = (int*)alloc((size_t)N * 4);
    int*   off   = (int*)alloc((size_t)(N + 1) * 4);
    int*   rank  = (int*)alloc((size_t)E * 4);
    int2*  edata = (int2*)alloc((size_t)E * 8);
    const int nb = (N + 1023) / 1024;
    int*   part  = (int*)alloc((size_t)nb * 4);
    short* w2f_hi = (short*)alloc(4 * 64 * 8 * 2);
    short* w2f_lo = (short*)alloc(4 * 64 * 8 * 2);
    short* l1f_hi = (short*)alloc(4 * 64 * 8 * 2);
    short* l1f_lo = (short*)alloc(4 * 64 * 8 * 2);
    short* l2f_hi = (short*)alloc(32 * 64 * 8 * 2);
    short* l2f_lo = (short*)alloc(32 * 64 * 8 * 2);

    float* oh2 = (float*)d_out;
    float* oh4 = oh2 + (size_t)N * OUTD;

    hipLaunchKernelGGL(k_init, dim3(256), dim3(256), 0, stream, deg, N);
    hipLaunchKernelGGL(k_wconv, dim3(1), dim3(256), 0, stream,
                       w2, l1w, l2w, w2f_hi, w2f_lo, l1f_hi, l1f_lo, l2f_hi, l2f_lo);
    hipLaunchKernelGGL(k_feat_mfma, dim3((N + 63) / 64), dim3(256), 0, stream,
                       feat, w1, att_src, att_dst, h_bf, as_, ad_, N);
    hipLaunchKernelGGL(k_deg, dim3(2048), dim3(256), 0, stream, ei, deg, rank, E);
    hipLaunchKernelGGL(k_scan_part, dim3(nb), dim3(1024), 0, stream, deg, part, N);
    hipLaunchKernelGGL(k_scan_top, dim3(1), dim3(1024), 0, stream, part, off, nb, N);
    hipLaunchKernelGGL(k_scan_down, dim3(nb), dim3(1024), 0, stream, deg, part, off, N);
    for (int pass = 0; pass < 4; ++pass) {
        int lo = (int)((size_t)N * pass / 4);
        int hi = (int)((size_t)N * (pass + 1) / 4);
        hipLaunchKernelGGL(k_fill, dim3(2048), dim3(256), 0, stream,
                           ei, as_, ad_, off, rank, edata, E, lo, hi);
    }
    hipLaunchKernelGGL(k_gatw, dim3((N + 3) / 4), dim3(256), 0, stream, off, edata, N);
    hipLaunchKernelGGL(k_gata, dim3((N + 3) / 4), dim3(256), 0, stream,
                       off, edata, h_bf, h1g, N);
    hipLaunchKernelGGL(k_mlp_fused, dim3((N + 63) / 64), dim3(256), 0, stream,
                       h1g, w2f_hi, w2f_lo, l1f_hi, l1f_lo, l2f_hi, l2f_lo,
                       l1b, l2b, oh2, oh4, N);
}

// Round 14
// 272.989 us; speedup vs baseline: 3.2834x; 1.1614x over previous
//
#include <hip/hip_runtime.h>
#include <math.h>

constexpr int IN_DIM = 256;
constexpr int HID    = 64;
constexpr int OUTD   = 32;
#define NEG_SLOPE 0.2f
#define EPSV 1e-16f

__device__ __forceinline__ float eluf(float x) {
    return x > 0.f ? x : expm1f(x);
}

__device__ __forceinline__ unsigned short f32_to_bf16_rne(float f) {
    unsigned u = __float_as_uint(f);
    unsigned r = u + 0x7fffu + ((u >> 16) & 1u);
    return (unsigned short)(r >> 16);
}
__device__ __forceinline__ float bf16_bits_to_f32(unsigned short s) {
    return __uint_as_float(((unsigned)s) << 16);
}

// ---------------- init: zero deg ----------------
__global__ void k_init(int* __restrict__ deg, int n) {
    int i = blockIdx.x * blockDim.x + threadIdx.x;
    int stride = gridDim.x * blockDim.x;
    for (; i < n; i += stride) deg[i] = 0;
}

// ---------------- one-shot weight fragment conversion (1 block) ----------------
__global__ __launch_bounds__(256) void k_wconv(
    const float* __restrict__ w2, const float* __restrict__ l1w,
    const float* __restrict__ l2w,
    short* __restrict__ w2f_hi, short* __restrict__ w2f_lo,
    short* __restrict__ l1f_hi, short* __restrict__ l1f_lo,
    short* __restrict__ l2f_hi, short* __restrict__ l2f_lo)
{
    int t = threadIdx.x;
    int lane = t & 63, combo = t >> 6;
    int lm = lane & 15, lg = lane >> 4;

    {
        int nt = combo >> 1, ks = combo & 1;
        #pragma unroll
        for (int i = 0; i < 8; ++i) {
            float f = w2[(size_t)(ks * 32 + lg * 8 + i) * 32 + nt * 16 + lm];
            unsigned short hb = f32_to_bf16_rne(f);
            float rem = f - bf16_bits_to_f32(hb);
            w2f_hi[((size_t)combo * 64 + lane) * 8 + i] = (short)hb;
            w2f_lo[((size_t)combo * 64 + lane) * 8 + i] = (short)f32_to_bf16_rne(rem);
        }
    }
    {
        int nt = combo;
        #pragma unroll
        for (int i = 0; i < 8; ++i) {
            float f = l1w[(size_t)(nt * 16 + lm) * 32 + lg * 8 + i];
            unsigned short hb = f32_to_bf16_rne(f);
            float rem = f - bf16_bits_to_f32(hb);
            l1f_hi[((size_t)combo * 64 + lane) * 8 + i] = (short)hb;
            l1f_lo[((size_t)combo * 64 + lane) * 8 + i] = (short)f32_to_bf16_rne(rem);
        }
    }
    for (int it = 0; it < 8; ++it) {
        int c = it * 4 + combo;
        int wv = c >> 3, ct = (c >> 1) & 3, ks = c & 1;
        #pragma unroll
        for (int i = 0; i < 8; ++i) {
            float f = l2w[(size_t)(wv * 64 + ct * 16 + lm) * 64 + ks * 32 + lg * 8 + i];
            unsigned short hb = f32_to_bf16_rne(f);
            float rem = f - bf16_bits_to_f32(hb);
            l2f_hi[((size_t)c * 64 + lane) * 8 + i] = (short)hb;
            l2f_lo[((size_t)c * 64 + lane) * 8 + i] = (short)f32_to_bf16_rne(rem);
        }
    }
}

// ---------------- fused: h = feat@w1 (MFMA) blocks  +  deg/rank atomic blocks ----
// Role by blockIdx%5: pos<4 -> feat tile fb = (bid/5)*4+pos; pos==4 -> deg chunk.
// Independent inputs; deg blocks idle on atomic returns while feat blocks use
// MFMA/HBM -> co-residency hides the atomic-throughput-bound k_deg time.
__global__ __launch_bounds__(256) void k_feat_deg(
    const float* __restrict__ feat, const float* __restrict__ w1,
    const float* __restrict__ att_src, const float* __restrict__ att_dst,
    unsigned short* __restrict__ h_bf, float* __restrict__ as_,
    float* __restrict__ ad_,
    const int* __restrict__ ei, int* __restrict__ deg, int* __restrict__ rank,
    int n, int e, int nDegBlocks)
{
    typedef __attribute__((ext_vector_type(8))) short bx8;
    typedef __attribute__((ext_vector_type(4))) float fx4;

    __shared__ short a_hi[4 * 8 * 64 * 8];   // 32 KB
    __shared__ short a_lo[4 * 8 * 64 * 8];   // 32 KB
    __shared__ float al_part[2][4][64];

    int bid = blockIdx.x;
    int grp = bid / 5, pos = bid % 5;
    int t = threadIdx.x, lane = t & 63, wv = t >> 6;

    if (pos == 4) {
        // ---- deg role ----
        if (grp >= nDegBlocks) return;
        int i = grp * 256 + t;
        int stride = nDegBlocks * 256;
        for (; i < e; i += stride) {
            int d = ei[(size_t)e + i];
            rank[i] = atomicAdd(&deg[d], 1);
        }
        return;
    }

    int fb = grp * 4 + pos;
    int base = fb * 64;
    if (base >= n) return;

    // ---- B (w1) fragments -> registers, hi/lo split ----
    bx8 bhi[8], blo[8];
    {
        int nj = wv * 16 + (lane & 15);
        int kg = (lane >> 4) * 8;
        #pragma unroll
        for (int ks = 0; ks < 8; ++ks) {
            #pragma unroll
            for (int i = 0; i < 8; ++i) {
                float f = w1[(size_t)(ks * 32 + kg + i) * 64 + nj];
                unsigned short hb = f32_to_bf16_rne(f);
                float rem = f - bf16_bits_to_f32(hb);
                bhi[ks][i] = (short)hb;
                blo[ks][i] = (short)f32_to_bf16_rne(rem);
            }
        }
    }

    float4 v[16];
    #pragma unroll
    for (int c = 0; c < 8; ++c) {
        int node = (t >> 5) + c * 8;
        int oct = t & 31;
        int gn = base + node;
        if (gn < n) {
            const float4* fp = (const float4*)(feat + (size_t)gn * 256);
            v[2 * c]     = fp[oct * 2];
            v[2 * c + 1] = fp[oct * 2 + 1];
        } else {
            v[2 * c]     = make_float4(0.f, 0.f, 0.f, 0.f);
            v[2 * c + 1] = make_float4(0.f, 0.f, 0.f, 0.f);
        }
    }
    #pragma unroll
    for (int c = 0; c < 8; ++c) {
        int node = (t >> 5) + c * 8;
        int oct = t & 31;
        int mt = node >> 4, lm = node & 15;
        int ks = oct >> 2, lg = oct & 3;
        int flane = lg * 16 + lm;
        int idx = (((mt * 8 + ks) * 64) + (flane ^ ks)) * 8;
        float ff[8] = { v[2*c].x, v[2*c].y, v[2*c].z, v[2*c].w,
                        v[2*c+1].x, v[2*c+1].y, v[2*c+1].z, v[2*c+1].w };
        bx8 hv, lv;
        #pragma unroll
        for (int i = 0; i < 8; ++i) {
            unsigned short hb = f32_to_bf16_rne(ff[i]);
            float rem = ff[i] - bf16_bits_to_f32(hb);
            hv[i] = (short)hb;
            lv[i] = (short)f32_to_bf16_rne(rem);
        }
        *(bx8*)&a_hi[idx] = hv;
        *(bx8*)&a_lo[idx] = lv;
    }
    __syncthreads();

    fx4 acc[4];
    #pragma unroll
    for (int mt = 0; mt < 4; ++mt) acc[mt] = (fx4){0.f, 0.f, 0.f, 0.f};
    #pragma unroll
    for (int mt = 0; mt < 4; ++mt) {
        #pragma unroll
        for (int ks = 0; ks < 8; ++ks) {
            int idx = (((mt * 8 + ks) * 64) + (lane ^ ks)) * 8;
            bx8 ah = *(bx8*)&a_hi[idx];
            bx8 al = *(bx8*)&a_lo[idx];
            acc[mt] = __builtin_amdgcn_mfma_f32_16x16x32_bf16(ah, bhi[ks], acc[mt], 0, 0, 0);
            acc[mt] = __builtin_amdgcn_mfma_f32_16x16x32_bf16(ah, blo[ks], acc[mt], 0, 0, 0);
            acc[mt] = __builtin_amdgcn_mfma_f32_16x16x32_bf16(al, bhi[ks], acc[mt], 0, 0, 0);
        }
    }

    float asj = att_src[wv * 16 + (lane & 15)];
    float adj = att_dst[wv * 16 + (lane & 15)];
    #pragma unroll
    for (int mt = 0; mt < 4; ++mt) {
        #pragma unroll
        for (int r = 0; r < 4; ++r) {
            int lrow = mt * 16 + (lane >> 4) * 4 + r;
            int node = base + lrow;
            float hv = acc[mt][r];
            if (node < n)
                h_bf[(size_t)node * 64 + wv * 16 + (lane & 15)] = f32_to_bf16_rne(hv);
            float p1 = hv * asj, p2 = hv * adj;
            p1 += __shfl_xor(p1, 1);  p2 += __shfl_xor(p2, 1);
            p1 += __shfl_xor(p1, 2);  p2 += __shfl_xor(p2, 2);
            p1 += __shfl_xor(p1, 4);  p2 += __shfl_xor(p2, 4);
            p1 += __shfl_xor(p1, 8);  p2 += __shfl_xor(p2, 8);
            if ((lane & 15) == 0) {
                al_part[0][wv][lrow] = p1;
                al_part[1][wv][lrow] = p2;
            }
        }
    }
    __syncthreads();
    if (t < 64) {
        int node = base + t;
        if (node < n) {
            as_[node] = al_part[0][0][t] + al_part[0][1][t] + al_part[0][2][t] + al_part[0][3][t];
            ad_[node] = al_part[1][0][t] + al_part[1][1][t] + al_part[1][2][t] + al_part[1][3][t];
        }
    }
}

// ---------------- multi-block exclusive scan, 3 phases ----------------
__global__ __launch_bounds__(1024) void k_scan_part(const int* __restrict__ deg,
                                                    int* __restrict__ part, int n) {
    __shared__ int wlds[16];
    int t = threadIdx.x, lane = t & 63, wv = t >> 6;
    int idx = blockIdx.x * 1024 + t;
    int v = (idx < n) ? deg[idx] : 0;
    #pragma unroll
    for (int s = 32; s > 0; s >>= 1) v += __shfl_xor(v, s);
    if (lane == 0) wlds[wv] = v;
    __syncthreads();
    if (t == 0) {
        int s = 0;
        #pragma unroll
        for (int w = 0; w < 16; ++w) s += wlds[w];
        part[blockIdx.x] = s;
    }
}

__global__ __launch_bounds__(1024) void k_scan_top(int* __restrict__ part,
                                                   int* __restrict__ off,
                                                   int nb, int n) {
    __shared__ int wsum[16];
    int t = threadIdx.x, lane = t & 63, wv = t >> 6;
    int v = (t < nb) ? part[t] : 0;
    int x = v;
    #pragma unroll
    for (int i = 1; i < 64; i <<= 1) {
        int u = __shfl_up(x, i);
        if (lane >= i) x += u;
    }
    if (lane == 63) wsum[wv] = x;
    __syncthreads();
    int add = 0;
    for (int w = 0; w < wv; ++w) add += wsum[w];
    if (t < nb) part[t] = x - v + add;
    if (t == nb - 1) off[n] = x + add;
}

__global__ __launch_bounds__(1024) void k_scan_down(const int* __restrict__ deg,
                                                    const int* __restrict__ part,
                                                    int* __restrict__ off, int n) {
    __shared__ int wsum[16];
    int t = threadIdx.x, lane = t & 63, wv = t >> 6;
    int idx = blockIdx.x * 1024 + t;
    int v = (idx < n) ? deg[idx] : 0;
    int x = v;
    #pragma unroll
    for (int i = 1; i < 64; i <<= 1) {
        int u = __shfl_up(x, i);
        if (lane >= i) x += u;
    }
    if (lane == 63) wsum[wv] = x;
    __syncthreads();
    int add = 0;
    for (int w = 0; w < wv; ++w) add += wsum[w];
    if (idx < n) off[idx] = x - v + add + part[blockIdx.x];
}

// ---------------- fill CSR (no atomics): edata[pos] = {src, leakyrelu(e)} ----
__global__ void k_fill(const int* __restrict__ ei, const float* __restrict__ as_,
                       const float* __restrict__ ad_, const int* __restrict__ off,
                       const int* __restrict__ rank, int2* __restrict__ edata,
                       int e, int lo, int hi) {
    int i = blockIdx.x * blockDim.x + threadIdx.x;
    int stride = gridDim.x * blockDim.x;
    for (; i < e; i += stride) {
        int d = ei[(size_t)e + i];
        if (d < lo || d >= hi) continue;
        int s = ei[i];
        float v = as_[s] + ad_[d];
        v = v > 0.f ? v : NEG_SLOPE * v;
        edata[off[d] + rank[i]] = make_int2(s, __float_as_int(v));
    }
}

// ---------------- softmax weights in-place on edata.y ----------------
__global__ __launch_bounds__(256) void k_gatw(const int* __restrict__ off,
                                              int2* __restrict__ edata, int n) {
    int lane = threadIdx.x & 63;
    int d = blockIdx.x * 4 + (threadIdx.x >> 6);
    if (d >= n) return;
    int beg = off[d], end = off[d + 1];
    float m = -3.0e38f;
    for (int i = beg + lane; i < end; i += 64)
        m = fmaxf(m, __int_as_float(edata[i].y));
    #pragma unroll
    for (int s = 32; s > 0; s >>= 1) m = fmaxf(m, __shfl_xor(m, s));

    int i0 = beg + lane;
    float e0 = 0.f, z = 0.f;
    if (i0 < end) { e0 = __expf(__int_as_float(edata[i0].y) - m); z = e0; }
    for (int i = i0 + 64; i < end; i += 64) {
        float e = __expf(__int_as_float(edata[i].y) - m);
        edata[i].y = __float_as_int(e);
        z += e;
    }
    #pragma unroll
    for (int s = 32; s > 0; s >>= 1) z += __shfl_xor(z, s);
    float rz = 1.f / (z + EPSV);
    if (i0 < end) edata[i0].y = __float_as_int(e0 * rz);
    for (int i = i0 + 64; i < end; i += 64)
        edata[i].y = __float_as_int(__int_as_float(edata[i].y) * rz);
}

// ---------------- weighted aggregate + elu -> h1 (bf16 h gather) ----------------
__global__ __launch_bounds__(256) void k_gata(const int* __restrict__ off,
                                              const int2* __restrict__ edata,
                                              const unsigned short* __restrict__ h_bf,
                                              float* __restrict__ h1, int n) {
    int lane = threadIdx.x & 63;
    int d = blockIdx.x * 4 + (threadIdx.x >> 6);
    if (d >= n) return;
    int beg = off[d], end = off[d + 1];
    float a0 = 0.f, a1 = 0.f, a2 = 0.f, a3 = 0.f;
    int i = beg;
    for (; i + 4 <= end; i += 4) {
        int2 e0 = edata[i],     e1 = edata[i + 1];
        int2 e2 = edata[i + 2], e3 = edata[i + 3];
        float v0 = bf16_bits_to_f32(h_bf[(size_t)e0.x * 64 + lane]);
        float v1 = bf16_bits_to_f32(h_bf[(size_t)e1.x * 64 + lane]);
        float v2 = bf16_bits_to_f32(h_bf[(size_t)e2.x * 64 + lane]);
        float v3 = bf16_bits_to_f32(h_bf[(size_t)e3.x * 64 + lane]);
        a0 += __int_as_float(e0.y) * v0;
        a1 += __int_as_float(e1.y) * v1;
        a2 += __int_as_float(e2.y) * v2;
        a3 += __int_as_float(e3.y) * v3;
    }
    for (; i < end; ++i) {
        int2 ed = edata[i];
        a0 += __int_as_float(ed.y) * bf16_bits_to_f32(h_bf[(size_t)ed.x * 64 + lane]);
    }
    h1[(size_t)d * 64 + lane] = eluf((a0 + a1) + (a2 + a3));
}

// ---------------- fused node MLP via bf16-split MFMA (pre-converted weights) ----
__global__ __launch_bounds__(256) void k_mlp_fused(
    const float* __restrict__ h1g,
    const short* __restrict__ w2f_hi, const short* __restrict__ w2f_lo,
    const short* __restrict__ l1f_hi, const short* __restrict__ l1f_lo,
    const short* __restrict__ l2f_hi, const short* __restrict__ l2f_lo,
    const float* __restrict__ l1b, const float* __restrict__ l2b,
    float* __restrict__ oh2, float* __restrict__ oh4, int n)
{
    typedef __attribute__((ext_vector_type(8))) short bx8;
    typedef __attribute__((ext_vector_type(4))) float fx4;

    __shared__ float lds2[64 * 36];
    __shared__ float lds3[64 * 68];

    int t = threadIdx.x, lane = t & 63, wv = t >> 6;
    int base = blockIdx.x * 64;
    int lm = lane & 15, lg = lane >> 4;

    fx4 acc2[2];
    acc2[0] = (fx4){0.f, 0.f, 0.f, 0.f};
    acc2[1] = (fx4){0.f, 0.f, 0.f, 0.f};
    {
        bx8 ahi[2], alo[2];
        int row = base + wv * 16 + lm;
        const float* hp = h1g + (size_t)row * 64 + lg * 8;
        #pragma unroll
        for (int ks = 0; ks < 2; ++ks) {
            float4 a0, a1;
            if (row < n) {
                a0 = *(const float4*)(hp + ks * 32);
                a1 = *(const float4*)(hp + ks * 32 + 4);
            } else {
                a0 = make_float4(0.f, 0.f, 0.f, 0.f);
                a1 = make_float4(0.f, 0.f, 0.f, 0.f);
            }
            float ff[8] = { a0.x, a0.y, a0.z, a0.w, a1.x, a1.y, a1.z, a1.w };
            #pragma unroll
            for (int i = 0; i < 8; ++i) {
                unsigned short hb = f32_to_bf16_rne(ff[i]);
                float rem = ff[i] - bf16_bits_to_f32(hb);
                ahi[ks][i] = (short)hb;
                alo[ks][i] = (short)f32_to_bf16_rne(rem);
            }
        }
        #pragma unroll
        for (int nt = 0; nt < 2; ++nt) {
            #pragma unroll
            for (int ks = 0; ks < 2; ++ks) {
                int c = nt * 2 + ks;
                bx8 bh = *(const bx8*)&w2f_hi[((size_t)c * 64 + lane) * 8];
                bx8 bl = *(const bx8*)&w2f_lo[((size_t)c * 64 + lane) * 8];
                acc2[nt] = __builtin_amdgcn_mfma_f32_16x16x32_bf16(ahi[ks], bh, acc2[nt], 0, 0, 0);
                acc2[nt] = __builtin_amdgcn_mfma_f32_16x16x32_bf16(ahi[ks], bl, acc2[nt], 0, 0, 0);
                acc2[nt] = __builtin_amdgcn_mfma_f32_16x16x32_bf16(alo[ks], bh, acc2[nt], 0, 0, 0);
            }
        }
    }
    #pragma unroll
    for (int nt = 0; nt < 2; ++nt) {
        #pragma unroll
        for (int r = 0; r < 4; ++r) {
            int lrow = wv * 16 + lg * 4 + r;
            int node = base + lrow;
            float v = acc2[nt][r];
            if (node < n) oh2[(size_t)node * 32 + nt * 16 + lm] = v;
            lds2[lrow * 36 + nt * 16 + lm] = v;
        }
    }
    __syncthreads();

    fx4 acc3[4];
    #pragma unroll
    for (int nt = 0; nt < 4; ++nt) acc3[nt] = (fx4){0.f, 0.f, 0.f, 0.f};
    {
        bx8 ahi, alo;
        {
            const float* ap = &lds2[(wv * 16 + lm) * 36 + lg * 8];
            float4 a0 = *(const float4*)ap;
            float4 a1 = *(const float4*)(ap + 4);
            float ff[8] = { a0.x, a0.y, a0.z, a0.w, a1.x, a1.y, a1.z, a1.w };
            #pragma unroll
            for (int i = 0; i < 8; ++i) {
                unsigned short hb = f32_to_bf16_rne(ff[i]);
                float rem = ff[i] - bf16_bits_to_f32(hb);
                ahi[i] = (short)hb;
                alo[i] = (short)f32_to_bf16_rne(rem);
            }
        }
        #pragma unroll
        for (int nt = 0; nt < 4; ++nt) {
            bx8 bh = *(const bx8*)&l1f_hi[((size_t)nt * 64 + lane) * 8];
            bx8 bl = *(const bx8*)&l1f_lo[((size_t)nt * 64 + lane) * 8];
            acc3[nt] = __builtin_amdgcn_mfma_f32_16x16x32_bf16(ahi, bh, acc3[nt], 0, 0, 0);
            acc3[nt] = __builtin_amdgcn_mfma_f32_16x16x32_bf16(ahi, bl, acc3[nt], 0, 0, 0);
            acc3[nt] = __builtin_amdgcn_mfma_f32_16x16x32_bf16(alo, bh, acc3[nt], 0, 0, 0);
        }
    }
    #pragma unroll
    for (int nt = 0; nt < 4; ++nt) {
        float b = l1b[nt * 16 + lm];
        #pragma unroll
        for (int r = 0; r < 4; ++r) {
            int lrow = wv * 16 + lg * 4 + r;
            lds3[lrow * 68 + nt * 16 + lm] = eluf(acc3[nt][r] + b);
        }
    }
    __syncthreads();

    float bias[4];
    #pragma unroll
    for (int ct = 0; ct < 4; ++ct) bias[ct] = l2b[wv * 64 + ct * 16 + lm];

    #pragma unroll
    for (int mt = 0; mt < 4; ++mt) {
        bx8 ahi[2], alo[2];
        #pragma unroll
        for (int ks = 0; ks < 2; ++ks) {
            const float* ap = &lds3[(mt * 16 + lm) * 68 + ks * 32 + lg * 8];
            float4 a0 = *(const float4*)ap;
            float4 a1 = *(const float4*)(ap + 4);
            float ff[8] = { a0.x, a0.y, a0.z, a0.w, a1.x, a1.y, a1.z, a1.w };
            #pragma unroll
            for (int i = 0; i < 8; ++i) {
                unsigned short hb = f32_to_bf16_rne(ff[i]);
                float rem = ff[i] - bf16_bits_to_f32(hb);
                ahi[ks][i] = (short)hb;
                alo[ks][i] = (short)f32_to_bf16_rne(rem);
            }
        }
        fx4 acc[4];
        #pragma unroll
        for (int ct = 0; ct < 4; ++ct) acc[ct] = (fx4){0.f, 0.f, 0.f, 0.f};
        #pragma unroll
        for (int ct = 0; ct < 4; ++ct) {
            #pragma unroll
            for (int ks = 0; ks < 2; ++ks) {
                int c = wv * 8 + ct * 2 + ks;
                bx8 bh = *(const bx8*)&l2f_hi[((size_t)c * 64 + lane) * 8];
                bx8 bl = *(const bx8*)&l2f_lo[((size_t)c * 64 + lane) * 8];
                acc[ct] = __builtin_amdgcn_mfma_f32_16x16x32_bf16(ahi[ks], bh, acc[ct], 0, 0, 0);
                acc[ct] = __builtin_amdgcn_mfma_f32_16x16x32_bf16(ahi[ks], bl, acc[ct], 0, 0, 0);
                acc[ct] = __builtin_amdgcn_mfma_f32_16x16x32_bf16(alo[ks], bh, acc[ct], 0, 0, 0);
            }
        }
        #pragma unroll
        for (int ct = 0; ct < 4; ++ct) {
            #pragma unroll
            for (int r = 0; r < 4; ++r) {
                int orow = base + mt * 16 + lg * 4 + r;
                if (orow < n) {
                    int ocol = wv * 64 + ct * 16 + lm;
                    oh4[(size_t)orow * 256 + ocol] = acc[ct][r] + bias[ct];
                }
            }
        }
    }
}

extern "C" void kernel_launch(void* const* d_in, const int* in_sizes, int n_in,
                              void* d_out, int out_size, void* d_ws, size_t ws_size,
                              hipStream_t stream) {
    const float* feat    = (const float*)d_in[0];
    const int*   ei      = (const int*)d_in[1];     // int64 in ref -> int32 on device
    const float* w1      = (const float*)d_in[2];
    const float* att_src = (const float*)d_in[3];
    const float* att_dst = (const float*)d_in[4];
    const float* w2      = (const float*)d_in[5];
    const float* l1w     = (const float*)d_in[6];
    const float* l1b     = (const float*)d_in[7];
    const float* l2w     = (const float*)d_in[8];
    const float* l2b     = (const float*)d_in[9];

    const int N = in_sizes[0] / IN_DIM;
    const int E = in_sizes[1] / 2;

    char* p = (char*)d_ws;
    auto alloc = [&](size_t bytes) {
        char* r = p;
        p += (bytes + 255) & ~(size_t)255;
        return r;
    };
    unsigned short* h_bf = (unsigned short*)alloc((size_t)N * HID * 2);
    float* h1g   = (float*)alloc((size_t)N * HID * 4);
    float* as_   = (float*)alloc((size_t)N * 4);
    float* ad_   = (float*)alloc((size_t)N * 4);
    int*   deg   = (int*)alloc((size_t)N * 4);
    int*   off   = (int*)alloc((size_t)(N + 1) * 4);
    int*   rank  = (int*)alloc((size_t)E * 4);
    int2*  edata = (int2*)alloc((size_t)E * 8);
    const int nb = (N + 1023) / 1024;
    int*   part  = (int*)alloc((size_t)nb * 4);
    short* w2f_hi = (short*)alloc(4 * 64 * 8 * 2);
    short* w2f_lo = (short*)alloc(4 * 64 * 8 * 2);
    short* l1f_hi = (short*)alloc(4 * 64 * 8 * 2);
    short* l1f_lo = (short*)alloc(4 * 64 * 8 * 2);
    short* l2f_hi = (short*)alloc(32 * 64 * 8 * 2);
    short* l2f_lo = (short*)alloc(32 * 64 * 8 * 2);

    float* oh2 = (float*)d_out;
    float* oh4 = oh2 + (size_t)N * OUTD;

    hipLaunchKernelGGL(k_init, dim3(256), dim3(256), 0, stream, deg, N);
    hipLaunchKernelGGL(k_wconv, dim3(1), dim3(256), 0, stream,
                       w2, l1w, l2w, w2f_hi, w2f_lo, l1f_hi, l1f_lo, l2f_hi, l2f_lo);
    // fused feat + deg: groups of 5 blocks (4 feat tiles + 1 deg chunk)
    const int nDegBlocks = 512;
    const int nFeatTiles = (N + 63) / 64;
    const int nGroups    = max((nFeatTiles + 3) / 4, nDegBlocks);
    hipLaunchKernelGGL(k_feat_deg, dim3(nGroups * 5), dim3(256), 0, stream,
                       feat, w1, att_src, att_dst, h_bf, as_, ad_,
                       ei, deg, rank, N, E, nDegBlocks);
    hipLaunchKernelGGL(k_scan_part, dim3(nb), dim3(1024), 0, stream, deg, part, N);
    hipLaunchKernelGGL(k_scan_top, dim3(1), dim3(1024), 0, stream, part, off, nb, N);
    hipLaunchKernelGGL(k_scan_down, dim3(nb), dim3(1024), 0, stream, deg, part, off, N);
    for (int pass = 0; pass < 4; ++pass) {
        int lo = (int)((size_t)N * pass / 4);
        int hi = (int)((size_t)N * (pass + 1) / 4);
        hipLaunchKernelGGL(k_fill, dim3(2048), dim3(256), 0, stream,
                           ei, as_, ad_, off, rank, edata, E, lo, hi);
    }
    hipLaunchKernelGGL(k_gatw, dim3((N + 3) / 4), dim3(256), 0, stream, off, edata, N);
    hipLaunchKernelGGL(k_gata, dim3((N + 3) / 4), dim3(256), 0, stream,
                       off, edata, h_bf, h1g, N);
    hipLaunchKernelGGL(k_mlp_fused, dim3((N + 63) / 64), dim3(256), 0, stream,
                       h1g, w2f_hi, w2f_lo, l1f_hi, l1f_lo, l2f_hi, l2f_lo,
                       l1b, l2b, oh2, oh4, N);
}

// Round 15
// 240.622 us; speedup vs baseline: 3.7251x; 1.1345x over previous
//
#include <hip/hip_runtime.h>
#include <math.h>

constexpr int IN_DIM = 256;
constexpr int HID    = 64;
constexpr int OUTD   = 32;
#define NEG_SLOPE 0.2f
#define EPSV 1e-16f

__device__ __forceinline__ float eluf(float x) {
    return x > 0.f ? x : expm1f(x);
}

__device__ __forceinline__ unsigned short f32_to_bf16_rne(float f) {
    unsigned u = __float_as_uint(f);
    unsigned r = u + 0x7fffu + ((u >> 16) & 1u);
    return (unsigned short)(r >> 16);
}
__device__ __forceinline__ float bf16_bits_to_f32(unsigned short s) {
    return __uint_as_float(((unsigned)s) << 16);
}

// ---------------- init: zero deg ----------------
__global__ void k_init(int* __restrict__ deg, int n) {
    int i = blockIdx.x * blockDim.x + threadIdx.x;
    int stride = gridDim.x * blockDim.x;
    for (; i < n; i += stride) deg[i] = 0;
}

// ---------------- one-shot weight fragment conversion (1 block) ----------------
__global__ __launch_bounds__(256) void k_wconv(
    const float* __restrict__ w2, const float* __restrict__ l1w,
    const float* __restrict__ l2w,
    short* __restrict__ w2f_hi, short* __restrict__ w2f_lo,
    short* __restrict__ l1f_hi, short* __restrict__ l1f_lo,
    short* __restrict__ l2f_hi, short* __restrict__ l2f_lo)
{
    int t = threadIdx.x;
    int lane = t & 63, combo = t >> 6;
    int lm = lane & 15, lg = lane >> 4;

    {
        int nt = combo >> 1, ks = combo & 1;
        #pragma unroll
        for (int i = 0; i < 8; ++i) {
            float f = w2[(size_t)(ks * 32 + lg * 8 + i) * 32 + nt * 16 + lm];
            unsigned short hb = f32_to_bf16_rne(f);
            float rem = f - bf16_bits_to_f32(hb);
            w2f_hi[((size_t)combo * 64 + lane) * 8 + i] = (short)hb;
            w2f_lo[((size_t)combo * 64 + lane) * 8 + i] = (short)f32_to_bf16_rne(rem);
        }
    }
    {
        int nt = combo;
        #pragma unroll
        for (int i = 0; i < 8; ++i) {
            float f = l1w[(size_t)(nt * 16 + lm) * 32 + lg * 8 + i];
            unsigned short hb = f32_to_bf16_rne(f);
            float rem = f - bf16_bits_to_f32(hb);
            l1f_hi[((size_t)combo * 64 + lane) * 8 + i] = (short)hb;
            l1f_lo[((size_t)combo * 64 + lane) * 8 + i] = (short)f32_to_bf16_rne(rem);
        }
    }
    for (int it = 0; it < 8; ++it) {
        int c = it * 4 + combo;
        int wv = c >> 3, ct = (c >> 1) & 3, ks = c & 1;
        #pragma unroll
        for (int i = 0; i < 8; ++i) {
            float f = l2w[(size_t)(wv * 64 + ct * 16 + lm) * 64 + ks * 32 + lg * 8 + i];
            unsigned short hb = f32_to_bf16_rne(f);
            float rem = f - bf16_bits_to_f32(hb);
            l2f_hi[((size_t)c * 64 + lane) * 8 + i] = (short)hb;
            l2f_lo[((size_t)c * 64 + lane) * 8 + i] = (short)f32_to_bf16_rne(rem);
        }
    }
}

// ---------------- fused: h = feat@w1 (MFMA) blocks  +  deg/rank atomic blocks ----
__global__ __launch_bounds__(256) void k_feat_deg(
    const float* __restrict__ feat, const float* __restrict__ w1,
    const float* __restrict__ att_src, const float* __restrict__ att_dst,
    unsigned short* __restrict__ h_bf, float* __restrict__ as_,
    float* __restrict__ ad_,
    const int* __restrict__ ei, int* __restrict__ deg, int* __restrict__ rank,
    int n, int e, int nDegBlocks)
{
    typedef __attribute__((ext_vector_type(8))) short bx8;
    typedef __attribute__((ext_vector_type(4))) float fx4;

    __shared__ short a_hi[4 * 8 * 64 * 8];   // 32 KB
    __shared__ short a_lo[4 * 8 * 64 * 8];   // 32 KB
    __shared__ float al_part[2][4][64];

    int bid = blockIdx.x;
    int grp = bid / 5, pos = bid % 5;
    int t = threadIdx.x, lane = t & 63, wv = t >> 6;

    if (pos == 4) {
        if (grp >= nDegBlocks) return;
        int i = grp * 256 + t;
        int stride = nDegBlocks * 256;
        for (; i < e; i += stride) {
            int d = ei[(size_t)e + i];
            rank[i] = atomicAdd(&deg[d], 1);
        }
        return;
    }

    int fb = grp * 4 + pos;
    int base = fb * 64;
    if (base >= n) return;

    bx8 bhi[8], blo[8];
    {
        int nj = wv * 16 + (lane & 15);
        int kg = (lane >> 4) * 8;
        #pragma unroll
        for (int ks = 0; ks < 8; ++ks) {
            #pragma unroll
            for (int i = 0; i < 8; ++i) {
                float f = w1[(size_t)(ks * 32 + kg + i) * 64 + nj];
                unsigned short hb = f32_to_bf16_rne(f);
                float rem = f - bf16_bits_to_f32(hb);
                bhi[ks][i] = (short)hb;
                blo[ks][i] = (short)f32_to_bf16_rne(rem);
            }
        }
    }

    float4 v[16];
    #pragma unroll
    for (int c = 0; c < 8; ++c) {
        int node = (t >> 5) + c * 8;
        int oct = t & 31;
        int gn = base + node;
        if (gn < n) {
            const float4* fp = (const float4*)(feat + (size_t)gn * 256);
            v[2 * c]     = fp[oct * 2];
            v[2 * c + 1] = fp[oct * 2 + 1];
        } else {
            v[2 * c]     = make_float4(0.f, 0.f, 0.f, 0.f);
            v[2 * c + 1] = make_float4(0.f, 0.f, 0.f, 0.f);
        }
    }
    #pragma unroll
    for (int c = 0; c < 8; ++c) {
        int node = (t >> 5) + c * 8;
        int oct = t & 31;
        int mt = node >> 4, lm = node & 15;
        int ks = oct >> 2, lg = oct & 3;
        int flane = lg * 16 + lm;
        int idx = (((mt * 8 + ks) * 64) + (flane ^ ks)) * 8;
        float ff[8] = { v[2*c].x, v[2*c].y, v[2*c].z, v[2*c].w,
                        v[2*c+1].x, v[2*c+1].y, v[2*c+1].z, v[2*c+1].w };
        bx8 hv, lv;
        #pragma unroll
        for (int i = 0; i < 8; ++i) {
            unsigned short hb = f32_to_bf16_rne(ff[i]);
            float rem = ff[i] - bf16_bits_to_f32(hb);
            hv[i] = (short)hb;
            lv[i] = (short)f32_to_bf16_rne(rem);
        }
        *(bx8*)&a_hi[idx] = hv;
        *(bx8*)&a_lo[idx] = lv;
    }
    __syncthreads();

    fx4 acc[4];
    #pragma unroll
    for (int mt = 0; mt < 4; ++mt) acc[mt] = (fx4){0.f, 0.f, 0.f, 0.f};
    #pragma unroll
    for (int mt = 0; mt < 4; ++mt) {
        #pragma unroll
        for (int ks = 0; ks < 8; ++ks) {
            int idx = (((mt * 8 + ks) * 64) + (lane ^ ks)) * 8;
            bx8 ah = *(bx8*)&a_hi[idx];
            bx8 al = *(bx8*)&a_lo[idx];
            acc[mt] = __builtin_amdgcn_mfma_f32_16x16x32_bf16(ah, bhi[ks], acc[mt], 0, 0, 0);
            acc[mt] = __builtin_amdgcn_mfma_f32_16x16x32_bf16(ah, blo[ks], acc[mt], 0, 0, 0);
            acc[mt] = __builtin_amdgcn_mfma_f32_16x16x32_bf16(al, bhi[ks], acc[mt], 0, 0, 0);
        }
    }

    float asj = att_src[wv * 16 + (lane & 15)];
    float adj = att_dst[wv * 16 + (lane & 15)];
    #pragma unroll
    for (int mt = 0; mt < 4; ++mt) {
        #pragma unroll
        for (int r = 0; r < 4; ++r) {
            int lrow = mt * 16 + (lane >> 4) * 4 + r;
            int node = base + lrow;
            float hv = acc[mt][r];
            if (node < n)
                h_bf[(size_t)node * 64 + wv * 16 + (lane & 15)] = f32_to_bf16_rne(hv);
            float p1 = hv * asj, p2 = hv * adj;
            p1 += __shfl_xor(p1, 1);  p2 += __shfl_xor(p2, 1);
            p1 += __shfl_xor(p1, 2);  p2 += __shfl_xor(p2, 2);
            p1 += __shfl_xor(p1, 4);  p2 += __shfl_xor(p2, 4);
            p1 += __shfl_xor(p1, 8);  p2 += __shfl_xor(p2, 8);
            if ((lane & 15) == 0) {
                al_part[0][wv][lrow] = p1;
                al_part[1][wv][lrow] = p2;
            }
        }
    }
    __syncthreads();
    if (t < 64) {
        int node = base + t;
        if (node < n) {
            as_[node] = al_part[0][0][t] + al_part[0][1][t] + al_part[0][2][t] + al_part[0][3][t];
            ad_[node] = al_part[1][0][t] + al_part[1][1][t] + al_part[1][2][t] + al_part[1][3][t];
        }
    }
}

// ---------------- multi-block exclusive scan, 3 phases ----------------
__global__ __launch_bounds__(1024) void k_scan_part(const int* __restrict__ deg,
                                                    int* __restrict__ part, int n) {
    __shared__ int wlds[16];
    int t = threadIdx.x, lane = t & 63, wv = t >> 6;
    int idx = blockIdx.x * 1024 + t;
    int v = (idx < n) ? deg[idx] : 0;
    #pragma unroll
    for (int s = 32; s > 0; s >>= 1) v += __shfl_xor(v, s);
    if (lane == 0) wlds[wv] = v;
    __syncthreads();
    if (t == 0) {
        int s = 0;
        #pragma unroll
        for (int w = 0; w < 16; ++w) s += wlds[w];
        part[blockIdx.x] = s;
    }
}

__global__ __launch_bounds__(1024) void k_scan_top(int* __restrict__ part,
                                                   int* __restrict__ off,
                                                   int nb, int n) {
    __shared__ int wsum[16];
    int t = threadIdx.x, lane = t & 63, wv = t >> 6;
    int v = (t < nb) ? part[t] : 0;
    int x = v;
    #pragma unroll
    for (int i = 1; i < 64; i <<= 1) {
        int u = __shfl_up(x, i);
        if (lane >= i) x += u;
    }
    if (lane == 63) wsum[wv] = x;
    __syncthreads();
    int add = 0;
    for (int w = 0; w < wv; ++w) add += wsum[w];
    if (t < nb) part[t] = x - v + add;
    if (t == nb - 1) off[n] = x + add;
}

__global__ __launch_bounds__(1024) void k_scan_down(const int* __restrict__ deg,
                                                    const int* __restrict__ part,
                                                    int* __restrict__ off, int n) {
    __shared__ int wsum[16];
    int t = threadIdx.x, lane = t & 63, wv = t >> 6;
    int idx = blockIdx.x * 1024 + t;
    int v = (idx < n) ? deg[idx] : 0;
    int x = v;
    #pragma unroll
    for (int i = 1; i < 64; i <<= 1) {
        int u = __shfl_up(x, i);
        if (lane >= i) x += u;
    }
    if (lane == 63) wsum[wv] = x;
    __syncthreads();
    int add = 0;
    for (int w = 0; w < wv; ++w) add += wsum[w];
    if (idx < n) off[idx] = x - v + add + part[blockIdx.x];
}

// ---------------- fill CSR (no atomics): srcs[pos] = src only ----------------
__global__ void k_fill(const int* __restrict__ ei, const int* __restrict__ off,
                       const int* __restrict__ rank, int* __restrict__ srcs,
                       int e, int lo, int hi) {
    int i = blockIdx.x * blockDim.x + threadIdx.x;
    int stride = gridDim.x * blockDim.x;
    for (; i < e; i += stride) {
        int d = ei[(size_t)e + i];
        if (d < lo || d >= hi) continue;
        srcs[off[d] + rank[i]] = ei[i];
    }
}

// ---------------- fused softmax + aggregate per dst wave -> h1 (bf16) ----------
// 3 sweeps: max, sum, aggregate. e computed on the fly: leaky(as_[s] + ad_[d]).
__global__ __launch_bounds__(256) void k_gat(const int* __restrict__ off,
                                             const int* __restrict__ srcs,
                                             const float* __restrict__ as_,
                                             const float* __restrict__ ad_,
                                             const unsigned short* __restrict__ h_bf,
                                             unsigned short* __restrict__ h1b, int n) {
    int lane = threadIdx.x & 63;
    int d = blockIdx.x * 4 + (threadIdx.x >> 6);
    if (d >= n) return;
    int beg = off[d], end = off[d + 1];
    float adv = ad_[d];

    // sweep 1: max
    float m = -3.0e38f;
    for (int i = beg + lane; i < end; i += 64) {
        float ev = as_[srcs[i]] + adv;
        ev = ev > 0.f ? ev : NEG_SLOPE * ev;
        m = fmaxf(m, ev);
    }
    #pragma unroll
    for (int s = 32; s > 0; s >>= 1) m = fmaxf(m, __shfl_xor(m, s));

    // sweep 2: sum
    float z = 0.f;
    for (int i = beg + lane; i < end; i += 64) {
        float ev = as_[srcs[i]] + adv;
        ev = ev > 0.f ? ev : NEG_SLOPE * ev;
        z += __expf(ev - m);
    }
    #pragma unroll
    for (int s = 32; s > 0; s >>= 1) z += __shfl_xor(z, s);
    float rz = 1.f / (z + EPSV);

    // sweep 3: aggregate (chunked broadcast)
    float a0 = 0.f, a1 = 0.f, a2 = 0.f, a3 = 0.f;
    for (int chunk = beg; chunk < end; chunk += 64) {
        int idx = chunk + lane;
        int sreg = 0; float wreg = 0.f;
        if (idx < end) {
            sreg = srcs[idx];
            float ev = as_[sreg] + adv;
            ev = ev > 0.f ? ev : NEG_SLOPE * ev;
            wreg = __expf(ev - m) * rz;
        }
        int cnt = min(64, end - chunk);
        int j = 0;
        for (; j + 4 <= cnt; j += 4) {
            int   s0 = __shfl(sreg, j),     s1 = __shfl(sreg, j + 1);
            int   s2 = __shfl(sreg, j + 2), s3 = __shfl(sreg, j + 3);
            float w0 = __shfl(wreg, j),     w1 = __shfl(wreg, j + 1);
            float w2 = __shfl(wreg, j + 2), w3 = __shfl(wreg, j + 3);
            a0 += w0 * bf16_bits_to_f32(h_bf[(size_t)s0 * 64 + lane]);
            a1 += w1 * bf16_bits_to_f32(h_bf[(size_t)s1 * 64 + lane]);
            a2 += w2 * bf16_bits_to_f32(h_bf[(size_t)s2 * 64 + lane]);
            a3 += w3 * bf16_bits_to_f32(h_bf[(size_t)s3 * 64 + lane]);
        }
        for (; j < cnt; ++j) {
            int   sj = __shfl(sreg, j);
            float wj = __shfl(wreg, j);
            a0 += wj * bf16_bits_to_f32(h_bf[(size_t)sj * 64 + lane]);
        }
    }
    h1b[(size_t)d * 64 + lane] = f32_to_bf16_rne(eluf((a0 + a1) + (a2 + a3)));
}

// ---------------- fused node MLP via MFMA (bf16 h1 in, pre-converted weights) ----
__global__ __launch_bounds__(256) void k_mlp_fused(
    const unsigned short* __restrict__ h1b,
    const short* __restrict__ w2f_hi, const short* __restrict__ w2f_lo,
    const short* __restrict__ l1f_hi, const short* __restrict__ l1f_lo,
    const short* __restrict__ l2f_hi, const short* __restrict__ l2f_lo,
    const float* __restrict__ l1b, const float* __restrict__ l2b,
    float* __restrict__ oh2, float* __restrict__ oh4, int n)
{
    typedef __attribute__((ext_vector_type(8))) short bx8;
    typedef __attribute__((ext_vector_type(4))) float fx4;

    __shared__ float lds2[64 * 36];
    __shared__ float lds3[64 * 68];

    int t = threadIdx.x, lane = t & 63, wv = t >> 6;
    int base = blockIdx.x * 64;
    int lm = lane & 15, lg = lane >> 4;

    // ---- step 1: h2 = h1 @ w2 ; h1 is exact bf16 -> no A split (2 MFMAs) ----
    fx4 acc2[2];
    acc2[0] = (fx4){0.f, 0.f, 0.f, 0.f};
    acc2[1] = (fx4){0.f, 0.f, 0.f, 0.f};
    {
        bx8 ahi[2];
        int row = base + wv * 16 + lm;
        #pragma unroll
        for (int ks = 0; ks < 2; ++ks) {
            if (row < n)
                ahi[ks] = *(const bx8*)(h1b + (size_t)row * 64 + ks * 32 + lg * 8);
            else
                ahi[ks] = (bx8){0, 0, 0, 0, 0, 0, 0, 0};
        }
        #pragma unroll
        for (int nt = 0; nt < 2; ++nt) {
            #pragma unroll
            for (int ks = 0; ks < 2; ++ks) {
                int c = nt * 2 + ks;
                bx8 bh = *(const bx8*)&w2f_hi[((size_t)c * 64 + lane) * 8];
                bx8 bl = *(const bx8*)&w2f_lo[((size_t)c * 64 + lane) * 8];
                acc2[nt] = __builtin_amdgcn_mfma_f32_16x16x32_bf16(ahi[ks], bh, acc2[nt], 0, 0, 0);
                acc2[nt] = __builtin_amdgcn_mfma_f32_16x16x32_bf16(ahi[ks], bl, acc2[nt], 0, 0, 0);
            }
        }
    }
    #pragma unroll
    for (int nt = 0; nt < 2; ++nt) {
        #pragma unroll
        for (int r = 0; r < 4; ++r) {
            int lrow = wv * 16 + lg * 4 + r;
            int node = base + lrow;
            float v = acc2[nt][r];
            if (node < n) oh2[(size_t)node * 32 + nt * 16 + lm] = v;
            lds2[lrow * 36 + nt * 16 + lm] = v;
        }
    }
    __syncthreads();

    // ---- step 2: h3 = elu(h2 @ l1w^T + l1b) ----
    fx4 acc3[4];
    #pragma unroll
    for (int nt = 0; nt < 4; ++nt) acc3[nt] = (fx4){0.f, 0.f, 0.f, 0.f};
    {
        bx8 ahi, alo;
        {
            const float* ap = &lds2[(wv * 16 + lm) * 36 + lg * 8];
            float4 a0 = *(const float4*)ap;
            float4 a1 = *(const float4*)(ap + 4);
            float ff[8] = { a0.x, a0.y, a0.z, a0.w, a1.x, a1.y, a1.z, a1.w };
            #pragma unroll
            for (int i = 0; i < 8; ++i) {
                unsigned short hb = f32_to_bf16_rne(ff[i]);
                float rem = ff[i] - bf16_bits_to_f32(hb);
                ahi[i] = (short)hb;
                alo[i] = (short)f32_to_bf16_rne(rem);
            }
        }
        #pragma unroll
        for (int nt = 0; nt < 4; ++nt) {
            bx8 bh = *(const bx8*)&l1f_hi[((size_t)nt * 64 + lane) * 8];
            bx8 bl = *(const bx8*)&l1f_lo[((size_t)nt * 64 + lane) * 8];
            acc3[nt] = __builtin_amdgcn_mfma_f32_16x16x32_bf16(ahi, bh, acc3[nt], 0, 0, 0);
            acc3[nt] = __builtin_amdgcn_mfma_f32_16x16x32_bf16(ahi, bl, acc3[nt], 0, 0, 0);
            acc3[nt] = __builtin_amdgcn_mfma_f32_16x16x32_bf16(alo, bh, acc3[nt], 0, 0, 0);
        }
    }
    #pragma unroll
    for (int nt = 0; nt < 4; ++nt) {
        float b = l1b[nt * 16 + lm];
        #pragma unroll
        for (int r = 0; r < 4; ++r) {
            int lrow = wv * 16 + lg * 4 + r;
            lds3[lrow * 68 + nt * 16 + lm] = eluf(acc3[nt][r] + b);
        }
    }
    __syncthreads();

    // ---- step 3: h4 = h3 @ l2w^T + l2b ----
    float bias[4];
    #pragma unroll
    for (int ct = 0; ct < 4; ++ct) bias[ct] = l2b[wv * 64 + ct * 16 + lm];

    #pragma unroll
    for (int mt = 0; mt < 4; ++mt) {
        bx8 ahi[2], alo[2];
        #pragma unroll
        for (int ks = 0; ks < 2; ++ks) {
            const float* ap = &lds3[(mt * 16 + lm) * 68 + ks * 32 + lg * 8];
            float4 a0 = *(const float4*)ap;
            float4 a1 = *(const float4*)(ap + 4);
            float ff[8] = { a0.x, a0.y, a0.z, a0.w, a1.x, a1.y, a1.z, a1.w };
            #pragma unroll
            for (int i = 0; i < 8; ++i) {
                unsigned short hb = f32_to_bf16_rne(ff[i]);
                float rem = ff[i] - bf16_bits_to_f32(hb);
                ahi[ks][i] = (short)hb;
                alo[ks][i] = (short)f32_to_bf16_rne(rem);
            }
        }
        fx4 acc[4];
        #pragma unroll
        for (int ct = 0; ct < 4; ++ct) acc[ct] = (fx4){0.f, 0.f, 0.f, 0.f};
        #pragma unroll
        for (int ct = 0; ct < 4; ++ct) {
            #pragma unroll
            for (int ks = 0; ks < 2; ++ks) {
                int c = wv * 8 + ct * 2 + ks;
                bx8 bh = *(const bx8*)&l2f_hi[((size_t)c * 64 + lane) * 8];
                bx8 bl = *(const bx8*)&l2f_lo[((size_t)c * 64 + lane) * 8];
                acc[ct] = __builtin_amdgcn_mfma_f32_16x16x32_bf16(ahi[ks], bh, acc[ct], 0, 0, 0);
                acc[ct] = __builtin_amdgcn_mfma_f32_16x16x32_bf16(ahi[ks], bl, acc[ct], 0, 0, 0);
                acc[ct] = __builtin_amdgcn_mfma_f32_16x16x32_bf16(alo[ks], bh, acc[ct], 0, 0, 0);
            }
        }
        #pragma unroll
        for (int ct = 0; ct < 4; ++ct) {
            #pragma unroll
            for (int r = 0; r < 4; ++r) {
                int orow = base + mt * 16 + lg * 4 + r;
                if (orow < n) {
                    int ocol = wv * 64 + ct * 16 + lm;
                    oh4[(size_t)orow * 256 + ocol] = acc[ct][r] + bias[ct];
                }
            }
        }
    }
}

extern "C" void kernel_launch(void* const* d_in, const int* in_sizes, int n_in,
                              void* d_out, int out_size, void* d_ws, size_t ws_size,
                              hipStream_t stream) {
    const float* feat    = (const float*)d_in[0];
    const int*   ei      = (const int*)d_in[1];     // int64 in ref -> int32 on device
    const float* w1      = (const float*)d_in[2];
    const float* att_src = (const float*)d_in[3];
    const float* att_dst = (const float*)d_in[4];
    const float* w2      = (const float*)d_in[5];
    const float* l1w     = (const float*)d_in[6];
    const float* l1b     = (const float*)d_in[7];
    const float* l2w     = (const float*)d_in[8];
    const float* l2b     = (const float*)d_in[9];

    const int N = in_sizes[0] / IN_DIM;
    const int E = in_sizes[1] / 2;

    char* p = (char*)d_ws;
    auto alloc = [&](size_t bytes) {
        char* r = p;
        p += (bytes + 255) & ~(size_t)255;
        return r;
    };
    unsigned short* h_bf = (unsigned short*)alloc((size_t)N * HID * 2);
    unsigned short* h1b  = (unsigned short*)alloc((size_t)N * HID * 2);
    float* as_   = (float*)alloc((size_t)N * 4);
    float* ad_   = (float*)alloc((size_t)N * 4);
    int*   deg   = (int*)alloc((size_t)N * 4);
    int*   off   = (int*)alloc((size_t)(N + 1) * 4);
    int*   rank  = (int*)alloc((size_t)E * 4);
    int*   srcs  = (int*)alloc((size_t)E * 4);
    const int nb = (N + 1023) / 1024;
    int*   part  = (int*)alloc((size_t)nb * 4);
    short* w2f_hi = (short*)alloc(4 * 64 * 8 * 2);
    short* w2f_lo = (short*)alloc(4 * 64 * 8 * 2);
    short* l1f_hi = (short*)alloc(4 * 64 * 8 * 2);
    short* l1f_lo = (short*)alloc(4 * 64 * 8 * 2);
    short* l2f_hi = (short*)alloc(32 * 64 * 8 * 2);
    short* l2f_lo = (short*)alloc(32 * 64 * 8 * 2);

    float* oh2 = (float*)d_out;
    float* oh4 = oh2 + (size_t)N * OUTD;

    hipLaunchKernelGGL(k_init, dim3(256), dim3(256), 0, stream, deg, N);
    hipLaunchKernelGGL(k_wconv, dim3(1), dim3(256), 0, stream,
                       w2, l1w, l2w, w2f_hi, w2f_lo, l1f_hi, l1f_lo, l2f_hi, l2f_lo);
    const int nDegBlocks = 512;
    const int nFeatTiles = (N + 63) / 64;
    const int nGroups    = max((nFeatTiles + 3) / 4, nDegBlocks);
    hipLaunchKernelGGL(k_feat_deg, dim3(nGroups * 5), dim3(256), 0, stream,
                       feat, w1, att_src, att_dst, h_bf, as_, ad_,
                       ei, deg, rank, N, E, nDegBlocks);
    hipLaunchKernelGGL(k_scan_part, dim3(nb), dim3(1024), 0, stream, deg, part, N);
    hipLaunchKernelGGL(k_scan_top, dim3(1), dim3(1024), 0, stream, part, off, nb, N);
    hipLaunchKernelGGL(k_scan_down, dim3(nb), dim3(1024), 0, stream, deg, part, off, N);
    for (int pass = 0; pass < 4; ++pass) {
        int lo = (int)((size_t)N * pass / 4);
        int hi = (int)((size_t)N * (pass + 1) / 4);
        hipLaunchKernelGGL(k_fill, dim3(2048), dim3(256), 0, stream,
                           ei, off, rank, srcs, E, lo, hi);
    }
    hipLaunchKernelGGL(k_gat, dim3((N + 3) / 4), dim3(256), 0, stream,
                       off, srcs, as_, ad_, h_bf, h1b, N);
    hipLaunchKernelGGL(k_mlp_fused, dim3((N + 63) / 64), dim3(256), 0, stream,
                       h1b, w2f_hi, w2f_lo, l1f_hi, l1f_lo, l2f_hi, l2f_lo,
                       l1b, l2b, oh2, oh4, N);
}